// Round 1
// baseline (1618.981 us; speedup 1.0000x reference)
//
#include <hip/hip_runtime.h>
#include <hip/hip_bf16.h>
#include <math.h>

typedef __attribute__((ext_vector_type(8))) __bf16 v8bf;
typedef __attribute__((ext_vector_type(4))) float v4f;

#define NBm 8
#define SEQ 1024
#define CDm 512

__device__ __forceinline__ unsigned short f2bf(float f) {
  union { float f; unsigned int u; } a; a.f = f;
  unsigned int r = a.u + 0x7fffu + ((a.u >> 16) & 1u);
  return (unsigned short)(r >> 16);
}
__device__ __forceinline__ float sigm(float x) { return 1.0f / (1.0f + __expf(-x)); }

// ---------- GroupNorm(pre) + pos_emb : x (B,512,1024) -> hs (B,512,1024) ----------
__global__ __launch_bounds__(256) void gn_pre_kernel(
    const float* __restrict__ x, const float* __restrict__ g, const float* __restrict__ be,
    const float* __restrict__ pos, float* __restrict__ hs) {
  int b = blockIdx.x >> 5, grp = blockIdx.x & 31;
  const float4* base = (const float4*)(x + ((size_t)b*512 + grp*16)*1024);
  float s = 0.f, s2 = 0.f;
  for (int i = threadIdx.x; i < 4096; i += 256) {
    float4 v = base[i];
    s += v.x + v.y + v.z + v.w;
    s2 += v.x*v.x + v.y*v.y + v.z*v.z + v.w*v.w;
  }
#pragma unroll
  for (int o = 32; o; o >>= 1) { s += __shfl_xor(s, o); s2 += __shfl_xor(s2, o); }
  __shared__ float rs[4], rs2[4], mr[2];
  int w = threadIdx.x >> 6;
  if ((threadIdx.x & 63) == 0) { rs[w] = s; rs2[w] = s2; }
  __syncthreads();
  if (threadIdx.x == 0) {
    float ts = rs[0]+rs[1]+rs[2]+rs[3], ts2 = rs2[0]+rs2[1]+rs2[2]+rs2[3];
    float mu = ts * (1.0f/16384.0f);
    float var = ts2 * (1.0f/16384.0f) - mu*mu;
    mr[0] = mu; mr[1] = rsqrtf(var + 1e-6f);
  }
  __syncthreads();
  float mu = mr[0], rstd = mr[1];
  const float4* pb = (const float4*)(pos + (size_t)grp*16*1024);
  float4* ob = (float4*)(hs + ((size_t)b*512 + grp*16)*1024);
  for (int i = threadIdx.x; i < 4096; i += 256) {
    float4 v = base[i], p = pb[i];
    int c = grp*16 + (i >> 8);
    float gg = g[c], bb = be[c];
    float4 o;
    o.x = (v.x - mu)*rstd*gg + bb + p.x;
    o.y = (v.y - mu)*rstd*gg + bb + p.y;
    o.z = (v.z - mu)*rstd*gg + bb + p.z;
    o.w = (v.w - mu)*rstd*gg + bb + p.w;
    ob[i] = o;
  }
}

// ---------- stats of hs per (b,group): contiguous 16384 floats ----------
__global__ __launch_bounds__(256) void gn_stats_kernel(
    const float* __restrict__ t, float* __restrict__ stats) {
  int bg = blockIdx.x;
  const float4* base = (const float4*)(t + (size_t)bg*16384);
  float s = 0.f, s2 = 0.f;
  for (int i = threadIdx.x; i < 4096; i += 256) {
    float4 v = base[i];
    s += v.x + v.y + v.z + v.w;
    s2 += v.x*v.x + v.y*v.y + v.z*v.z + v.w*v.w;
  }
#pragma unroll
  for (int o = 32; o; o >>= 1) { s += __shfl_xor(s, o); s2 += __shfl_xor(s2, o); }
  __shared__ float rs[4], rs2[4];
  int w = threadIdx.x >> 6;
  if ((threadIdx.x & 63) == 0) { rs[w] = s; rs2[w] = s2; }
  __syncthreads();
  if (threadIdx.x == 0) {
    float ts = rs[0]+rs[1]+rs[2]+rs[3], ts2 = rs2[0]+rs2[1]+rs2[2]+rs2[3];
    float mu = ts * (1.0f/16384.0f);
    float var = ts2 * (1.0f/16384.0f) - mu*mu;
    stats[bg*2] = mu; stats[bg*2+1] = rsqrtf(var + 1e-6f);
  }
}

// ---------- conv1x1 (512->64) + SiLU ----------
__global__ __launch_bounds__(256) void conv1_kernel(
    const float* __restrict__ hs, const float* __restrict__ w,
    const float* __restrict__ bias, float* __restrict__ a1) {
  int b = blockIdx.z, oc0 = blockIdx.y * 8;
  int s = blockIdx.x * 256 + threadIdx.x;
  float acc[8];
#pragma unroll
  for (int j = 0; j < 8; ++j) acc[j] = bias[oc0+j];
  const float* hb = hs + (size_t)b*512*1024 + s;
#pragma unroll 8
  for (int ic = 0; ic < 512; ++ic) {
    float h = hb[(size_t)ic*1024];
#pragma unroll
    for (int j = 0; j < 8; ++j) acc[j] += h * w[(oc0+j)*512 + ic];
  }
#pragma unroll
  for (int j = 0; j < 8; ++j) {
    float v = acc[j];
    a1[((size_t)b*64 + oc0 + j)*1024 + s] = v * sigm(v);
  }
}

// ---------- conv3x3 (64->64) + SiLU ----------
__global__ __launch_bounds__(256) void conv2_kernel(
    const float* __restrict__ a1, const float* __restrict__ w,
    const float* __restrict__ bias, float* __restrict__ a2) {
  int b = blockIdx.z, oc0 = blockIdx.y * 8;
  int s = blockIdx.x * 256 + threadIdx.x;
  int y = s >> 5, x = s & 31;
  float acc[8];
#pragma unroll
  for (int j = 0; j < 8; ++j) acc[j] = bias[oc0+j];
  for (int ic = 0; ic < 64; ++ic) {
    const float* ar = a1 + ((size_t)b*64 + ic)*1024;
#pragma unroll
    for (int dy = 0; dy < 3; ++dy) {
      int yy = y + dy - 1;
      if ((unsigned)yy >= 32u) continue;
#pragma unroll
      for (int dx = 0; dx < 3; ++dx) {
        int xx = x + dx - 1;
        if ((unsigned)xx >= 32u) continue;
        float v = ar[yy*32 + xx];
#pragma unroll
        for (int j = 0; j < 8; ++j)
          acc[j] += v * w[(((oc0+j)*64 + ic)*9) + dy*3 + dx];
      }
    }
  }
#pragma unroll
  for (int j = 0; j < 8; ++j) {
    float v = acc[j];
    a2[((size_t)b*64 + oc0 + j)*1024 + s] = v * sigm(v);
  }
}

// ---------- conv1x1 (64->1) + sigmoid ----------
__global__ __launch_bounds__(256) void conv3_kernel(
    const float* __restrict__ a2, const float* __restrict__ w,
    const float* __restrict__ bias, float* __restrict__ swp) {
  int b = blockIdx.y;
  int s = blockIdx.x * 256 + threadIdx.x;
  float acc = bias[0];
#pragma unroll 8
  for (int ic = 0; ic < 64; ++ic)
    acc += a2[((size_t)b*64 + ic)*1024 + s] * w[ic];
  swp[b*1024 + s] = sigm(acc);
}

// ---------- GN(norm)+transpose -> sh (B,S,C) bf16 ; spatial gate -> msh bf16 ----------
__global__ __launch_bounds__(256) void norm_transpose_kernel(
    const float* __restrict__ hs, const float* __restrict__ swp,
    const float* __restrict__ stats, const float* __restrict__ g,
    const float* __restrict__ be,
    unsigned short* __restrict__ sh, unsigned short* __restrict__ msh) {
  int b = blockIdx.y;
  int s = blockIdx.x * 4 + (threadIdx.x >> 6);
  int oct = threadIdx.x & 63;
  int c0 = oct * 8;
  int grp = c0 >> 4;
  float mu = stats[(b*32 + grp)*2], rstd = stats[(b*32 + grp)*2 + 1];
  float wgt = swp[b*1024 + s];
  const float* hb = hs + ((size_t)b*512 + c0)*1024 + s;
  unsigned short so[8], mo[8];
#pragma unroll
  for (int j = 0; j < 8; ++j) {
    float v = hb[(size_t)j*1024];
    float sv = (v - mu)*rstd*g[c0+j] + be[c0+j];
    so[j] = f2bf(sv);
    mo[j] = f2bf(v * wgt);
  }
  size_t o = (size_t)(b*1024 + s)*512 + c0;
  *(ushort4*)(sh + o)     = make_ushort4(so[0], so[1], so[2], so[3]);
  *(ushort4*)(sh + o + 4) = make_ushort4(so[4], so[5], so[6], so[7]);
  *(ushort4*)(msh + o)     = make_ushort4(mo[0], mo[1], mo[2], mo[3]);
  *(ushort4*)(msh + o + 4) = make_ushort4(mo[4], mo[5], mo[6], mo[7]);
}

// ---------- weight f32 -> bf16 convert (all 12 weights in one launch) ----------
struct WCvt { const float* src; int dstOff; int n; };
struct WCvtArgs { WCvt w[12]; };
__global__ __launch_bounds__(256) void wconvert_kernel(WCvtArgs a, unsigned short* __restrict__ dst) {
  WCvt e = a.w[blockIdx.y];
  int i = blockIdx.x * 256 + threadIdx.x;
  if (i < e.n) dst[e.dstOff + i] = f2bf(e.src[i]);
}

// ---------- bf16 transpose (B,S,Cdim) -> (B,Cdim,S) ----------
__global__ __launch_bounds__(256) void transpose_bf16_kernel(
    const unsigned short* __restrict__ in, unsigned short* __restrict__ out, int Cdim) {
  int b = blockIdx.z, c = blockIdx.y;
  int s = blockIdx.x * 256 + threadIdx.x;
  out[((size_t)b*Cdim + c)*1024 + s] = in[((size_t)b*1024 + s)*Cdim + c];
}

// ---------- generic batched GEMM: out[m,n] = scale * sum_k A[m,k]*B[n,k] + bias[n] ----------
// A,B bf16 row-major; epi: 0=f32 store, 1=bf16 store, 2=silu then bf16 store
struct GemmDesc {
  const unsigned short* A; const unsigned short* B; void* out; const float* bias;
  float scale;
  int M, N, K, lda, ldb, ldo, epi;
  long long Ay, Az, By, Bz, Oy, Oz;
};
__global__ __launch_bounds__(256) void gemm_bt_kernel(GemmDesc d) {
  int wave = blockIdx.x * 4 + (threadIdx.x >> 6);
  int tn = d.N >> 4, tm = d.M >> 4;
  if (wave >= tm * tn) return;
  int mt = wave / tn, nt = wave - mt * tn;
  const unsigned short* A = d.A + (long long)blockIdx.y * d.Ay + (long long)blockIdx.z * d.Az;
  const unsigned short* B = d.B + (long long)blockIdx.y * d.By + (long long)blockIdx.z * d.Bz;
  int lane = threadIdx.x & 63, ln = lane & 15, qd = lane >> 4;
  const unsigned short* ap = A + (size_t)(mt*16 + ln)*d.lda + qd*8;
  const unsigned short* bp = B + (size_t)(nt*16 + ln)*d.ldb + qd*8;
  v4f acc = {0.f, 0.f, 0.f, 0.f};
  int steps = d.K >> 5;
  for (int i = 0; i < steps; ++i) {
    v8bf av = *(const v8bf*)ap;
    v8bf bv = *(const v8bf*)bp;
    acc = __builtin_amdgcn_mfma_f32_16x16x32_bf16(av, bv, acc, 0, 0, 0);
    ap += 32; bp += 32;
  }
  float bia = d.bias ? d.bias[nt*16 + ln] : 0.0f;
  size_t obase = (size_t)((long long)blockIdx.y * d.Oy + (long long)blockIdx.z * d.Oz);
#pragma unroll
  for (int r = 0; r < 4; ++r) {
    float v = acc[r] * d.scale + bia;
    if (d.epi == 2) v = v * sigm(v);
    int row = mt*16 + qd*4 + r, col = nt*16 + ln;
    size_t oi = obase + (size_t)row * d.ldo + col;
    if (d.epi == 0) ((float*)d.out)[oi] = v;
    else ((unsigned short*)d.out)[oi] = f2bf(v);
  }
}

// ---------- row softmax: S f32 (nrows,1024) -> P bf16 normalized ----------
__global__ __launch_bounds__(256) void softmax_kernel(
    const float* __restrict__ S, unsigned short* __restrict__ P, int nrows) {
  int row = blockIdx.x * 4 + (threadIdx.x >> 6);
  if (row >= nrows) return;
  int l = threadIdx.x & 63;
  const float4* s4 = (const float4*)(S + (size_t)row * 1024);
  float4 v[4];
  float m = -1e30f;
#pragma unroll
  for (int t = 0; t < 4; ++t) {
    v[t] = s4[t*64 + l];
    m = fmaxf(m, fmaxf(fmaxf(v[t].x, v[t].y), fmaxf(v[t].z, v[t].w)));
  }
#pragma unroll
  for (int o = 32; o; o >>= 1) m = fmaxf(m, __shfl_xor(m, o));
  float sum = 0.f;
#pragma unroll
  for (int t = 0; t < 4; ++t) {
    v[t].x = __expf(v[t].x - m); v[t].y = __expf(v[t].y - m);
    v[t].z = __expf(v[t].z - m); v[t].w = __expf(v[t].w - m);
    sum += v[t].x + v[t].y + v[t].z + v[t].w;
  }
#pragma unroll
  for (int o = 32; o; o >>= 1) sum += __shfl_xor(sum, o);
  float r = 1.0f / sum;
  unsigned short* p = P + (size_t)row * 1024;
#pragma unroll
  for (int t = 0; t < 4; ++t) {
    ushort4 u = make_ushort4(f2bf(v[t].x * r), f2bf(v[t].y * r),
                             f2bf(v[t].z * r), f2bf(v[t].w * r));
    ((ushort4*)(p + t*256))[l] = u;
  }
}

// ---------- stats over (B,S,C)-layout tensor per (b,group) ----------
__global__ __launch_bounds__(256) void gn_stats_bsc_kernel(
    const float* __restrict__ t, float* __restrict__ stats) {
  int b = blockIdx.x >> 5, grp = blockIdx.x & 31;
  int i4 = threadIdx.x & 3, s0 = threadIdx.x >> 2;
  float s = 0.f, s2 = 0.f;
  for (int j = 0; j < 16; ++j) {
    int sI = s0 + j*64;
    float4 v = *(const float4*)(t + ((size_t)(b*1024 + sI)*512 + grp*16 + i4*4));
    s += v.x + v.y + v.z + v.w;
    s2 += v.x*v.x + v.y*v.y + v.z*v.z + v.w*v.w;
  }
#pragma unroll
  for (int o = 32; o; o >>= 1) { s += __shfl_xor(s, o); s2 += __shfl_xor(s2, o); }
  __shared__ float rs[4], rs2[4];
  int w = threadIdx.x >> 6;
  if ((threadIdx.x & 63) == 0) { rs[w] = s; rs2[w] = s2; }
  __syncthreads();
  if (threadIdx.x == 0) {
    float ts = rs[0]+rs[1]+rs[2]+rs[3], ts2 = rs2[0]+rs2[1]+rs2[2]+rs2[3];
    float mu = ts * (1.0f/16384.0f);
    float var = ts2 * (1.0f/16384.0f) - mu*mu;
    stats[(b*32+grp)*2] = mu; stats[(b*32+grp)*2+1] = rsqrtf(var + 1e-6f);
  }
}

// ---------- GN(post) + residual, (B,S,C) -> (B,C,S) ----------
__global__ __launch_bounds__(256) void final_out_kernel(
    const float* __restrict__ fin, const float* __restrict__ stats,
    const float* __restrict__ g, const float* __restrict__ be,
    const float* __restrict__ x, float* __restrict__ out) {
  int c = blockIdx.x, b = blockIdx.y;
  int grp = c >> 4;
  float mu = stats[(b*32+grp)*2], rstd = stats[(b*32+grp)*2+1];
  float gg = g[c], bb = be[c];
  size_t obase = ((size_t)b*512 + c)*1024;
  for (int s = threadIdx.x; s < 1024; s += 256) {
    float v = fin[((size_t)(b*1024) + s)*512 + c];
    out[obase + s] = (v - mu)*rstd*gg + bb + x[obase + s];
  }
}

// =====================================================================
static void launch_gemm(hipStream_t st, const unsigned short* A, const unsigned short* B,
                        void* out, const float* bias, float scale,
                        int M, int N, int K, int lda, int ldb, int ldo, int epi,
                        long long Ay, long long Az, long long By, long long Bz,
                        long long Oy, long long Oz, int gy, int gz) {
  GemmDesc d;
  d.A = A; d.B = B; d.out = out; d.bias = bias; d.scale = scale;
  d.M = M; d.N = N; d.K = K; d.lda = lda; d.ldb = ldb; d.ldo = ldo; d.epi = epi;
  d.Ay = Ay; d.Az = Az; d.By = By; d.Bz = Bz; d.Oy = Oy; d.Oz = Oz;
  int tiles = (M/16)*(N/16);
  int bx = (tiles + 3) / 4;
  gemm_bt_kernel<<<dim3(bx, gy, gz), dim3(256), 0, st>>>(d);
}

extern "C" void kernel_launch(void* const* d_in, const int* in_sizes, int n_in,
                              void* d_out, int out_size, void* d_ws, size_t ws_size,
                              hipStream_t stream) {
  const float* x      = (const float*)d_in[0];
  const float* pre_g  = (const float*)d_in[1];
  const float* pre_b  = (const float*)d_in[2];
  const float* norm_g = (const float*)d_in[3];
  const float* norm_b = (const float*)d_in[4];
  const float* post_g = (const float*)d_in[5];
  const float* post_b = (const float*)d_in[6];
  const float* pos    = (const float*)d_in[7];
  const float* sa_w1  = (const float*)d_in[8];
  const float* sa_b1  = (const float*)d_in[9];
  const float* sa_w2  = (const float*)d_in[10];
  const float* sa_b2  = (const float*)d_in[11];
  const float* sa_w3  = (const float*)d_in[12];
  const float* sa_b3  = (const float*)d_in[13];
  const float* ff_b1  = (const float*)d_in[24];
  const float* ff_b2  = (const float*)d_in[26];
  const float* out_b  = (const float*)d_in[28];
  float* outp = (float*)d_out;

  char* ws = (char*)d_ws;
  size_t off = 0;
  auto alloc = [&](size_t bytes) -> void* {
    void* p = ws + off; off += (bytes + 255) & ~(size_t)255; return p;
  };
  float* HS   = (float*)alloc(16777216);
  float* A1   = (float*)alloc(2097152);
  float* A2   = (float*)alloc(2097152);
  float* SW   = (float*)alloc(32768);
  float* STATS= (float*)alloc(4096);
  unsigned short* SHB  = (unsigned short*)alloc(8388608);
  unsigned short* MSHB = (unsigned short*)alloc(8388608);
  unsigned short* WBF  = (unsigned short*)alloc(5242880);
  unsigned short* QBF  = (unsigned short*)alloc(8388608);
  unsigned short* KBF  = (unsigned short*)alloc(8388608);
  unsigned short* VBF  = (unsigned short*)alloc(8388608);
  unsigned short* VTB  = (unsigned short*)alloc(8388608);
  unsigned short* QM0  = (unsigned short*)alloc(4194304);
  unsigned short* QM1  = (unsigned short*)alloc(4194304);
  unsigned short* KM0  = (unsigned short*)alloc(4194304);
  unsigned short* KM1  = (unsigned short*)alloc(4194304);
  unsigned short* VM0  = (unsigned short*)alloc(4194304);
  unsigned short* VM1  = (unsigned short*)alloc(4194304);
  unsigned short* VMT0 = (unsigned short*)alloc(4194304);
  unsigned short* VMT1 = (unsigned short*)alloc(4194304);
  float* SBUF = (float*)alloc(33554432);
  unsigned short* PBUF = (unsigned short*)alloc(16777216);
  unsigned short* COMB = (unsigned short*)alloc(16777216);
  unsigned short* FFMID= (unsigned short*)alloc(8388608);
  unsigned short* FUSED= (unsigned short*)alloc(8388608);
  float* FINAL= (float*)alloc(16777216);

  // weight bf16 offsets (elements)
  const int OWQ=0, OWK=262144, OWV=524288, OWQ0=786432, OWK0=917504, OWV0=1048576,
            OWQ1=1179648, OWK1=1310720, OWV1=1441792, OFF1=1572864, OFF2=2097152, OOW=2359296;

  // 1) GN(pre) + pos
  gn_pre_kernel<<<dim3(256), dim3(256), 0, stream>>>(x, pre_g, pre_b, pos, HS);
  // 2) stats for GN(norm) over hs
  gn_stats_kernel<<<dim3(256), dim3(256), 0, stream>>>(HS, STATS);
  // 3) spatial gate convs
  conv1_kernel<<<dim3(4, 8, 8), dim3(256), 0, stream>>>(HS, sa_w1, sa_b1, A1);
  conv2_kernel<<<dim3(4, 8, 8), dim3(256), 0, stream>>>(A1, sa_w2, sa_b2, A2);
  conv3_kernel<<<dim3(4, 8), dim3(256), 0, stream>>>(A2, sa_w3, sa_b3, SW);
  // 4) weights -> bf16
  {
    WCvtArgs a;
    const int srcIdx[12] = {14,15,16,17,18,19,20,21,22,23,25,27};
    const int dofs[12] = {OWQ,OWK,OWV,OWQ0,OWK0,OWV0,OWQ1,OWK1,OWV1,OFF1,OFF2,OOW};
    const int ns[12]   = {262144,262144,262144,131072,131072,131072,131072,131072,131072,524288,262144,262144};
    for (int i = 0; i < 12; ++i) { a.w[i].src = (const float*)d_in[srcIdx[i]]; a.w[i].dstOff = dofs[i]; a.w[i].n = ns[i]; }
    wconvert_kernel<<<dim3(2048, 12), dim3(256), 0, stream>>>(a, WBF);
  }
  // 5) GN(norm)+transpose -> SHB ; gate -> MSHB
  norm_transpose_kernel<<<dim3(256, 8), dim3(256), 0, stream>>>(HS, SW, STATS, norm_g, norm_b, SHB, MSHB);

  // 6) projections (M=8192 tokens)
  launch_gemm(stream, SHB,  WBF+OWQ,  QBF, nullptr, 0.125f,  8192, 512, 512, 512, 512, 512, 1, 0,0,0,0,0,0, 1,1);
  launch_gemm(stream, SHB,  WBF+OWK,  KBF, nullptr, 1.0f,    8192, 512, 512, 512, 512, 512, 1, 0,0,0,0,0,0, 1,1);
  launch_gemm(stream, SHB,  WBF+OWV,  VBF, nullptr, 1.0f,    8192, 512, 512, 512, 512, 512, 1, 0,0,0,0,0,0, 1,1);
  launch_gemm(stream, MSHB, WBF+OWQ0, QM0, nullptr, 0.0625f, 8192, 256, 512, 512, 512, 256, 1, 0,0,0,0,0,0, 1,1);
  launch_gemm(stream, MSHB, WBF+OWQ1, QM1, nullptr, 0.0625f, 8192, 256, 512, 512, 512, 256, 1, 0,0,0,0,0,0, 1,1);
  launch_gemm(stream, SHB,  WBF+OWK0, KM0, nullptr, 1.0f,    8192, 256, 512, 512, 512, 256, 1, 0,0,0,0,0,0, 1,1);
  launch_gemm(stream, SHB,  WBF+OWK1, KM1, nullptr, 1.0f,    8192, 256, 512, 512, 512, 256, 1, 0,0,0,0,0,0, 1,1);
  launch_gemm(stream, SHB,  WBF+OWV0, VM0, nullptr, 1.0f,    8192, 256, 512, 512, 512, 256, 1, 0,0,0,0,0,0, 1,1);
  launch_gemm(stream, SHB,  WBF+OWV1, VM1, nullptr, 1.0f,    8192, 256, 512, 512, 512, 256, 1, 0,0,0,0,0,0, 1,1);

  // 7) V transposes for PV B-operands
  transpose_bf16_kernel<<<dim3(4, 512, 8), dim3(256), 0, stream>>>(VBF, VTB, 512);
  transpose_bf16_kernel<<<dim3(4, 256, 8), dim3(256), 0, stream>>>(VM0, VMT0, 256);
  transpose_bf16_kernel<<<dim3(4, 256, 8), dim3(256), 0, stream>>>(VM1, VMT1, 256);

  // 8) standard MHSA, 8 q-slabs of 128 rows
  for (int slab = 0; slab < 8; ++slab) {
    long long qs = slab * 128;
    // scores: per (b,h): (128 x 64) @ (1024 x 64)^T -> f32
    launch_gemm(stream, QBF + qs*512, KBF, SBUF, nullptr, 1.0f,
                128, 1024, 64, 512, 512, 1024, 0,
                1024LL*512, 64, 1024LL*512, 64, 8LL*128*1024, 128LL*1024, 8, 8);
    softmax_kernel<<<dim3(2048), dim3(256), 0, stream>>>(SBUF, PBUF, 8192);
    // PV: per (b,h): (128 x 1024) @ (64 x 1024)^T -> comb[:, :512] bf16
    launch_gemm(stream, PBUF, VTB, COMB + qs*1024, nullptr, 1.0f,
                128, 64, 1024, 1024, 1024, 1024, 1,
                8LL*128*1024, 128LL*1024, 512LL*1024, 64LL*1024, 1024LL*1024, 64, 8, 8);
  }

  // 9) two multi-scale branches
  for (int br = 0; br < 2; ++br) {
    const unsigned short* QMb = br ? QM1 : QM0;
    const unsigned short* KMb = br ? KM1 : KM0;
    const unsigned short* VMTb = br ? VMT1 : VMT0;
    launch_gemm(stream, QMb, KMb, SBUF, nullptr, 1.0f,
                1024, 1024, 256, 256, 256, 1024, 0,
                1024LL*256, 0, 1024LL*256, 0, 1024LL*1024, 0, 8, 1);
    softmax_kernel<<<dim3(2048), dim3(256), 0, stream>>>(SBUF, PBUF, 8192);
    launch_gemm(stream, PBUF, VMTb, COMB + 512 + br*256, nullptr, 1.0f,
                1024, 256, 1024, 1024, 1024, 1024, 1,
                1024LL*1024, 0, 256LL*1024, 0, 1024LL*1024, 0, 8, 1);
  }

  // 10) FF + out projection
  launch_gemm(stream, COMB,  WBF+OFF1, FFMID, ff_b1, 1.0f, 8192, 512, 1024, 1024, 1024, 512, 2, 0,0,0,0,0,0, 1,1);
  launch_gemm(stream, FFMID, WBF+OFF2, FUSED, ff_b2, 1.0f, 8192, 512, 512,  512,  512,  512, 1, 0,0,0,0,0,0, 1,1);
  launch_gemm(stream, FUSED, WBF+OOW,  FINAL, out_b, 1.0f, 8192, 512, 512,  512,  512,  512, 0, 0,0,0,0,0,0, 1,1);

  // 11) GN(post) + residual
  gn_stats_bsc_kernel<<<dim3(256), dim3(256), 0, stream>>>(FINAL, STATS);
  final_out_kernel<<<dim3(512, 8), dim3(256), 0, stream>>>(FINAL, STATS, post_g, post_b, x, outp);

  (void)in_sizes; (void)n_in; (void)out_size; (void)ws_size;
}

// Round 2
// 948.320 us; speedup vs baseline: 1.7072x; 1.7072x over previous
//
#include <hip/hip_runtime.h>
#include <hip/hip_bf16.h>
#include <math.h>

typedef __attribute__((ext_vector_type(8))) __bf16 v8bf;
typedef __attribute__((ext_vector_type(4))) float v4f;

__device__ __forceinline__ unsigned short f2bf(float f) {
  union { float f; unsigned int u; } a; a.f = f;
  unsigned int r = a.u + 0x7fffu + ((a.u >> 16) & 1u);
  return (unsigned short)(r >> 16);
}
__device__ __forceinline__ float sigm(float x) { return 1.0f / (1.0f + __expf(-x)); }

__device__ __forceinline__ void async16(const void* g, void* l) {
  __builtin_amdgcn_global_load_lds(
      (const __attribute__((address_space(1))) unsigned int*)g,
      (__attribute__((address_space(3))) unsigned int*)l, 16, 0, 0);
}

// ---------- GroupNorm(pre) + pos_emb : x (B,512,1024) -> hs (B,512,1024) ----------
__global__ __launch_bounds__(256) void gn_pre_kernel(
    const float* __restrict__ x, const float* __restrict__ g, const float* __restrict__ be,
    const float* __restrict__ pos, float* __restrict__ hs) {
  int b = blockIdx.x >> 5, grp = blockIdx.x & 31;
  const float4* base = (const float4*)(x + ((size_t)b*512 + grp*16)*1024);
  float s = 0.f, s2 = 0.f;
  for (int i = threadIdx.x; i < 4096; i += 256) {
    float4 v = base[i];
    s += v.x + v.y + v.z + v.w;
    s2 += v.x*v.x + v.y*v.y + v.z*v.z + v.w*v.w;
  }
#pragma unroll
  for (int o = 32; o; o >>= 1) { s += __shfl_xor(s, o); s2 += __shfl_xor(s2, o); }
  __shared__ float rs[4], rs2[4], mr[2];
  int w = threadIdx.x >> 6;
  if ((threadIdx.x & 63) == 0) { rs[w] = s; rs2[w] = s2; }
  __syncthreads();
  if (threadIdx.x == 0) {
    float ts = rs[0]+rs[1]+rs[2]+rs[3], ts2 = rs2[0]+rs2[1]+rs2[2]+rs2[3];
    float mu = ts * (1.0f/16384.0f);
    float var = ts2 * (1.0f/16384.0f) - mu*mu;
    mr[0] = mu; mr[1] = rsqrtf(var + 1e-6f);
  }
  __syncthreads();
  float mu = mr[0], rstd = mr[1];
  const float4* pb = (const float4*)(pos + (size_t)grp*16*1024);
  float4* ob = (float4*)(hs + ((size_t)b*512 + grp*16)*1024);
  for (int i = threadIdx.x; i < 4096; i += 256) {
    float4 v = base[i], p = pb[i];
    int c = grp*16 + (i >> 8);
    float gg = g[c], bb = be[c];
    float4 o;
    o.x = (v.x - mu)*rstd*gg + bb + p.x;
    o.y = (v.y - mu)*rstd*gg + bb + p.y;
    o.z = (v.z - mu)*rstd*gg + bb + p.z;
    o.w = (v.w - mu)*rstd*gg + bb + p.w;
    ob[i] = o;
  }
}

// ---------- stats of hs per (b,group): contiguous 16384 floats ----------
__global__ __launch_bounds__(256) void gn_stats_kernel(
    const float* __restrict__ t, float* __restrict__ stats) {
  int bg = blockIdx.x;
  const float4* base = (const float4*)(t + (size_t)bg*16384);
  float s = 0.f, s2 = 0.f;
  for (int i = threadIdx.x; i < 4096; i += 256) {
    float4 v = base[i];
    s += v.x + v.y + v.z + v.w;
    s2 += v.x*v.x + v.y*v.y + v.z*v.z + v.w*v.w;
  }
#pragma unroll
  for (int o = 32; o; o >>= 1) { s += __shfl_xor(s, o); s2 += __shfl_xor(s2, o); }
  __shared__ float rs[4], rs2[4];
  int w = threadIdx.x >> 6;
  if ((threadIdx.x & 63) == 0) { rs[w] = s; rs2[w] = s2; }
  __syncthreads();
  if (threadIdx.x == 0) {
    float ts = rs[0]+rs[1]+rs[2]+rs[3], ts2 = rs2[0]+rs2[1]+rs2[2]+rs2[3];
    float mu = ts * (1.0f/16384.0f);
    float var = ts2 * (1.0f/16384.0f) - mu*mu;
    stats[bg*2] = mu; stats[bg*2+1] = rsqrtf(var + 1e-6f);
  }
}

// ---------- conv1x1 (512->64) + SiLU ----------
__global__ __launch_bounds__(256) void conv1_kernel(
    const float* __restrict__ hs, const float* __restrict__ w,
    const float* __restrict__ bias, float* __restrict__ a1) {
  int b = blockIdx.z, oc0 = blockIdx.y * 8;
  int s = blockIdx.x * 256 + threadIdx.x;
  float acc[8];
#pragma unroll
  for (int j = 0; j < 8; ++j) acc[j] = bias[oc0+j];
  const float* hb = hs + (size_t)b*512*1024 + s;
#pragma unroll 8
  for (int ic = 0; ic < 512; ++ic) {
    float h = hb[(size_t)ic*1024];
#pragma unroll
    for (int j = 0; j < 8; ++j) acc[j] += h * w[(oc0+j)*512 + ic];
  }
#pragma unroll
  for (int j = 0; j < 8; ++j) {
    float v = acc[j];
    a1[((size_t)b*64 + oc0 + j)*1024 + s] = v * sigm(v);
  }
}

// ---------- conv3x3 (64->64) + SiLU ----------
__global__ __launch_bounds__(256) void conv2_kernel(
    const float* __restrict__ a1, const float* __restrict__ w,
    const float* __restrict__ bias, float* __restrict__ a2) {
  int b = blockIdx.z, oc0 = blockIdx.y * 8;
  int s = blockIdx.x * 256 + threadIdx.x;
  int y = s >> 5, x = s & 31;
  float acc[8];
#pragma unroll
  for (int j = 0; j < 8; ++j) acc[j] = bias[oc0+j];
  for (int ic = 0; ic < 64; ++ic) {
    const float* ar = a1 + ((size_t)b*64 + ic)*1024;
#pragma unroll
    for (int dy = 0; dy < 3; ++dy) {
      int yy = y + dy - 1;
      if ((unsigned)yy >= 32u) continue;
#pragma unroll
      for (int dx = 0; dx < 3; ++dx) {
        int xx = x + dx - 1;
        if ((unsigned)xx >= 32u) continue;
        float v = ar[yy*32 + xx];
#pragma unroll
        for (int j = 0; j < 8; ++j)
          acc[j] += v * w[(((oc0+j)*64 + ic)*9) + dy*3 + dx];
      }
    }
  }
#pragma unroll
  for (int j = 0; j < 8; ++j) {
    float v = acc[j];
    a2[((size_t)b*64 + oc0 + j)*1024 + s] = v * sigm(v);
  }
}

// ---------- conv1x1 (64->1) + sigmoid ----------
__global__ __launch_bounds__(256) void conv3_kernel(
    const float* __restrict__ a2, const float* __restrict__ w,
    const float* __restrict__ bias, float* __restrict__ swp) {
  int b = blockIdx.y;
  int s = blockIdx.x * 256 + threadIdx.x;
  float acc = bias[0];
#pragma unroll 8
  for (int ic = 0; ic < 64; ++ic)
    acc += a2[((size_t)b*64 + ic)*1024 + s] * w[ic];
  swp[b*1024 + s] = sigm(acc);
}

// ---------- GN(norm)+transpose -> sh (B,S,C) bf16 ; spatial gate -> msh bf16 ----------
__global__ __launch_bounds__(256) void norm_transpose_kernel(
    const float* __restrict__ hs, const float* __restrict__ swp,
    const float* __restrict__ stats, const float* __restrict__ g,
    const float* __restrict__ be,
    unsigned short* __restrict__ sh, unsigned short* __restrict__ msh) {
  int b = blockIdx.y;
  int s = blockIdx.x * 4 + (threadIdx.x >> 6);
  int oct = threadIdx.x & 63;
  int c0 = oct * 8;
  int grp = c0 >> 4;
  float mu = stats[(b*32 + grp)*2], rstd = stats[(b*32 + grp)*2 + 1];
  float wgt = swp[b*1024 + s];
  const float* hb = hs + ((size_t)b*512 + c0)*1024 + s;
  unsigned short so[8], mo[8];
#pragma unroll
  for (int j = 0; j < 8; ++j) {
    float v = hb[(size_t)j*1024];
    float sv = (v - mu)*rstd*g[c0+j] + be[c0+j];
    so[j] = f2bf(sv);
    mo[j] = f2bf(v * wgt);
  }
  size_t o = (size_t)(b*1024 + s)*512 + c0;
  *(ushort4*)(sh + o)     = make_ushort4(so[0], so[1], so[2], so[3]);
  *(ushort4*)(sh + o + 4) = make_ushort4(so[4], so[5], so[6], so[7]);
  *(ushort4*)(msh + o)     = make_ushort4(mo[0], mo[1], mo[2], mo[3]);
  *(ushort4*)(msh + o + 4) = make_ushort4(mo[4], mo[5], mo[6], mo[7]);
}

// ---------- weight f32 -> bf16 convert with scale ----------
struct WCvt { const float* src; int dstOff; int n; float scale; };
struct WCvtArgs { WCvt w[12]; };
__global__ __launch_bounds__(256) void wconvert_kernel(WCvtArgs a, unsigned short* __restrict__ dst) {
  WCvt e = a.w[blockIdx.y];
  int i = blockIdx.x * 256 + threadIdx.x;
  if (i < e.n) dst[e.dstOff + i] = f2bf(e.src[i] * e.scale);
}

// ---------- LDS-tiled bf16 transpose: in (B*1024, ldin) cols [colOff, colOff+Cd) -> out (B, Cd, 1024)
__global__ __launch_bounds__(256) void transpose_tile_kernel(
    const unsigned short* __restrict__ in, unsigned short* __restrict__ out,
    int ldin, int colOff) {
  __shared__ unsigned short t[64][65];
  int s0 = blockIdx.x * 64, c0 = blockIdx.y * 64, b = blockIdx.z;
  int Cd = gridDim.y * 64;
  int tx = threadIdx.x & 63, ty = threadIdx.x >> 6;
#pragma unroll
  for (int i = 0; i < 16; ++i) {
    int s = ty + i*4;
    t[s][tx] = in[((size_t)(b*1024 + s0 + s))*ldin + colOff + c0 + tx];
  }
  __syncthreads();
#pragma unroll
  for (int i = 0; i < 16; ++i) {
    int c = ty + i*4;
    out[((size_t)b*Cd + c0 + c)*1024 + s0 + tx] = t[tx][c];
  }
}

// ---------- tiled GEMM (m97 structure): out[m,n] = sum_k A[m,k]*B[n,k] (+bias[n]) ----------
// epi: 0 = f32 store, 1 = bf16 store, 2 = silu -> bf16 store
struct GemmDesc {
  const unsigned short* A; const unsigned short* B; void* out; const float* bias;
  int M, N, K, lda, ldb, ldo, epi;
  long long Ay, Az, By, Bz, Oy, Oz;
};

template<int BM, int BN>
__global__ __launch_bounds__(256) void gemm_tile_kernel(GemmDesc d) {
  constexpr int WGM = (BN >= 128) ? 2 : 4;       // wave grid MxN: 2x2 or 4x1
  constexpr int WGN = 4 / WGM;
  constexpr int MT = BM / (16 * WGM);
  constexpr int NT = BN / (16 * WGN);
  constexpr int AIT = (BM * 4) / 256;            // 16B staging chunks / 256 threads
  constexpr int BIT = (BN * 4) / 256;
  __shared__ __align__(16) unsigned short As[BM * 32];
  __shared__ __align__(16) unsigned short Bs[BN * 32];

  int ntx = d.N / BN;
  int bm0 = (blockIdx.x / ntx) * BM, bn0 = (blockIdx.x % ntx) * BN;
  const unsigned short* A = d.A + (long long)blockIdx.y * d.Ay
      + (long long)blockIdx.z * d.Az + (size_t)bm0 * d.lda;
  const unsigned short* B = d.B + (long long)blockIdx.y * d.By
      + (long long)blockIdx.z * d.Bz + (size_t)bn0 * d.ldb;
  int tid = threadIdx.x, lane = tid & 63, w = tid >> 6;
  int wm = (WGN == 2) ? (w >> 1) : w;
  int wn = (WGN == 2) ? (w & 1) : 0;
  int ln = lane & 15, qd = lane >> 4;

  v4f acc[MT][NT];
#pragma unroll
  for (int i = 0; i < MT; ++i)
#pragma unroll
    for (int j = 0; j < NT; ++j) acc[i][j] = (v4f){0.f, 0.f, 0.f, 0.f};

  int nks = d.K >> 5;
  for (int ks = 0; ks < nks; ++ks) {
    int kof = ks * 32;
#pragma unroll
    for (int it = 0; it < AIT; ++it) {
      int c = it * 256 + tid;
      async16(A + (size_t)(c >> 2) * d.lda + (c & 3) * 8 + kof,
              As + (it * 256 + w * 64) * 8);
    }
#pragma unroll
    for (int it = 0; it < BIT; ++it) {
      int c = it * 256 + tid;
      async16(B + (size_t)(c >> 2) * d.ldb + (c & 3) * 8 + kof,
              Bs + (it * 256 + w * 64) * 8);
    }
    __syncthreads();
    v8bf af[MT], bfr[NT];
#pragma unroll
    for (int i = 0; i < MT; ++i)
      af[i] = *(const v8bf*)(As + (wm * MT * 16 + i * 16 + ln) * 32 + qd * 8);
#pragma unroll
    for (int j = 0; j < NT; ++j)
      bfr[j] = *(const v8bf*)(Bs + (wn * NT * 16 + j * 16 + ln) * 32 + qd * 8);
#pragma unroll
    for (int i = 0; i < MT; ++i)
#pragma unroll
      for (int j = 0; j < NT; ++j)
        acc[i][j] = __builtin_amdgcn_mfma_f32_16x16x32_bf16(af[i], bfr[j], acc[i][j], 0, 0, 0);
    __syncthreads();
  }

  size_t obase = (size_t)((long long)blockIdx.y * d.Oy + (long long)blockIdx.z * d.Oz);
#pragma unroll
  for (int i = 0; i < MT; ++i) {
#pragma unroll
    for (int j = 0; j < NT; ++j) {
      int col = bn0 + wn * NT * 16 + j * 16 + ln;
      float bia = d.bias ? d.bias[col] : 0.0f;
#pragma unroll
      for (int r = 0; r < 4; ++r) {
        int row = bm0 + wm * MT * 16 + i * 16 + qd * 4 + r;
        float v = acc[i][j][r] + bia;
        if (d.epi == 2) v = v * sigm(v);
        size_t oi = obase + (size_t)row * d.ldo + col;
        if (d.epi == 0) ((float*)d.out)[oi] = v;
        else ((unsigned short*)d.out)[oi] = f2bf(v);
      }
    }
  }
}

// ---------- row softmax: S f32 (nrows,1024) -> P bf16 normalized ----------
__global__ __launch_bounds__(256) void softmax_kernel(
    const float* __restrict__ S, unsigned short* __restrict__ P, int nrows) {
  int row = blockIdx.x * 4 + (threadIdx.x >> 6);
  if (row >= nrows) return;
  int l = threadIdx.x & 63;
  const float4* s4 = (const float4*)(S + (size_t)row * 1024);
  float4 v[4];
  float m = -1e30f;
#pragma unroll
  for (int t = 0; t < 4; ++t) {
    v[t] = s4[t*64 + l];
    m = fmaxf(m, fmaxf(fmaxf(v[t].x, v[t].y), fmaxf(v[t].z, v[t].w)));
  }
#pragma unroll
  for (int o = 32; o; o >>= 1) m = fmaxf(m, __shfl_xor(m, o));
  float sum = 0.f;
#pragma unroll
  for (int t = 0; t < 4; ++t) {
    v[t].x = __expf(v[t].x - m); v[t].y = __expf(v[t].y - m);
    v[t].z = __expf(v[t].z - m); v[t].w = __expf(v[t].w - m);
    sum += v[t].x + v[t].y + v[t].z + v[t].w;
  }
#pragma unroll
  for (int o = 32; o; o >>= 1) sum += __shfl_xor(sum, o);
  float r = 1.0f / sum;
  unsigned short* p = P + (size_t)row * 1024;
#pragma unroll
  for (int t = 0; t < 4; ++t) {
    ushort4 u = make_ushort4(f2bf(v[t].x * r), f2bf(v[t].y * r),
                             f2bf(v[t].z * r), f2bf(v[t].w * r));
    ((ushort4*)(p + t*256))[l] = u;
  }
}

// ---------- stats over (B,S,C)-layout tensor per (b,group) ----------
__global__ __launch_bounds__(256) void gn_stats_bsc_kernel(
    const float* __restrict__ t, float* __restrict__ stats) {
  int b = blockIdx.x >> 5, grp = blockIdx.x & 31;
  int i4 = threadIdx.x & 3, s0 = threadIdx.x >> 2;
  float s = 0.f, s2 = 0.f;
  for (int j = 0; j < 16; ++j) {
    int sI = s0 + j*64;
    float4 v = *(const float4*)(t + ((size_t)(b*1024 + sI)*512 + grp*16 + i4*4));
    s += v.x + v.y + v.z + v.w;
    s2 += v.x*v.x + v.y*v.y + v.z*v.z + v.w*v.w;
  }
#pragma unroll
  for (int o = 32; o; o >>= 1) { s += __shfl_xor(s, o); s2 += __shfl_xor(s2, o); }
  __shared__ float rs[4], rs2[4];
  int w = threadIdx.x >> 6;
  if ((threadIdx.x & 63) == 0) { rs[w] = s; rs2[w] = s2; }
  __syncthreads();
  if (threadIdx.x == 0) {
    float ts = rs[0]+rs[1]+rs[2]+rs[3], ts2 = rs2[0]+rs2[1]+rs2[2]+rs2[3];
    float mu = ts * (1.0f/16384.0f);
    float var = ts2 * (1.0f/16384.0f) - mu*mu;
    stats[(b*32+grp)*2] = mu; stats[(b*32+grp)*2+1] = rsqrtf(var + 1e-6f);
  }
}

// ---------- GN(post) + residual, (B,S,C) -> (B,C,S) ----------
__global__ __launch_bounds__(256) void final_out_kernel(
    const float* __restrict__ fin, const float* __restrict__ stats,
    const float* __restrict__ g, const float* __restrict__ be,
    const float* __restrict__ x, float* __restrict__ out) {
  int c = blockIdx.x, b = blockIdx.y;
  int grp = c >> 4;
  float mu = stats[(b*32+grp)*2], rstd = stats[(b*32+grp)*2+1];
  float gg = g[c], bb = be[c];
  size_t obase = ((size_t)b*512 + c)*1024;
  for (int s = threadIdx.x; s < 1024; s += 256) {
    float v = fin[((size_t)(b*1024) + s)*512 + c];
    out[obase + s] = (v - mu)*rstd*gg + bb + x[obase + s];
  }
}

// =====================================================================
static void launch_gemm128(hipStream_t st, const unsigned short* A, const unsigned short* B,
                           void* out, const float* bias,
                           int M, int N, int K, int lda, int ldb, int ldo, int epi,
                           long long Ay, long long Az, long long By, long long Bz,
                           long long Oy, long long Oz, int gy, int gz) {
  GemmDesc d{A, B, out, bias, M, N, K, lda, ldb, ldo, epi, Ay, Az, By, Bz, Oy, Oz};
  gemm_tile_kernel<128,128><<<dim3((M/128)*(N/128), gy, gz), dim3(256), 0, st>>>(d);
}
static void launch_gemm64(hipStream_t st, const unsigned short* A, const unsigned short* B,
                          void* out, const float* bias,
                          int M, int N, int K, int lda, int ldb, int ldo, int epi,
                          long long Ay, long long Az, long long By, long long Bz,
                          long long Oy, long long Oz, int gy, int gz) {
  GemmDesc d{A, B, out, bias, M, N, K, lda, ldb, ldo, epi, Ay, Az, By, Bz, Oy, Oz};
  gemm_tile_kernel<128,64><<<dim3((M/128)*(N/64), gy, gz), dim3(256), 0, st>>>(d);
}

extern "C" void kernel_launch(void* const* d_in, const int* in_sizes, int n_in,
                              void* d_out, int out_size, void* d_ws, size_t ws_size,
                              hipStream_t stream) {
  const float* x      = (const float*)d_in[0];
  const float* pre_g  = (const float*)d_in[1];
  const float* pre_b  = (const float*)d_in[2];
  const float* norm_g = (const float*)d_in[3];
  const float* norm_b = (const float*)d_in[4];
  const float* post_g = (const float*)d_in[5];
  const float* post_b = (const float*)d_in[6];
  const float* pos    = (const float*)d_in[7];
  const float* sa_w1  = (const float*)d_in[8];
  const float* sa_b1  = (const float*)d_in[9];
  const float* sa_w2  = (const float*)d_in[10];
  const float* sa_b2  = (const float*)d_in[11];
  const float* sa_w3  = (const float*)d_in[12];
  const float* sa_b3  = (const float*)d_in[13];
  const float* ff_b1  = (const float*)d_in[24];
  const float* ff_b2  = (const float*)d_in[26];
  const float* out_b  = (const float*)d_in[28];
  float* outp = (float*)d_out;

  char* ws = (char*)d_ws;
  size_t off = 0;
  auto alloc = [&](size_t bytes) -> void* {
    void* p = ws + off; off += (bytes + 255) & ~(size_t)255; return p;
  };
  float* HS   = (float*)alloc(16777216);
  float* A1   = (float*)alloc(2097152);
  float* A2   = (float*)alloc(2097152);
  float* SW   = (float*)alloc(32768);
  float* STATS= (float*)alloc(4096);
  unsigned short* SHB  = (unsigned short*)alloc(8388608);   // (B*S,512) normed
  unsigned short* MSHB = (unsigned short*)alloc(8388608);   // (B*S,512) gated
  unsigned short* WBF  = (unsigned short*)alloc(5242880);   // packed bf16 weights
  unsigned short* QKV  = (unsigned short*)alloc(25165824);  // (B*S,1536) Q|K|V
  unsigned short* QM   = (unsigned short*)alloc(8388608);   // (B*S,512)  Q0|Q1
  unsigned short* KVM  = (unsigned short*)alloc(16777216);  // (B*S,1024) K0|K1|V0|V1
  unsigned short* VTB  = (unsigned short*)alloc(8388608);   // (B,512,1024) V^T
  unsigned short* VMT  = (unsigned short*)alloc(8388608);   // (B,512,1024) [V0|V1]^T
  float* SBUF = (float*)alloc(33554432);
  unsigned short* PBUF = (unsigned short*)alloc(16777216);
  unsigned short* COMB = (unsigned short*)alloc(16777216);  // (B*S,1024)
  unsigned short* FFMID= (unsigned short*)alloc(8388608);
  unsigned short* FUSED= (unsigned short*)alloc(8388608);
  float* FINAL= (float*)alloc(16777216);

  // packed weight offsets (elements): QKV(1536x512) | QM(512x512) | KVM(1024x512) | FF1(512x1024) | FF2(512x512) | OW(512x512)
  const int OQKV=0, OQM=786432, OKVM=1048576, OFF1=1572864, OFF2=2097152, OOW=2359296;

  // 1) GN(pre) + pos
  gn_pre_kernel<<<dim3(256), dim3(256), 0, stream>>>(x, pre_g, pre_b, pos, HS);
  // 2) stats for GN(norm) over hs
  gn_stats_kernel<<<dim3(256), dim3(256), 0, stream>>>(HS, STATS);
  // 3) spatial gate convs
  conv1_kernel<<<dim3(4, 8, 8), dim3(256), 0, stream>>>(HS, sa_w1, sa_b1, A1);
  conv2_kernel<<<dim3(4, 8, 8), dim3(256), 0, stream>>>(A1, sa_w2, sa_b2, A2);
  conv3_kernel<<<dim3(4, 8), dim3(256), 0, stream>>>(A2, sa_w3, sa_b3, SW);
  // 4) weights -> bf16 (softmax scales folded into Q weights)
  {
    WCvtArgs a;
    const int   srcIdx[12] = {14,15,16,17,20,18,21,19,22,23,25,27};
    const int   dofs[12]   = {OQKV, OQKV+262144, OQKV+524288,
                              OQM, OQM+131072,
                              OKVM, OKVM+131072, OKVM+262144, OKVM+393216,
                              OFF1, OFF2, OOW};
    const int   ns[12]     = {262144,262144,262144,131072,131072,131072,131072,131072,131072,524288,262144,262144};
    const float sc[12]     = {0.125f,1.f,1.f,0.0625f,0.0625f,1.f,1.f,1.f,1.f,1.f,1.f,1.f};
    for (int i = 0; i < 12; ++i) { a.w[i].src = (const float*)d_in[srcIdx[i]]; a.w[i].dstOff = dofs[i]; a.w[i].n = ns[i]; a.w[i].scale = sc[i]; }
    wconvert_kernel<<<dim3(2048, 12), dim3(256), 0, stream>>>(a, WBF);
  }
  // 5) GN(norm)+transpose -> SHB ; gate -> MSHB
  norm_transpose_kernel<<<dim3(256, 8), dim3(256), 0, stream>>>(HS, SW, STATS, norm_g, norm_b, SHB, MSHB);

  // 6) fused projections
  launch_gemm128(stream, SHB,  WBF+OQKV, QKV, nullptr, 8192, 1536, 512, 512, 512, 1536, 1, 0,0,0,0,0,0, 1,1);
  launch_gemm128(stream, MSHB, WBF+OQM,  QM,  nullptr, 8192, 512,  512, 512, 512, 512,  1, 0,0,0,0,0,0, 1,1);
  launch_gemm128(stream, SHB,  WBF+OKVM, KVM, nullptr, 8192, 1024, 512, 512, 512, 1024, 1, 0,0,0,0,0,0, 1,1);

  // 7) V transposes (LDS-tiled)
  transpose_tile_kernel<<<dim3(16, 8, 8), dim3(256), 0, stream>>>(QKV, VTB, 1536, 1024);
  transpose_tile_kernel<<<dim3(16, 8, 8), dim3(256), 0, stream>>>(KVM, VMT, 1024, 512);

  // 8) standard MHSA, 8 q-slabs of 128 rows
  for (int slab = 0; slab < 8; ++slab) {
    long long qs = (long long)slab * 128 * 1536;
    // scores per (b,h): (128 x 64) @ (1024 x 64)^T -> f32   [scale folded into Q]
    launch_gemm128(stream, QKV + qs, QKV + 512, SBUF, nullptr,
                   128, 1024, 64, 1536, 1536, 1024, 0,
                   1024LL*1536, 64, 1024LL*1536, 64, 8LL*128*1024, 128LL*1024, 8, 8);
    softmax_kernel<<<dim3(2048), dim3(256), 0, stream>>>(SBUF, PBUF, 8192);
    // PV per (b,h): (128 x 1024) @ (64 x 1024)^T -> comb[:, h*64:...] bf16
    launch_gemm64(stream, PBUF, VTB, COMB + (size_t)slab*128*1024, nullptr,
                  128, 64, 1024, 1024, 1024, 1024, 1,
                  8LL*128*1024, 128LL*1024, 512LL*1024, 64LL*1024, 1024LL*1024, 64, 8, 8);
  }

  // 9) two multi-scale branches
  for (int br = 0; br < 2; ++br) {
    launch_gemm128(stream, QM + br*256, KVM + br*256, SBUF, nullptr,
                   1024, 1024, 256, 512, 1024, 1024, 0,
                   1024LL*512, 0, 1024LL*1024, 0, 1024LL*1024, 0, 8, 1);
    softmax_kernel<<<dim3(2048), dim3(256), 0, stream>>>(SBUF, PBUF, 8192);
    launch_gemm128(stream, PBUF, VMT + (size_t)br*256*1024, COMB + 512 + br*256, nullptr,
                   1024, 256, 1024, 1024, 1024, 1024, 1,
                   1024LL*1024, 0, 512LL*1024, 0, 1024LL*1024, 0, 8, 1);
  }

  // 10) FF + out projection
  launch_gemm128(stream, COMB,  WBF+OFF1, FFMID, ff_b1, 8192, 512, 1024, 1024, 1024, 512, 2, 0,0,0,0,0,0, 1,1);
  launch_gemm128(stream, FFMID, WBF+OFF2, FUSED, ff_b2, 8192, 512, 512,  512,  512,  512, 1, 0,0,0,0,0,0, 1,1);
  launch_gemm128(stream, FUSED, WBF+OOW,  FINAL, out_b, 8192, 512, 512,  512,  512,  512, 0, 0,0,0,0,0,0, 1,1);

  // 11) GN(post) + residual
  gn_stats_bsc_kernel<<<dim3(256), dim3(256), 0, stream>>>(FINAL, STATS);
  final_out_kernel<<<dim3(512, 8), dim3(256), 0, stream>>>(FINAL, STATS, post_g, post_b, x, outp);

  (void)in_sizes; (void)n_in; (void)out_size; (void)ws_size;
}

// Round 3
// 574.835 us; speedup vs baseline: 2.8164x; 1.6497x over previous
//
#include <hip/hip_runtime.h>
#include <hip/hip_bf16.h>
#include <math.h>

typedef __attribute__((ext_vector_type(8))) __bf16 v8bf;
typedef __attribute__((ext_vector_type(4))) float v4f;

__device__ __forceinline__ unsigned short f2bf(float f) {
  union { float f; unsigned int u; } a; a.f = f;
  unsigned int r = a.u + 0x7fffu + ((a.u >> 16) & 1u);
  return (unsigned short)(r >> 16);
}
__device__ __forceinline__ float bf2f(unsigned short u) {
  union { unsigned int i; float f; } a; a.i = ((unsigned int)u) << 16; return a.f;
}
__device__ __forceinline__ float sigm(float x) { return 1.0f / (1.0f + __expf(-x)); }

__device__ __forceinline__ void async16(const void* g, void* l) {
  __builtin_amdgcn_global_load_lds(
      (const __attribute__((address_space(1))) unsigned int*)g,
      (__attribute__((address_space(3))) unsigned int*)l, 16, 0, 0);
}

// ---------- GN(pre) + pos -> hs f32 (B,512,1024); fused GN(norm) stats ----------
__global__ __launch_bounds__(256) void gn_pre_kernel(
    const float* __restrict__ x, const float* __restrict__ g, const float* __restrict__ be,
    const float* __restrict__ pos, float* __restrict__ hs, float* __restrict__ stats) {
  int b = blockIdx.x >> 5, grp = blockIdx.x & 31;
  const float4* base = (const float4*)(x + ((size_t)b*512 + grp*16)*1024);
  float s = 0.f, s2 = 0.f;
  for (int i = threadIdx.x; i < 4096; i += 256) {
    float4 v = base[i];
    s += v.x + v.y + v.z + v.w;
    s2 += v.x*v.x + v.y*v.y + v.z*v.z + v.w*v.w;
  }
#pragma unroll
  for (int o = 32; o; o >>= 1) { s += __shfl_xor(s, o); s2 += __shfl_xor(s2, o); }
  __shared__ float rs[4], rs2[4], mr[2];
  int w = threadIdx.x >> 6;
  if ((threadIdx.x & 63) == 0) { rs[w] = s; rs2[w] = s2; }
  __syncthreads();
  if (threadIdx.x == 0) {
    float ts = rs[0]+rs[1]+rs[2]+rs[3], ts2 = rs2[0]+rs2[1]+rs2[2]+rs2[3];
    float mu = ts * (1.0f/16384.0f);
    float var = ts2 * (1.0f/16384.0f) - mu*mu;
    mr[0] = mu; mr[1] = rsqrtf(var + 1e-6f);
  }
  __syncthreads();
  float mu = mr[0], rstd = mr[1];
  const float4* pb = (const float4*)(pos + (size_t)grp*16*1024);
  float4* ob = (float4*)(hs + ((size_t)b*512 + grp*16)*1024);
  float ns = 0.f, ns2 = 0.f;
  for (int i = threadIdx.x; i < 4096; i += 256) {
    float4 v = base[i], p = pb[i];
    int c = grp*16 + (i >> 8);
    float gg = g[c], bb = be[c];
    float4 o;
    o.x = (v.x - mu)*rstd*gg + bb + p.x;
    o.y = (v.y - mu)*rstd*gg + bb + p.y;
    o.z = (v.z - mu)*rstd*gg + bb + p.z;
    o.w = (v.w - mu)*rstd*gg + bb + p.w;
    ob[i] = o;
    ns += o.x + o.y + o.z + o.w;
    ns2 += o.x*o.x + o.y*o.y + o.z*o.z + o.w*o.w;
  }
#pragma unroll
  for (int o = 32; o; o >>= 1) { ns += __shfl_xor(ns, o); ns2 += __shfl_xor(ns2, o); }
  if ((threadIdx.x & 63) == 0) { rs[w] = ns; rs2[w] = ns2; }
  __syncthreads();
  if (threadIdx.x == 0) {
    float ts = rs[0]+rs[1]+rs[2]+rs[3], ts2 = rs2[0]+rs2[1]+rs2[2]+rs2[3];
    float nmu = ts * (1.0f/16384.0f);
    float nvar = ts2 * (1.0f/16384.0f) - nmu*nmu;
    stats[(b*32+grp)*2] = nmu; stats[(b*32+grp)*2+1] = rsqrtf(nvar + 1e-6f);
  }
}

// ---------- HS f32 ch-major -> HSB bf16 token-major ----------
__global__ __launch_bounds__(256) void hs_to_bsc_kernel(
    const float* __restrict__ hs, unsigned short* __restrict__ hsb) {
  int b = blockIdx.y;
  int s = blockIdx.x * 4 + (threadIdx.x >> 6);
  int c0 = (threadIdx.x & 63) * 8;
  const float* hb = hs + ((size_t)b*512 + c0)*1024 + s;
  unsigned short o[8];
#pragma unroll
  for (int j = 0; j < 8; ++j) o[j] = f2bf(hb[(size_t)j*1024]);
  size_t oo = (size_t)(b*1024 + s)*512 + c0;
  *(ushort4*)(hsb + oo)     = make_ushort4(o[0], o[1], o[2], o[3]);
  *(ushort4*)(hsb + oo + 4) = make_ushort4(o[4], o[5], o[6], o[7]);
}

// ---------- im2col: A1 (B*S,64) bf16 -> IM2 (B*S,576) bf16 ----------
__global__ __launch_bounds__(256) void im2col_kernel(
    const unsigned short* __restrict__ a1, unsigned short* __restrict__ im2) {
  int row0 = blockIdx.x * 8;
#pragma unroll
  for (int it = 0; it < 3; ++it) {
    int cc = it*256 + threadIdx.x;
    if (cc >= 576) break;
    int rl = cc / 72, rr = cc - rl*72;
    int tap = rr >> 3, ch8 = rr & 7;
    int row = row0 + rl;
    int bb = row >> 10, s = row & 1023;
    int y = s >> 5, xx0 = s & 31;
    int yy = y + tap/3 - 1, xx = xx0 + tap%3 - 1;
    ushort4 v0 = make_ushort4(0,0,0,0), v1 = make_ushort4(0,0,0,0);
    if ((unsigned)yy < 32u && (unsigned)xx < 32u) {
      const unsigned short* src = a1 + ((size_t)(bb*1024 + yy*32 + xx))*64 + ch8*8;
      v0 = *(const ushort4*)src; v1 = *(const ushort4*)(src + 4);
    }
    unsigned short* dst = im2 + (size_t)row*576 + tap*64 + ch8*8;
    *(ushort4*)dst = v0; *(ushort4*)(dst + 4) = v1;
  }
}

// ---------- conv3: A2 (B*S,64) bf16 -> SW sigmoid gate f32 ----------
__global__ __launch_bounds__(256) void conv3_kernel(
    const unsigned short* __restrict__ a2, const float* __restrict__ w,
    const float* __restrict__ bias, float* __restrict__ swp) {
  int row = blockIdx.x * 256 + threadIdx.x;
  const unsigned short* ar = a2 + (size_t)row*64;
  float acc = bias[0];
#pragma unroll
  for (int ic = 0; ic < 64; ic += 4) {
    ushort4 u = *(const ushort4*)(ar + ic);
    acc += bf2f(u.x)*w[ic] + bf2f(u.y)*w[ic+1] + bf2f(u.z)*w[ic+2] + bf2f(u.w)*w[ic+3];
  }
  swp[row] = sigm(acc);
}

// ---------- gate + GN(norm): HSB -> SHB (normed), MSHB (gated) ----------
__global__ __launch_bounds__(256) void gate_norm_kernel(
    const unsigned short* __restrict__ hsb, const float* __restrict__ swp,
    const float* __restrict__ stats, const float* __restrict__ g,
    const float* __restrict__ be,
    unsigned short* __restrict__ sh, unsigned short* __restrict__ msh) {
  int b = blockIdx.y;
  int s = blockIdx.x * 4 + (threadIdx.x >> 6);
  int c0 = (threadIdx.x & 63) * 8;
  int grp = c0 >> 4;
  float mu = stats[(b*32 + grp)*2], rstd = stats[(b*32 + grp)*2 + 1];
  float wgt = swp[b*1024 + s];
  size_t o = (size_t)(b*1024 + s)*512 + c0;
  ushort4 u0 = *(const ushort4*)(hsb + o), u1 = *(const ushort4*)(hsb + o + 4);
  unsigned short uu[8] = {u0.x,u0.y,u0.z,u0.w,u1.x,u1.y,u1.z,u1.w};
  unsigned short so[8], mo[8];
#pragma unroll
  for (int j = 0; j < 8; ++j) {
    float v = bf2f(uu[j]);
    so[j] = f2bf((v - mu)*rstd*g[c0+j] + be[c0+j]);
    mo[j] = f2bf(v * wgt);
  }
  *(ushort4*)(sh + o)     = make_ushort4(so[0], so[1], so[2], so[3]);
  *(ushort4*)(sh + o + 4) = make_ushort4(so[4], so[5], so[6], so[7]);
  *(ushort4*)(msh + o)     = make_ushort4(mo[0], mo[1], mo[2], mo[3]);
  *(ushort4*)(msh + o + 4) = make_ushort4(mo[4], mo[5], mo[6], mo[7]);
}

// ---------- weight f32 -> bf16 convert with scale ----------
struct WCvt { const float* src; int dstOff; int n; float scale; };
struct WCvtArgs { WCvt w[13]; };
__global__ __launch_bounds__(256) void wconvert_kernel(WCvtArgs a, unsigned short* __restrict__ dst) {
  WCvt e = a.w[blockIdx.y];
  int i = blockIdx.x * 256 + threadIdx.x;
  if (i < e.n) dst[e.dstOff + i] = f2bf(e.src[i] * e.scale);
}

// ---------- conv2 weight reorder: OIHW (64,64,3,3) -> (oc, tap*64+ic) bf16 ----------
__global__ __launch_bounds__(256) void w2reorder_kernel(
    const float* __restrict__ w2, unsigned short* __restrict__ dst) {
  int e = blockIdx.x * 256 + threadIdx.x;
  if (e >= 36864) return;
  int oc = e / 576, r = e - oc*576;
  int tap = r >> 6, ic = r & 63;
  dst[e] = f2bf(w2[(oc*64 + ic)*9 + tap]);
}

// ---------- LDS-tiled bf16 transpose: in (B*1024, ldin) cols [colOff,+Cd) -> out (B,Cd,1024)
__global__ __launch_bounds__(256) void transpose_tile_kernel(
    const unsigned short* __restrict__ in, unsigned short* __restrict__ out,
    int ldin, int colOff) {
  __shared__ unsigned short t[64][65];
  int s0 = blockIdx.x * 64, c0 = blockIdx.y * 64, b = blockIdx.z;
  int Cd = gridDim.y * 64;
  int tx = threadIdx.x & 63, ty = threadIdx.x >> 6;
#pragma unroll
  for (int i = 0; i < 16; ++i) {
    int s = ty + i*4;
    t[s][tx] = in[((size_t)(b*1024 + s0 + s))*ldin + colOff + c0 + tx];
  }
  __syncthreads();
#pragma unroll
  for (int i = 0; i < 16; ++i) {
    int c = ty + i*4;
    out[((size_t)b*Cd + c0 + c)*1024 + s0 + tx] = t[tx][c];
  }
}

// ---------- tiled GEMM (m97 structure) ----------
// epi: 0 = f32 store, 1 = bf16 store, 2 = silu -> bf16 store
struct GemmDesc {
  const unsigned short* A; const unsigned short* B; void* out; const float* bias;
  int M, N, K, lda, ldb, ldo, epi;
  long long Ay, Az, By, Bz, Oy, Oz;
};

template<int BM, int BN>
__global__ __launch_bounds__(256) void gemm_tile_kernel(GemmDesc d) {
  constexpr int WGM = (BN >= 128) ? 2 : 4;
  constexpr int WGN = 4 / WGM;
  constexpr int MT = BM / (16 * WGM);
  constexpr int NT = BN / (16 * WGN);
  constexpr int AIT = (BM * 4) / 256;
  constexpr int BIT = (BN * 4) / 256;
  __shared__ __align__(16) unsigned short As[BM * 32];
  __shared__ __align__(16) unsigned short Bs[BN * 32];

  int ntx = d.N / BN;
  int bm0 = (blockIdx.x / ntx) * BM, bn0 = (blockIdx.x % ntx) * BN;
  const unsigned short* A = d.A + (long long)blockIdx.y * d.Ay
      + (long long)blockIdx.z * d.Az + (size_t)bm0 * d.lda;
  const unsigned short* B = d.B + (long long)blockIdx.y * d.By
      + (long long)blockIdx.z * d.Bz + (size_t)bn0 * d.ldb;
  int tid = threadIdx.x, lane = tid & 63, w = tid >> 6;
  int wm = (WGN == 2) ? (w >> 1) : w;
  int wn = (WGN == 2) ? (w & 1) : 0;
  int ln = lane & 15, qd = lane >> 4;

  v4f acc[MT][NT];
#pragma unroll
  for (int i = 0; i < MT; ++i)
#pragma unroll
    for (int j = 0; j < NT; ++j) acc[i][j] = (v4f){0.f, 0.f, 0.f, 0.f};

  int nks = d.K >> 5;
  for (int ks = 0; ks < nks; ++ks) {
    int kof = ks * 32;
#pragma unroll
    for (int it = 0; it < AIT; ++it) {
      int c = it * 256 + tid;
      async16(A + (size_t)(c >> 2) * d.lda + (c & 3) * 8 + kof,
              As + (it * 256 + w * 64) * 8);
    }
#pragma unroll
    for (int it = 0; it < BIT; ++it) {
      int c = it * 256 + tid;
      async16(B + (size_t)(c >> 2) * d.ldb + (c & 3) * 8 + kof,
              Bs + (it * 256 + w * 64) * 8);
    }
    __syncthreads();
    v8bf af[MT], bfr[NT];
#pragma unroll
    for (int i = 0; i < MT; ++i)
      af[i] = *(const v8bf*)(As + (wm * MT * 16 + i * 16 + ln) * 32 + qd * 8);
#pragma unroll
    for (int j = 0; j < NT; ++j)
      bfr[j] = *(const v8bf*)(Bs + (wn * NT * 16 + j * 16 + ln) * 32 + qd * 8);
#pragma unroll
    for (int i = 0; i < MT; ++i)
#pragma unroll
      for (int j = 0; j < NT; ++j)
        acc[i][j] = __builtin_amdgcn_mfma_f32_16x16x32_bf16(af[i], bfr[j], acc[i][j], 0, 0, 0);
    __syncthreads();
  }

  size_t obase = (size_t)((long long)blockIdx.y * d.Oy + (long long)blockIdx.z * d.Oz);
#pragma unroll
  for (int i = 0; i < MT; ++i) {
#pragma unroll
    for (int j = 0; j < NT; ++j) {
      int col = bn0 + wn * NT * 16 + j * 16 + ln;
      float bia = d.bias ? d.bias[col] : 0.0f;
#pragma unroll
      for (int r = 0; r < 4; ++r) {
        int row = bm0 + wm * MT * 16 + i * 16 + qd * 4 + r;
        float v = acc[i][j][r] + bia;
        if (d.epi == 2) v = v * sigm(v);
        size_t oi = obase + (size_t)row * d.ldo + col;
        if (d.epi == 0) ((float*)d.out)[oi] = v;
        else ((unsigned short*)d.out)[oi] = f2bf(v);
      }
    }
  }
}

// ---------- flash attention, std MHSA: D=64, S=1024, online softmax ----------
// grid (qt=8, h=8, b=8), 256 thr. Q from QKV[:, h*64:], K from QKV[:, 512+h*64:],
// Vt from VTB (b, 512, 1024). out -> COMB[:, h*64:] (ldo 1024).
__global__ __launch_bounds__(256) void flash_attn_kernel(
    const unsigned short* __restrict__ QKV, const unsigned short* __restrict__ VTB,
    unsigned short* __restrict__ out) {
  __shared__ __align__(16) unsigned short Ks[128*64];
  __shared__ __align__(16) unsigned short Vts[64*128];
  __shared__ __align__(16) unsigned short Pw[4][32*128];
  int qt = blockIdx.x, h = blockIdx.y, b = blockIdx.z;
  int tid = threadIdx.x, lane = tid & 63, w = tid >> 6;
  int ln = lane & 15, qd = lane >> 4;

  const unsigned short* Qbase = QKV + ((size_t)(b*1024 + qt*128 + w*32))*1536 + h*64;
  v8bf aq[2][2];
#pragma unroll
  for (int i = 0; i < 2; ++i)
#pragma unroll
    for (int s = 0; s < 2; ++s)
      aq[i][s] = *(const v8bf*)(Qbase + (size_t)(i*16 + ln)*1536 + s*32 + qd*8);

  v4f o_acc[2][4];
  float m_run[2][4], l_run[2][4];
#pragma unroll
  for (int i = 0; i < 2; ++i) {
#pragma unroll
    for (int dn = 0; dn < 4; ++dn) o_acc[i][dn] = (v4f){0.f,0.f,0.f,0.f};
#pragma unroll
    for (int r = 0; r < 4; ++r) { m_run[i][r] = -1e30f; l_run[i][r] = 0.f; }
  }

  const unsigned short* Kg = QKV + 512 + (size_t)(b*1024)*1536 + h*64;
  const unsigned short* Vg = VTB + ((size_t)(b*512) + h*64)*1024;

  for (int kt = 0; kt < 8; ++kt) {
#pragma unroll
    for (int it = 0; it < 4; ++it) {         // K tile: 128x64 = 1024 chunks
      int c = it*256 + tid;
      async16(Kg + (size_t)(kt*128 + (c >> 3))*1536 + (c & 7)*8,
              Ks + (it*256 + w*64)*8);
    }
#pragma unroll
    for (int it = 0; it < 4; ++it) {         // Vt tile: 64x128 = 1024 chunks
      int c = it*256 + tid;
      async16(Vg + (size_t)(c >> 4)*1024 + kt*128 + (c & 15)*8,
              Vts + (it*256 + w*64)*8);
    }
    __syncthreads();

#pragma unroll
    for (int i = 0; i < 2; ++i) {
      v4f sc[8];
#pragma unroll
      for (int n = 0; n < 8; ++n) {
        v4f a = (v4f){0.f,0.f,0.f,0.f};
#pragma unroll
        for (int s = 0; s < 2; ++s) {
          v8bf kb = *(const v8bf*)(Ks + (n*16 + ln)*64 + s*32 + qd*8);
          a = __builtin_amdgcn_mfma_f32_16x16x32_bf16(aq[i][s], kb, a, 0, 0, 0);
        }
        sc[n] = a;
      }
#pragma unroll
      for (int r = 0; r < 4; ++r) {
        float mx = -1e30f;
#pragma unroll
        for (int n = 0; n < 8; ++n) mx = fmaxf(mx, sc[n][r]);
#pragma unroll
        for (int o = 1; o < 16; o <<= 1) mx = fmaxf(mx, __shfl_xor(mx, o));
        float mn = fmaxf(m_run[i][r], mx);
        float alpha = __expf(m_run[i][r] - mn);
        m_run[i][r] = mn;
        float rsum = 0.f;
#pragma unroll
        for (int n = 0; n < 8; ++n) {
          float p = __expf(sc[n][r] - mn);
          sc[n][r] = p; rsum += p;
        }
#pragma unroll
        for (int o = 1; o < 16; o <<= 1) rsum += __shfl_xor(rsum, o);
        l_run[i][r] = l_run[i][r]*alpha + rsum;
#pragma unroll
        for (int dn = 0; dn < 4; ++dn) o_acc[i][dn][r] *= alpha;
#pragma unroll
        for (int n = 0; n < 8; ++n)
          Pw[w][(i*16 + qd*4 + r)*128 + n*16 + ln] = f2bf(sc[n][r]);
      }
    }
    // PV: O += P * V   (P from per-wave LDS in A-layout, Vt as B-operand)
#pragma unroll
    for (int i = 0; i < 2; ++i)
#pragma unroll
      for (int dn = 0; dn < 4; ++dn) {
        v4f a = o_acc[i][dn];
#pragma unroll
        for (int ks2 = 0; ks2 < 4; ++ks2) {
          v8bf pf = *(const v8bf*)(&Pw[w][(i*16 + ln)*128 + ks2*32 + qd*8]);
          v8bf vf = *(const v8bf*)(Vts + (dn*16 + ln)*128 + ks2*32 + qd*8);
          a = __builtin_amdgcn_mfma_f32_16x16x32_bf16(pf, vf, a, 0, 0, 0);
        }
        o_acc[i][dn] = a;
      }
    __syncthreads();
  }

  unsigned short* ob = out + ((size_t)(b*1024 + qt*128 + w*32))*1024 + h*64;
#pragma unroll
  for (int i = 0; i < 2; ++i)
#pragma unroll
    for (int r = 0; r < 4; ++r) {
      float rinv = 1.0f / l_run[i][r];
#pragma unroll
      for (int dn = 0; dn < 4; ++dn)
        ob[(size_t)(i*16 + qd*4 + r)*1024 + dn*16 + ln] = f2bf(o_acc[i][dn][r] * rinv);
    }
}

// ---------- row softmax over bf16 logits: (nrows,1024) -> P bf16 ----------
__global__ __launch_bounds__(256) void softmax_bf16_kernel(
    const unsigned short* __restrict__ S, unsigned short* __restrict__ P, int nrows) {
  int row = blockIdx.x * 4 + (threadIdx.x >> 6);
  if (row >= nrows) return;
  int l = threadIdx.x & 63;
  const ushort4* sp = (const ushort4*)(S + (size_t)row * 1024);
  float v[16];
  float m = -1e30f;
#pragma unroll
  for (int t = 0; t < 4; ++t) {
    ushort4 u = sp[t*64 + l];
    v[t*4+0] = bf2f(u.x); v[t*4+1] = bf2f(u.y); v[t*4+2] = bf2f(u.z); v[t*4+3] = bf2f(u.w);
    m = fmaxf(m, fmaxf(fmaxf(v[t*4], v[t*4+1]), fmaxf(v[t*4+2], v[t*4+3])));
  }
#pragma unroll
  for (int o = 32; o; o >>= 1) m = fmaxf(m, __shfl_xor(m, o));
  float sum = 0.f;
#pragma unroll
  for (int t = 0; t < 16; ++t) { v[t] = __expf(v[t] - m); sum += v[t]; }
#pragma unroll
  for (int o = 32; o; o >>= 1) sum += __shfl_xor(sum, o);
  float r = 1.0f / sum;
  ushort4* p = (ushort4*)(P + (size_t)row * 1024);
#pragma unroll
  for (int t = 0; t < 4; ++t)
    p[t*64 + l] = make_ushort4(f2bf(v[t*4]*r), f2bf(v[t*4+1]*r), f2bf(v[t*4+2]*r), f2bf(v[t*4+3]*r));
}

// ---------- stats over (B,S,C) f32 per (b,group) ----------
__global__ __launch_bounds__(256) void gn_stats_bsc_kernel(
    const float* __restrict__ t, float* __restrict__ stats) {
  int b = blockIdx.x >> 5, grp = blockIdx.x & 31;
  int i4 = threadIdx.x & 3, s0 = threadIdx.x >> 2;
  float s = 0.f, s2 = 0.f;
  for (int j = 0; j < 16; ++j) {
    int sI = s0 + j*64;
    float4 v = *(const float4*)(t + ((size_t)(b*1024 + sI)*512 + grp*16 + i4*4));
    s += v.x + v.y + v.z + v.w;
    s2 += v.x*v.x + v.y*v.y + v.z*v.z + v.w*v.w;
  }
#pragma unroll
  for (int o = 32; o; o >>= 1) { s += __shfl_xor(s, o); s2 += __shfl_xor(s2, o); }
  __shared__ float rs[4], rs2[4];
  int w = threadIdx.x >> 6;
  if ((threadIdx.x & 63) == 0) { rs[w] = s; rs2[w] = s2; }
  __syncthreads();
  if (threadIdx.x == 0) {
    float ts = rs[0]+rs[1]+rs[2]+rs[3], ts2 = rs2[0]+rs2[1]+rs2[2]+rs2[3];
    float mu = ts * (1.0f/16384.0f);
    float var = ts2 * (1.0f/16384.0f) - mu*mu;
    stats[(b*32+grp)*2] = mu; stats[(b*32+grp)*2+1] = rsqrtf(var + 1e-6f);
  }
}

// ---------- GN(post) + residual, (B,S,C) -> (B,C,S) ----------
__global__ __launch_bounds__(256) void final_out_kernel(
    const float* __restrict__ fin, const float* __restrict__ stats,
    const float* __restrict__ g, const float* __restrict__ be,
    const float* __restrict__ x, float* __restrict__ out) {
  int c = blockIdx.x, b = blockIdx.y;
  int grp = c >> 4;
  float mu = stats[(b*32+grp)*2], rstd = stats[(b*32+grp)*2+1];
  float gg = g[c], bb = be[c];
  size_t obase = ((size_t)b*512 + c)*1024;
  for (int s = threadIdx.x; s < 1024; s += 256) {
    float v = fin[((size_t)(b*1024) + s)*512 + c];
    out[obase + s] = (v - mu)*rstd*gg + bb + x[obase + s];
  }
}

// =====================================================================
static void launch_gemm128(hipStream_t st, const unsigned short* A, const unsigned short* B,
                           void* out, const float* bias,
                           int M, int N, int K, int lda, int ldb, int ldo, int epi,
                           long long Ay, long long Az, long long By, long long Bz,
                           long long Oy, long long Oz, int gy, int gz) {
  GemmDesc d{A, B, out, bias, M, N, K, lda, ldb, ldo, epi, Ay, Az, By, Bz, Oy, Oz};
  gemm_tile_kernel<128,128><<<dim3((M/128)*(N/128), gy, gz), dim3(256), 0, st>>>(d);
}
static void launch_gemm64(hipStream_t st, const unsigned short* A, const unsigned short* B,
                          void* out, const float* bias,
                          int M, int N, int K, int lda, int ldb, int ldo, int epi) {
  GemmDesc d{A, B, out, bias, M, N, K, lda, ldb, ldo, epi, 0,0,0,0,0,0};
  gemm_tile_kernel<128,64><<<dim3((M/128)*(N/64), 1, 1), dim3(256), 0, st>>>(d);
}

extern "C" void kernel_launch(void* const* d_in, const int* in_sizes, int n_in,
                              void* d_out, int out_size, void* d_ws, size_t ws_size,
                              hipStream_t stream) {
  const float* x      = (const float*)d_in[0];
  const float* pre_g  = (const float*)d_in[1];
  const float* pre_b  = (const float*)d_in[2];
  const float* norm_g = (const float*)d_in[3];
  const float* norm_b = (const float*)d_in[4];
  const float* post_g = (const float*)d_in[5];
  const float* post_b = (const float*)d_in[6];
  const float* pos    = (const float*)d_in[7];
  const float* sa_b1  = (const float*)d_in[9];
  const float* sa_w2  = (const float*)d_in[10];
  const float* sa_b2  = (const float*)d_in[11];
  const float* sa_w3  = (const float*)d_in[12];
  const float* sa_b3  = (const float*)d_in[13];
  const float* ff_b1  = (const float*)d_in[24];
  const float* ff_b2  = (const float*)d_in[26];
  const float* out_b  = (const float*)d_in[28];
  float* outp = (float*)d_out;

  char* ws = (char*)d_ws;
  size_t off = 0;
  auto alloc = [&](size_t bytes) -> void* {
    void* p = ws + off; off += (bytes + 255) & ~(size_t)255; return p;
  };
  float* HS    = (float*)alloc(16777216);          // (B,512,1024) f32
  float* SW    = (float*)alloc(32768);             // gate
  float* STATS = (float*)alloc(4096);
  unsigned short* HSB  = (unsigned short*)alloc(8388608);   // (B*S,512) hs bf16
  unsigned short* A1   = (unsigned short*)alloc(1048576);   // (B*S,64)
  unsigned short* IM2  = (unsigned short*)alloc(9437184);   // (B*S,576)
  unsigned short* A2   = (unsigned short*)alloc(1048576);   // (B*S,64)
  unsigned short* SHB  = (unsigned short*)alloc(8388608);   // normed
  unsigned short* MSHB = (unsigned short*)alloc(8388608);   // gated
  unsigned short* WBF  = (unsigned short*)alloc(6291456);   // packed bf16 weights
  unsigned short* QKV  = (unsigned short*)alloc(25165824);  // (B*S,1536)
  unsigned short* QM   = (unsigned short*)alloc(8388608);   // (B*S,512)
  unsigned short* KVM  = (unsigned short*)alloc(16777216);  // (B*S,1024)
  unsigned short* VTB  = (unsigned short*)alloc(8388608);   // (B,512,1024) V^T
  unsigned short* VMT  = (unsigned short*)alloc(8388608);   // (B,512,1024) [V0|V1]^T
  unsigned short* SBUF = (unsigned short*)alloc(16777216);  // branch scores bf16
  unsigned short* PBUF = (unsigned short*)alloc(16777216);  // branch probs bf16
  unsigned short* COMB = (unsigned short*)alloc(16777216);  // (B*S,1024)
  unsigned short* FFMID= (unsigned short*)alloc(8388608);
  unsigned short* FUSED= (unsigned short*)alloc(8388608);
  float* FINAL = (float*)alloc(16777216);

  // WBF element offsets
  const int OQKV=0, OQM=786432, OKVM=1048576, OFF1=1572864, OFF2=2097152,
            OOW=2359296, OW1=2621440, OW2R=2654208;

  // 1) GN(pre)+pos -> HS, fused GN(norm) stats
  gn_pre_kernel<<<dim3(256), dim3(256), 0, stream>>>(x, pre_g, pre_b, pos, HS, STATS);
  // 2) weights -> bf16 (attention scales folded into Q weights)
  {
    WCvtArgs a;
    const int   srcIdx[13] = {14,15,16,17,20,18,21,19,22,23,25,27,8};
    const int   dofs[13]   = {OQKV, OQKV+262144, OQKV+524288,
                              OQM, OQM+131072,
                              OKVM, OKVM+131072, OKVM+262144, OKVM+393216,
                              OFF1, OFF2, OOW, OW1};
    const int   ns[13]     = {262144,262144,262144,131072,131072,131072,131072,131072,131072,524288,262144,262144,32768};
    const float sc[13]     = {0.125f,1.f,1.f,0.0625f,0.0625f,1.f,1.f,1.f,1.f,1.f,1.f,1.f,1.f};
    for (int i = 0; i < 13; ++i) { a.w[i].src = (const float*)d_in[srcIdx[i]]; a.w[i].dstOff = dofs[i]; a.w[i].n = ns[i]; a.w[i].scale = sc[i]; }
    wconvert_kernel<<<dim3(2048, 13), dim3(256), 0, stream>>>(a, WBF);
  }
  w2reorder_kernel<<<dim3(144), dim3(256), 0, stream>>>(sa_w2, WBF + OW2R);
  // 3) HS -> HSB bf16 token-major
  hs_to_bsc_kernel<<<dim3(256, 8), dim3(256), 0, stream>>>(HS, HSB);
  // 4) spatial gate chain as GEMMs
  launch_gemm64(stream, HSB, WBF+OW1,  A1, sa_b1, 8192, 64, 512, 512, 512, 64, 2);
  im2col_kernel<<<dim3(1024), dim3(256), 0, stream>>>(A1, IM2);
  launch_gemm64(stream, IM2, WBF+OW2R, A2, sa_b2, 8192, 64, 576, 576, 576, 64, 2);
  conv3_kernel<<<dim3(32), dim3(256), 0, stream>>>(A2, sa_w3, sa_b3, SW);
  // 5) gate + norm
  gate_norm_kernel<<<dim3(256, 8), dim3(256), 0, stream>>>(HSB, SW, STATS, norm_g, norm_b, SHB, MSHB);

  // 6) fused projections
  launch_gemm128(stream, SHB,  WBF+OQKV, QKV, nullptr, 8192, 1536, 512, 512, 512, 1536, 1, 0,0,0,0,0,0, 1,1);
  launch_gemm128(stream, MSHB, WBF+OQM,  QM,  nullptr, 8192, 512,  512, 512, 512, 512,  1, 0,0,0,0,0,0, 1,1);
  launch_gemm128(stream, SHB,  WBF+OKVM, KVM, nullptr, 8192, 1024, 512, 512, 512, 1024, 1, 0,0,0,0,0,0, 1,1);

  // 7) V transposes
  transpose_tile_kernel<<<dim3(16, 8, 8), dim3(256), 0, stream>>>(QKV, VTB, 1536, 1024);
  transpose_tile_kernel<<<dim3(16, 8, 8), dim3(256), 0, stream>>>(KVM, VMT, 1024, 512);

  // 8) std MHSA: single fused flash kernel -> COMB[:, 0:512]
  flash_attn_kernel<<<dim3(8, 8, 8), dim3(256), 0, stream>>>(QKV, VTB, COMB);

  // 9) two multi-scale branches (bf16 scores)
  for (int br = 0; br < 2; ++br) {
    launch_gemm128(stream, QM + br*256, KVM + br*256, SBUF, nullptr,
                   1024, 1024, 256, 512, 1024, 1024, 1,
                   1024LL*512, 0, 1024LL*1024, 0, 1024LL*1024, 0, 8, 1);
    softmax_bf16_kernel<<<dim3(2048), dim3(256), 0, stream>>>(SBUF, PBUF, 8192);
    launch_gemm128(stream, PBUF, VMT + (size_t)br*256*1024, COMB + 512 + br*256, nullptr,
                   1024, 256, 1024, 1024, 1024, 1024, 1,
                   1024LL*1024, 0, 512LL*1024, 0, 1024LL*1024, 0, 8, 1);
  }

  // 10) FF + out projection
  launch_gemm128(stream, COMB,  WBF+OFF1, FFMID, ff_b1, 8192, 512, 1024, 1024, 1024, 512, 2, 0,0,0,0,0,0, 1,1);
  launch_gemm128(stream, FFMID, WBF+OFF2, FUSED, ff_b2, 8192, 512, 512,  512,  512,  512, 1, 0,0,0,0,0,0, 1,1);
  launch_gemm128(stream, FUSED, WBF+OOW,  FINAL, out_b, 8192, 512, 512,  512,  512,  512, 0, 0,0,0,0,0,0, 1,1);

  // 11) GN(post) + residual
  gn_stats_bsc_kernel<<<dim3(256), dim3(256), 0, stream>>>(FINAL, STATS);
  final_out_kernel<<<dim3(512, 8), dim3(256), 0, stream>>>(FINAL, STATS, post_g, post_b, x, outp);

  (void)in_sizes; (void)n_in; (void)out_size; (void)ws_size;
}

// Round 4
// 499.840 us; speedup vs baseline: 3.2390x; 1.1500x over previous
//
#include <hip/hip_runtime.h>
#include <hip/hip_bf16.h>
#include <math.h>

typedef __attribute__((ext_vector_type(8))) __bf16 v8bf;
typedef __attribute__((ext_vector_type(4))) float v4f;

__device__ __forceinline__ unsigned short f2bf(float f) {
  union { float f; unsigned int u; } a; a.f = f;
  unsigned int r = a.u + 0x7fffu + ((a.u >> 16) & 1u);
  return (unsigned short)(r >> 16);
}
__device__ __forceinline__ float bf2f(unsigned short u) {
  union { unsigned int i; float f; } a; a.i = ((unsigned int)u) << 16; return a.f;
}
__device__ __forceinline__ float sigm(float x) { return 1.0f / (1.0f + __expf(-x)); }

__device__ __forceinline__ void async16(const void* g, void* l) {
  __builtin_amdgcn_global_load_lds(
      (const __attribute__((address_space(1))) unsigned int*)g,
      (__attribute__((address_space(3))) unsigned int*)l, 16, 0, 0);
}

// ---------- GN(pre) + pos -> hs f32 (B,512,1024); fused GN(norm) stats ----------
__global__ __launch_bounds__(256) void gn_pre_kernel(
    const float* __restrict__ x, const float* __restrict__ g, const float* __restrict__ be,
    const float* __restrict__ pos, float* __restrict__ hs, float* __restrict__ stats) {
  int b = blockIdx.x >> 5, grp = blockIdx.x & 31;
  const float4* base = (const float4*)(x + ((size_t)b*512 + grp*16)*1024);
  float s = 0.f, s2 = 0.f;
  for (int i = threadIdx.x; i < 4096; i += 256) {
    float4 v = base[i];
    s += v.x + v.y + v.z + v.w;
    s2 += v.x*v.x + v.y*v.y + v.z*v.z + v.w*v.w;
  }
#pragma unroll
  for (int o = 32; o; o >>= 1) { s += __shfl_xor(s, o); s2 += __shfl_xor(s2, o); }
  __shared__ float rs[4], rs2[4], mr[2];
  int w = threadIdx.x >> 6;
  if ((threadIdx.x & 63) == 0) { rs[w] = s; rs2[w] = s2; }
  __syncthreads();
  if (threadIdx.x == 0) {
    float ts = rs[0]+rs[1]+rs[2]+rs[3], ts2 = rs2[0]+rs2[1]+rs2[2]+rs2[3];
    float mu = ts * (1.0f/16384.0f);
    float var = ts2 * (1.0f/16384.0f) - mu*mu;
    mr[0] = mu; mr[1] = rsqrtf(var + 1e-6f);
  }
  __syncthreads();
  float mu = mr[0], rstd = mr[1];
  const float4* pb = (const float4*)(pos + (size_t)grp*16*1024);
  float4* ob = (float4*)(hs + ((size_t)b*512 + grp*16)*1024);
  float ns = 0.f, ns2 = 0.f;
  for (int i = threadIdx.x; i < 4096; i += 256) {
    float4 v = base[i], p = pb[i];
    int c = grp*16 + (i >> 8);
    float gg = g[c], bb = be[c];
    float4 o;
    o.x = (v.x - mu)*rstd*gg + bb + p.x;
    o.y = (v.y - mu)*rstd*gg + bb + p.y;
    o.z = (v.z - mu)*rstd*gg + bb + p.z;
    o.w = (v.w - mu)*rstd*gg + bb + p.w;
    ob[i] = o;
    ns += o.x + o.y + o.z + o.w;
    ns2 += o.x*o.x + o.y*o.y + o.z*o.z + o.w*o.w;
  }
#pragma unroll
  for (int o = 32; o; o >>= 1) { ns += __shfl_xor(ns, o); ns2 += __shfl_xor(ns2, o); }
  if ((threadIdx.x & 63) == 0) { rs[w] = ns; rs2[w] = ns2; }
  __syncthreads();
  if (threadIdx.x == 0) {
    float ts = rs[0]+rs[1]+rs[2]+rs[3], ts2 = rs2[0]+rs2[1]+rs2[2]+rs2[3];
    float nmu = ts * (1.0f/16384.0f);
    float nvar = ts2 * (1.0f/16384.0f) - nmu*nmu;
    stats[(b*32+grp)*2] = nmu; stats[(b*32+grp)*2+1] = rsqrtf(nvar + 1e-6f);
  }
}

// ---------- HS f32 ch-major -> HSB bf16 token-major (LDS-tiled transpose) ----------
__global__ __launch_bounds__(256) void hs_to_bsc_kernel(
    const float* __restrict__ hs, unsigned short* __restrict__ hsb) {
  __shared__ float t[64][65];
  int s0 = blockIdx.x * 64, c0 = blockIdx.y * 64, b = blockIdx.z;
  int tx = threadIdx.x & 63, ty = threadIdx.x >> 6;
#pragma unroll
  for (int i = 0; i < 16; ++i) {
    int c = ty + i*4;
    t[c][tx] = hs[((size_t)(b*512 + c0 + c))*1024 + s0 + tx];
  }
  __syncthreads();
#pragma unroll
  for (int i = 0; i < 16; ++i) {
    int s = ty + i*4;
    hsb[((size_t)(b*1024 + s0 + s))*512 + c0 + tx] = f2bf(t[tx][s]);
  }
}

// ---------- im2col: A1 (B*S,64) bf16 -> IM2 (B*S,576) bf16 ----------
__global__ __launch_bounds__(256) void im2col_kernel(
    const unsigned short* __restrict__ a1, unsigned short* __restrict__ im2) {
  int row0 = blockIdx.x * 8;
#pragma unroll
  for (int it = 0; it < 3; ++it) {
    int cc = it*256 + threadIdx.x;
    if (cc >= 576) break;
    int rl = cc / 72, rr = cc - rl*72;
    int tap = rr >> 3, ch8 = rr & 7;
    int row = row0 + rl;
    int bb = row >> 10, s = row & 1023;
    int y = s >> 5, xx0 = s & 31;
    int yy = y + tap/3 - 1, xx = xx0 + tap%3 - 1;
    ushort4 v0 = make_ushort4(0,0,0,0), v1 = make_ushort4(0,0,0,0);
    if ((unsigned)yy < 32u && (unsigned)xx < 32u) {
      const unsigned short* src = a1 + ((size_t)(bb*1024 + yy*32 + xx))*64 + ch8*8;
      v0 = *(const ushort4*)src; v1 = *(const ushort4*)(src + 4);
    }
    unsigned short* dst = im2 + (size_t)row*576 + tap*64 + ch8*8;
    *(ushort4*)dst = v0; *(ushort4*)(dst + 4) = v1;
  }
}

// ---------- conv3: A2 (B*S,64) bf16 -> SW sigmoid gate f32 ----------
__global__ __launch_bounds__(256) void conv3_kernel(
    const unsigned short* __restrict__ a2, const float* __restrict__ w,
    const float* __restrict__ bias, float* __restrict__ swp) {
  int row = blockIdx.x * 256 + threadIdx.x;
  const unsigned short* ar = a2 + (size_t)row*64;
  float acc = bias[0];
#pragma unroll
  for (int ic = 0; ic < 64; ic += 4) {
    ushort4 u = *(const ushort4*)(ar + ic);
    acc += bf2f(u.x)*w[ic] + bf2f(u.y)*w[ic+1] + bf2f(u.z)*w[ic+2] + bf2f(u.w)*w[ic+3];
  }
  swp[row] = sigm(acc);
}

// ---------- gate + GN(norm): HSB -> SHB (normed), MSHB (gated) ----------
__global__ __launch_bounds__(256) void gate_norm_kernel(
    const unsigned short* __restrict__ hsb, const float* __restrict__ swp,
    const float* __restrict__ stats, const float* __restrict__ g,
    const float* __restrict__ be,
    unsigned short* __restrict__ sh, unsigned short* __restrict__ msh) {
  int b = blockIdx.y;
  int s = blockIdx.x * 4 + (threadIdx.x >> 6);
  int c0 = (threadIdx.x & 63) * 8;
  int grp = c0 >> 4;
  float mu = stats[(b*32 + grp)*2], rstd = stats[(b*32 + grp)*2 + 1];
  float wgt = swp[b*1024 + s];
  size_t o = (size_t)(b*1024 + s)*512 + c0;
  ushort4 u0 = *(const ushort4*)(hsb + o), u1 = *(const ushort4*)(hsb + o + 4);
  unsigned short uu[8] = {u0.x,u0.y,u0.z,u0.w,u1.x,u1.y,u1.z,u1.w};
  unsigned short so[8], mo[8];
#pragma unroll
  for (int j = 0; j < 8; ++j) {
    float v = bf2f(uu[j]);
    so[j] = f2bf((v - mu)*rstd*g[c0+j] + be[c0+j]);
    mo[j] = f2bf(v * wgt);
  }
  *(ushort4*)(sh + o)     = make_ushort4(so[0], so[1], so[2], so[3]);
  *(ushort4*)(sh + o + 4) = make_ushort4(so[4], so[5], so[6], so[7]);
  *(ushort4*)(msh + o)     = make_ushort4(mo[0], mo[1], mo[2], mo[3]);
  *(ushort4*)(msh + o + 4) = make_ushort4(mo[4], mo[5], mo[6], mo[7]);
}

// ---------- weight f32 -> bf16 convert with scale ----------
struct WCvt { const float* src; int dstOff; int n; float scale; };
struct WCvtArgs { WCvt w[13]; };
__global__ __launch_bounds__(256) void wconvert_kernel(WCvtArgs a, unsigned short* __restrict__ dst) {
  WCvt e = a.w[blockIdx.y];
  int i = blockIdx.x * 256 + threadIdx.x;
  if (i < e.n) dst[e.dstOff + i] = f2bf(e.src[i] * e.scale);
}

// ---------- conv2 weight reorder: OIHW (64,64,3,3) -> (oc, tap*64+ic) bf16 ----------
__global__ __launch_bounds__(256) void w2reorder_kernel(
    const float* __restrict__ w2, unsigned short* __restrict__ dst) {
  int e = blockIdx.x * 256 + threadIdx.x;
  if (e >= 36864) return;
  int oc = e / 576, r = e - oc*576;
  int tap = r >> 6, ic = r & 63;
  dst[e] = f2bf(w2[(oc*64 + ic)*9 + tap]);
}

// ---------- LDS-tiled bf16 transpose: in (B*1024, ldin) cols [colOff,+Cd) -> out (B,Cd,1024)
__global__ __launch_bounds__(256) void transpose_tile_kernel(
    const unsigned short* __restrict__ in, unsigned short* __restrict__ out,
    int ldin, int colOff) {
  __shared__ unsigned short t[64][65];
  int s0 = blockIdx.x * 64, c0 = blockIdx.y * 64, b = blockIdx.z;
  int Cd = gridDim.y * 64;
  int tx = threadIdx.x & 63, ty = threadIdx.x >> 6;
#pragma unroll
  for (int i = 0; i < 16; ++i) {
    int s = ty + i*4;
    t[s][tx] = in[((size_t)(b*1024 + s0 + s))*ldin + colOff + c0 + tx];
  }
  __syncthreads();
#pragma unroll
  for (int i = 0; i < 16; ++i) {
    int c = ty + i*4;
    out[((size_t)b*Cd + c0 + c)*1024 + s0 + tx] = t[tx][c];
  }
}

// ---------- tiled GEMM (m97 structure) ----------
// epi: 0 = f32 store, 1 = bf16 store, 2 = silu -> bf16 store
struct GemmDesc {
  const unsigned short* A; const unsigned short* B; void* out; const float* bias;
  int M, N, K, lda, ldb, ldo, epi;
  long long Ay, Az, By, Bz, Oy, Oz;
};

template<int BM, int BN>
__global__ __launch_bounds__(256) void gemm_tile_kernel(GemmDesc d) {
  constexpr int WGM = (BN >= 128) ? 2 : 4;
  constexpr int WGN = 4 / WGM;
  constexpr int MT = BM / (16 * WGM);
  constexpr int NT = BN / (16 * WGN);
  constexpr int AIT = (BM * 4) / 256;
  constexpr int BIT = (BN * 4) / 256;
  __shared__ __align__(16) unsigned short As[BM * 32];
  __shared__ __align__(16) unsigned short Bs[BN * 32];

  int ntx = d.N / BN;
  int bm0 = (blockIdx.x / ntx) * BM, bn0 = (blockIdx.x % ntx) * BN;
  const unsigned short* A = d.A + (long long)blockIdx.y * d.Ay
      + (long long)blockIdx.z * d.Az + (size_t)bm0 * d.lda;
  const unsigned short* B = d.B + (long long)blockIdx.y * d.By
      + (long long)blockIdx.z * d.Bz + (size_t)bn0 * d.ldb;
  int tid = threadIdx.x, lane = tid & 63, w = tid >> 6;
  int wm = (WGN == 2) ? (w >> 1) : w;
  int wn = (WGN == 2) ? (w & 1) : 0;
  int ln = lane & 15, qd = lane >> 4;

  v4f acc[MT][NT];
#pragma unroll
  for (int i = 0; i < MT; ++i)
#pragma unroll
    for (int j = 0; j < NT; ++j) acc[i][j] = (v4f){0.f, 0.f, 0.f, 0.f};

  int nks = d.K >> 5;
  for (int ks = 0; ks < nks; ++ks) {
    int kof = ks * 32;
#pragma unroll
    for (int it = 0; it < AIT; ++it) {
      int c = it * 256 + tid;
      async16(A + (size_t)(c >> 2) * d.lda + (c & 3) * 8 + kof,
              As + (it * 256 + w * 64) * 8);
    }
#pragma unroll
    for (int it = 0; it < BIT; ++it) {
      int c = it * 256 + tid;
      async16(B + (size_t)(c >> 2) * d.ldb + (c & 3) * 8 + kof,
              Bs + (it * 256 + w * 64) * 8);
    }
    __syncthreads();
    v8bf af[MT], bfr[NT];
#pragma unroll
    for (int i = 0; i < MT; ++i)
      af[i] = *(const v8bf*)(As + (wm * MT * 16 + i * 16 + ln) * 32 + qd * 8);
#pragma unroll
    for (int j = 0; j < NT; ++j)
      bfr[j] = *(const v8bf*)(Bs + (wn * NT * 16 + j * 16 + ln) * 32 + qd * 8);
#pragma unroll
    for (int i = 0; i < MT; ++i)
#pragma unroll
      for (int j = 0; j < NT; ++j)
        acc[i][j] = __builtin_amdgcn_mfma_f32_16x16x32_bf16(af[i], bfr[j], acc[i][j], 0, 0, 0);
    __syncthreads();
  }

  size_t obase = (size_t)((long long)blockIdx.y * d.Oy + (long long)blockIdx.z * d.Oz);
#pragma unroll
  for (int i = 0; i < MT; ++i) {
#pragma unroll
    for (int j = 0; j < NT; ++j) {
      int col = bn0 + wn * NT * 16 + j * 16 + ln;
      float bia = d.bias ? d.bias[col] : 0.0f;
#pragma unroll
      for (int r = 0; r < 4; ++r) {
        int row = bm0 + wm * MT * 16 + i * 16 + qd * 4 + r;
        float v = acc[i][j][r] + bia;
        if (d.epi == 2) v = v * sigm(v);
        size_t oi = obase + (size_t)row * d.ldo + col;
        if (d.epi == 0) ((float*)d.out)[oi] = v;
        else ((unsigned short*)d.out)[oi] = f2bf(v);
      }
    }
  }
}

// ---------- flash attention, std MHSA: D=64, S=1024 ----------
// Fixed-max softmax (logits bounded, scale pre-folded into Q weights), deferred
// row-sum reduction. XOR-swizzled LDS (stride 128B/256B conflicts killed).
// grid (h=8, b=8, qt=8) so same-(b,h) blocks share an XCD's L2 for K/V.
__global__ __launch_bounds__(256) void flash_attn_kernel(
    const unsigned short* __restrict__ QKV, const unsigned short* __restrict__ VTB,
    unsigned short* __restrict__ out) {
  __shared__ __align__(16) unsigned short Ks[128*64];   // swizzled: chunk^ (row&7)
  __shared__ __align__(16) unsigned short Vts[64*128];  // swizzled
  __shared__ __align__(16) unsigned short Pw[4][16*128]; // per-wave, swizzled
  int h = blockIdx.x, b = blockIdx.y, qt = blockIdx.z;
  int tid = threadIdx.x, lane = tid & 63, w = tid >> 6;
  int ln = lane & 15, qd = lane >> 4;

  const unsigned short* Qbase = QKV + ((size_t)(b*1024 + qt*128 + w*32))*1536 + h*64;
  v8bf aq[2][2];
#pragma unroll
  for (int i = 0; i < 2; ++i)
#pragma unroll
    for (int s = 0; s < 2; ++s)
      aq[i][s] = *(const v8bf*)(Qbase + (size_t)(i*16 + ln)*1536 + s*32 + qd*8);

  v4f o_acc[2][4];
  float l_part[2][4];
#pragma unroll
  for (int i = 0; i < 2; ++i)
#pragma unroll
    for (int dn = 0; dn < 4; ++dn) o_acc[i][dn] = (v4f){0.f,0.f,0.f,0.f};
#pragma unroll
  for (int i = 0; i < 2; ++i)
#pragma unroll
    for (int r = 0; r < 4; ++r) l_part[i][r] = 0.f;

  const unsigned short* Kg = QKV + 512 + (size_t)(b*1024)*1536 + h*64;
  const unsigned short* Vg = VTB + ((size_t)(b*512) + h*64)*1024;

  for (int kt = 0; kt < 8; ++kt) {
#pragma unroll
    for (int it = 0; it < 4; ++it) {   // K tile 128x64: phys chunk c&7 holds logical (c&7)^(row&7)
      int c = it*256 + tid;
      async16(Kg + (size_t)(kt*128 + (c >> 3))*1536 + (((c & 7) ^ ((c >> 3) & 7)) << 3),
              Ks + c*8);
    }
#pragma unroll
    for (int it = 0; it < 4; ++it) {   // Vt tile 64x128: phys chunk c&15 holds logical (c&15)^(row&7)
      int c = it*256 + tid;
      async16(Vg + (size_t)(c >> 4)*1024 + kt*128 + ((((c & 15) ^ ((c >> 4) & 7))) << 3),
              Vts + c*8);
    }
    __syncthreads();

#pragma unroll
    for (int i = 0; i < 2; ++i) {
      v4f sc[8];
#pragma unroll
      for (int n = 0; n < 8; ++n) {
        v4f a = (v4f){0.f,0.f,0.f,0.f};
#pragma unroll
        for (int s = 0; s < 2; ++s) {
          v8bf kb = *(const v8bf*)(Ks + (n*16 + ln)*64 + (((s*4 + qd) ^ (ln & 7)) << 3));
          a = __builtin_amdgcn_mfma_f32_16x16x32_bf16(aq[i][s], kb, a, 0, 0, 0);
        }
        sc[n] = a;
      }
#pragma unroll
      for (int r = 0; r < 4; ++r) {
        int row7 = (qd*4 + r) & 7;
        float acc_l = 0.f;
#pragma unroll
        for (int n = 0; n < 8; ++n) {
          float p = __expf(sc[n][r]);
          acc_l += p;
          Pw[w][(qd*4 + r)*128 + (((n*2 + (ln >> 3)) ^ row7) << 3) + (ln & 7)] = f2bf(p);
        }
        l_part[i][r] += acc_l;
      }
      // PV for this i-subtile (Pw per-wave; in-wave DS ordering gives the sync)
#pragma unroll
      for (int dn = 0; dn < 4; ++dn) {
        v4f a = o_acc[i][dn];
#pragma unroll
        for (int ks2 = 0; ks2 < 4; ++ks2) {
          int phys = (((ks2*4 + qd) ^ (ln & 7)) << 3);
          v8bf pf = *(const v8bf*)(&Pw[w][ln*128 + phys]);
          v8bf vf = *(const v8bf*)(Vts + (dn*16 + ln)*128 + phys);
          a = __builtin_amdgcn_mfma_f32_16x16x32_bf16(pf, vf, a, 0, 0, 0);
        }
        o_acc[i][dn] = a;
      }
    }
    __syncthreads();
  }

  unsigned short* ob = out + ((size_t)(b*1024 + qt*128 + w*32))*1024 + h*64;
#pragma unroll
  for (int i = 0; i < 2; ++i)
#pragma unroll
    for (int r = 0; r < 4; ++r) {
      float l = l_part[i][r];
      l += __shfl_xor(l, 1); l += __shfl_xor(l, 2);
      l += __shfl_xor(l, 4); l += __shfl_xor(l, 8);
      float rinv = 1.0f / l;
#pragma unroll
      for (int dn = 0; dn < 4; ++dn)
        ob[(size_t)(i*16 + qd*4 + r)*1024 + dn*16 + ln] = f2bf(o_acc[i][dn][r] * rinv);
    }
}

// ---------- row softmax over bf16 logits: (nrows,1024) -> P bf16 ----------
__global__ __launch_bounds__(256) void softmax_bf16_kernel(
    const unsigned short* __restrict__ S, unsigned short* __restrict__ P, int nrows) {
  int row = blockIdx.x * 4 + (threadIdx.x >> 6);
  if (row >= nrows) return;
  int l = threadIdx.x & 63;
  const ushort4* sp = (const ushort4*)(S + (size_t)row * 1024);
  float v[16];
  float m = -1e30f;
#pragma unroll
  for (int t = 0; t < 4; ++t) {
    ushort4 u = sp[t*64 + l];
    v[t*4+0] = bf2f(u.x); v[t*4+1] = bf2f(u.y); v[t*4+2] = bf2f(u.z); v[t*4+3] = bf2f(u.w);
    m = fmaxf(m, fmaxf(fmaxf(v[t*4], v[t*4+1]), fmaxf(v[t*4+2], v[t*4+3])));
  }
#pragma unroll
  for (int o = 32; o; o >>= 1) m = fmaxf(m, __shfl_xor(m, o));
  float sum = 0.f;
#pragma unroll
  for (int t = 0; t < 16; ++t) { v[t] = __expf(v[t] - m); sum += v[t]; }
#pragma unroll
  for (int o = 32; o; o >>= 1) sum += __shfl_xor(sum, o);
  float r = 1.0f / sum;
  ushort4* p = (ushort4*)(P + (size_t)row * 1024);
#pragma unroll
  for (int t = 0; t < 4; ++t)
    p[t*64 + l] = make_ushort4(f2bf(v[t*4]*r), f2bf(v[t*4+1]*r), f2bf(v[t*4+2]*r), f2bf(v[t*4+3]*r));
}

// ---------- stats over (B,S,C) f32 per (b,group) ----------
__global__ __launch_bounds__(256) void gn_stats_bsc_kernel(
    const float* __restrict__ t, float* __restrict__ stats) {
  int b = blockIdx.x >> 5, grp = blockIdx.x & 31;
  int i4 = threadIdx.x & 3, s0 = threadIdx.x >> 2;
  float s = 0.f, s2 = 0.f;
  for (int j = 0; j < 16; ++j) {
    int sI = s0 + j*64;
    float4 v = *(const float4*)(t + ((size_t)(b*1024 + sI)*512 + grp*16 + i4*4));
    s += v.x + v.y + v.z + v.w;
    s2 += v.x*v.x + v.y*v.y + v.z*v.z + v.w*v.w;
  }
#pragma unroll
  for (int o = 32; o; o >>= 1) { s += __shfl_xor(s, o); s2 += __shfl_xor(s2, o); }
  __shared__ float rs[4], rs2[4];
  int w = threadIdx.x >> 6;
  if ((threadIdx.x & 63) == 0) { rs[w] = s; rs2[w] = s2; }
  __syncthreads();
  if (threadIdx.x == 0) {
    float ts = rs[0]+rs[1]+rs[2]+rs[3], ts2 = rs2[0]+rs2[1]+rs2[2]+rs2[3];
    float mu = ts * (1.0f/16384.0f);
    float var = ts2 * (1.0f/16384.0f) - mu*mu;
    stats[(b*32+grp)*2] = mu; stats[(b*32+grp)*2+1] = rsqrtf(var + 1e-6f);
  }
}

// ---------- GN(post) + residual, (B,S,C) -> (B,C,S), LDS-tiled ----------
__global__ __launch_bounds__(256) void final_out_kernel(
    const float* __restrict__ fin, const float* __restrict__ stats,
    const float* __restrict__ g, const float* __restrict__ be,
    const float* __restrict__ x, float* __restrict__ out) {
  __shared__ float t[64][65];
  int s0 = blockIdx.x * 64, c0 = blockIdx.y * 64, b = blockIdx.z;
  int tx = threadIdx.x & 63, ty = threadIdx.x >> 6;
#pragma unroll
  for (int i = 0; i < 16; ++i) {
    int s = ty + i*4;
    t[s][tx] = fin[((size_t)(b*1024 + s0 + s))*512 + c0 + tx];
  }
  __syncthreads();
#pragma unroll
  for (int i = 0; i < 16; ++i) {
    int c = ty + i*4;
    int cc = c0 + c, grp = cc >> 4;
    float mu = stats[(b*32+grp)*2], rstd = stats[(b*32+grp)*2+1];
    float gg = g[cc], bb = be[cc];
    size_t oi = ((size_t)(b*512 + cc))*1024 + s0 + tx;
    out[oi] = (t[tx][c] - mu)*rstd*gg + bb + x[oi];
  }
}

// =====================================================================
static void launch_gemm128(hipStream_t st, const unsigned short* A, const unsigned short* B,
                           void* out, const float* bias,
                           int M, int N, int K, int lda, int ldb, int ldo, int epi,
                           long long Ay, long long Az, long long By, long long Bz,
                           long long Oy, long long Oz, int gy, int gz) {
  GemmDesc d{A, B, out, bias, M, N, K, lda, ldb, ldo, epi, Ay, Az, By, Bz, Oy, Oz};
  gemm_tile_kernel<128,128><<<dim3((M/128)*(N/128), gy, gz), dim3(256), 0, st>>>(d);
}
static void launch_gemm64(hipStream_t st, const unsigned short* A, const unsigned short* B,
                          void* out, const float* bias,
                          int M, int N, int K, int lda, int ldb, int ldo, int epi) {
  GemmDesc d{A, B, out, bias, M, N, K, lda, ldb, ldo, epi, 0,0,0,0,0,0};
  gemm_tile_kernel<128,64><<<dim3((M/128)*(N/64), 1, 1), dim3(256), 0, st>>>(d);
}

extern "C" void kernel_launch(void* const* d_in, const int* in_sizes, int n_in,
                              void* d_out, int out_size, void* d_ws, size_t ws_size,
                              hipStream_t stream) {
  const float* x      = (const float*)d_in[0];
  const float* pre_g  = (const float*)d_in[1];
  const float* pre_b  = (const float*)d_in[2];
  const float* norm_g = (const float*)d_in[3];
  const float* norm_b = (const float*)d_in[4];
  const float* post_g = (const float*)d_in[5];
  const float* post_b = (const float*)d_in[6];
  const float* pos    = (const float*)d_in[7];
  const float* sa_b1  = (const float*)d_in[9];
  const float* sa_w2  = (const float*)d_in[10];
  const float* sa_b2  = (const float*)d_in[11];
  const float* sa_w3  = (const float*)d_in[12];
  const float* sa_b3  = (const float*)d_in[13];
  const float* ff_b1  = (const float*)d_in[24];
  const float* ff_b2  = (const float*)d_in[26];
  const float* out_b  = (const float*)d_in[28];
  float* outp = (float*)d_out;

  char* ws = (char*)d_ws;
  size_t off = 0;
  auto alloc = [&](size_t bytes) -> void* {
    void* p = ws + off; off += (bytes + 255) & ~(size_t)255; return p;
  };
  float* HS    = (float*)alloc(16777216);          // (B,512,1024) f32
  float* SW    = (float*)alloc(32768);             // gate
  float* STATS = (float*)alloc(4096);
  unsigned short* HSB  = (unsigned short*)alloc(8388608);   // (B*S,512) hs bf16
  unsigned short* A1   = (unsigned short*)alloc(1048576);   // (B*S,64)
  unsigned short* IM2  = (unsigned short*)alloc(9437184);   // (B*S,576)
  unsigned short* A2   = (unsigned short*)alloc(1048576);   // (B*S,64)
  unsigned short* SHB  = (unsigned short*)alloc(8388608);   // normed
  unsigned short* MSHB = (unsigned short*)alloc(8388608);   // gated
  unsigned short* WBF  = (unsigned short*)alloc(6291456);   // packed bf16 weights
  unsigned short* QKV  = (unsigned short*)alloc(25165824);  // (B*S,1536)
  unsigned short* QM   = (unsigned short*)alloc(8388608);   // (B*S,512)
  unsigned short* KVM  = (unsigned short*)alloc(16777216);  // (B*S,1024)
  unsigned short* VTB  = (unsigned short*)alloc(8388608);   // (B,512,1024) V^T
  unsigned short* VMT  = (unsigned short*)alloc(8388608);   // (B,512,1024) [V0|V1]^T
  unsigned short* SBUF = (unsigned short*)alloc(16777216);  // branch scores bf16
  unsigned short* PBUF = (unsigned short*)alloc(16777216);  // branch probs bf16
  unsigned short* COMB = (unsigned short*)alloc(16777216);  // (B*S,1024)
  unsigned short* FFMID= (unsigned short*)alloc(8388608);
  unsigned short* FUSED= (unsigned short*)alloc(8388608);
  float* FINAL = (float*)alloc(16777216);

  // WBF element offsets
  const int OQKV=0, OQM=786432, OKVM=1048576, OFF1=1572864, OFF2=2097152,
            OOW=2359296, OW1=2621440, OW2R=2654208;

  // 1) GN(pre)+pos -> HS, fused GN(norm) stats
  gn_pre_kernel<<<dim3(256), dim3(256), 0, stream>>>(x, pre_g, pre_b, pos, HS, STATS);
  // 2) weights -> bf16 (attention scales folded into Q weights)
  {
    WCvtArgs a;
    const int   srcIdx[13] = {14,15,16,17,20,18,21,19,22,23,25,27,8};
    const int   dofs[13]   = {OQKV, OQKV+262144, OQKV+524288,
                              OQM, OQM+131072,
                              OKVM, OKVM+131072, OKVM+262144, OKVM+393216,
                              OFF1, OFF2, OOW, OW1};
    const int   ns[13]     = {262144,262144,262144,131072,131072,131072,131072,131072,131072,524288,262144,262144,32768};
    const float sc[13]     = {0.125f,1.f,1.f,0.0625f,0.0625f,1.f,1.f,1.f,1.f,1.f,1.f,1.f,1.f};
    for (int i = 0; i < 13; ++i) { a.w[i].src = (const float*)d_in[srcIdx[i]]; a.w[i].dstOff = dofs[i]; a.w[i].n = ns[i]; a.w[i].scale = sc[i]; }
    wconvert_kernel<<<dim3(2048, 13), dim3(256), 0, stream>>>(a, WBF);
  }
  w2reorder_kernel<<<dim3(144), dim3(256), 0, stream>>>(sa_w2, WBF + OW2R);
  // 3) HS -> HSB bf16 token-major (tiled transpose)
  hs_to_bsc_kernel<<<dim3(16, 8, 8), dim3(256), 0, stream>>>(HS, HSB);
  // 4) spatial gate chain as GEMMs
  launch_gemm64(stream, HSB, WBF+OW1,  A1, sa_b1, 8192, 64, 512, 512, 512, 64, 2);
  im2col_kernel<<<dim3(1024), dim3(256), 0, stream>>>(A1, IM2);
  launch_gemm64(stream, IM2, WBF+OW2R, A2, sa_b2, 8192, 64, 576, 576, 576, 64, 2);
  conv3_kernel<<<dim3(32), dim3(256), 0, stream>>>(A2, sa_w3, sa_b3, SW);
  // 5) gate + norm
  gate_norm_kernel<<<dim3(256, 8), dim3(256), 0, stream>>>(HSB, SW, STATS, norm_g, norm_b, SHB, MSHB);

  // 6) fused projections
  launch_gemm128(stream, SHB,  WBF+OQKV, QKV, nullptr, 8192, 1536, 512, 512, 512, 1536, 1, 0,0,0,0,0,0, 1,1);
  launch_gemm128(stream, MSHB, WBF+OQM,  QM,  nullptr, 8192, 512,  512, 512, 512, 512,  1, 0,0,0,0,0,0, 1,1);
  launch_gemm128(stream, SHB,  WBF+OKVM, KVM, nullptr, 8192, 1024, 512, 512, 512, 1024, 1, 0,0,0,0,0,0, 1,1);

  // 7) V transposes
  transpose_tile_kernel<<<dim3(16, 8, 8), dim3(256), 0, stream>>>(QKV, VTB, 1536, 1024);
  transpose_tile_kernel<<<dim3(16, 8, 8), dim3(256), 0, stream>>>(KVM, VMT, 1024, 512);

  // 8) std MHSA: single fused flash kernel -> COMB[:, 0:512]
  flash_attn_kernel<<<dim3(8, 8, 8), dim3(256), 0, stream>>>(QKV, VTB, COMB);

  // 9) two multi-scale branches (bf16 scores)
  for (int br = 0; br < 2; ++br) {
    launch_gemm128(stream, QM + br*256, KVM + br*256, SBUF, nullptr,
                   1024, 1024, 256, 512, 1024, 1024, 1,
                   1024LL*512, 0, 1024LL*1024, 0, 1024LL*1024, 0, 8, 1);
    softmax_bf16_kernel<<<dim3(2048), dim3(256), 0, stream>>>(SBUF, PBUF, 8192);
    launch_gemm128(stream, PBUF, VMT + (size_t)br*256*1024, COMB + 512 + br*256, nullptr,
                   1024, 256, 1024, 1024, 1024, 1024, 1,
                   1024LL*1024, 0, 512LL*1024, 0, 1024LL*1024, 0, 8, 1);
  }

  // 10) FF + out projection
  launch_gemm128(stream, COMB,  WBF+OFF1, FFMID, ff_b1, 8192, 512, 1024, 1024, 1024, 512, 2, 0,0,0,0,0,0, 1,1);
  launch_gemm128(stream, FFMID, WBF+OFF2, FUSED, ff_b2, 8192, 512, 512,  512,  512,  512, 1, 0,0,0,0,0,0, 1,1);
  launch_gemm128(stream, FUSED, WBF+OOW,  FINAL, out_b, 8192, 512, 512,  512,  512,  512, 0, 0,0,0,0,0,0, 1,1);

  // 11) GN(post) + residual (tiled)
  gn_stats_bsc_kernel<<<dim3(256), dim3(256), 0, stream>>>(FINAL, STATS);
  final_out_kernel<<<dim3(16, 8, 8), dim3(256), 0, stream>>>(FINAL, STATS, post_g, post_b, x, outp);

  (void)in_sizes; (void)n_in; (void)out_size; (void)ws_size;
}

// Round 5
// 479.892 us; speedup vs baseline: 3.3736x; 1.0416x over previous
//
#include <hip/hip_runtime.h>
#include <hip/hip_bf16.h>
#include <math.h>

typedef __attribute__((ext_vector_type(8))) __bf16 v8bf;
typedef __attribute__((ext_vector_type(4))) float v4f;

__device__ __forceinline__ unsigned short f2bf(float f) {
  union { float f; unsigned int u; } a; a.f = f;
  unsigned int r = a.u + 0x7fffu + ((a.u >> 16) & 1u);
  return (unsigned short)(r >> 16);
}
__device__ __forceinline__ unsigned short f2bf_trunc(float f) {
  union { float f; unsigned int u; } a; a.f = f;
  return (unsigned short)(a.u >> 16);
}
__device__ __forceinline__ float bf2f(unsigned short u) {
  union { unsigned int i; float f; } a; a.i = ((unsigned int)u) << 16; return a.f;
}
__device__ __forceinline__ float sigm(float x) { return 1.0f / (1.0f + __expf(-x)); }

__device__ __forceinline__ void async16(const void* g, void* l) {
  __builtin_amdgcn_global_load_lds(
      (const __attribute__((address_space(1))) unsigned int*)g,
      (__attribute__((address_space(3))) unsigned int*)l, 16, 0, 0);
}

// ---------- GN(pre)+pos -> HSB bf16 token-major directly; fused GN(norm) stats ----------
// one block per (b,grp): 16 ch x 1024 s staged in 64KB LDS, 3 passes.
__global__ __launch_bounds__(256) void gn_pre_kernel(
    const float* __restrict__ x, const float* __restrict__ g, const float* __restrict__ be,
    const float* __restrict__ pos, unsigned short* __restrict__ hsb, float* __restrict__ stats) {
  __shared__ float L[16384];
  __shared__ float rs[4], rs2[4], mr[2];
  int b = blockIdx.x >> 5, grp = blockIdx.x & 31;
  const float4* base = (const float4*)(x + ((size_t)b*512 + grp*16)*1024);
  float4* L4 = (float4*)L;
  int w = threadIdx.x >> 6;
  float s = 0.f, s2 = 0.f;
  for (int i = threadIdx.x; i < 4096; i += 256) {
    float4 v = base[i];
    L4[i] = v;
    s += v.x + v.y + v.z + v.w;
    s2 += v.x*v.x + v.y*v.y + v.z*v.z + v.w*v.w;
  }
#pragma unroll
  for (int o = 32; o; o >>= 1) { s += __shfl_xor(s, o); s2 += __shfl_xor(s2, o); }
  if ((threadIdx.x & 63) == 0) { rs[w] = s; rs2[w] = s2; }
  __syncthreads();
  if (threadIdx.x == 0) {
    float ts = rs[0]+rs[1]+rs[2]+rs[3], ts2 = rs2[0]+rs2[1]+rs2[2]+rs2[3];
    float mu = ts * (1.0f/16384.0f);
    float var = ts2 * (1.0f/16384.0f) - mu*mu;
    mr[0] = mu; mr[1] = rsqrtf(var + 1e-6f);
  }
  __syncthreads();
  float mu = mr[0], rstd = mr[1];
  const float4* pb = (const float4*)(pos + (size_t)grp*16*1024);
  float ns = 0.f, ns2 = 0.f;
  for (int i = threadIdx.x; i < 4096; i += 256) {
    float4 v = L4[i], p = pb[i];
    int c = grp*16 + (i >> 8);
    float gg = g[c], bb = be[c];
    float4 o;
    o.x = (v.x - mu)*rstd*gg + bb + p.x;
    o.y = (v.y - mu)*rstd*gg + bb + p.y;
    o.z = (v.z - mu)*rstd*gg + bb + p.z;
    o.w = (v.w - mu)*rstd*gg + bb + p.w;
    L4[i] = o;
    ns += o.x + o.y + o.z + o.w;
    ns2 += o.x*o.x + o.y*o.y + o.z*o.z + o.w*o.w;
  }
#pragma unroll
  for (int o = 32; o; o >>= 1) { ns += __shfl_xor(ns, o); ns2 += __shfl_xor(ns2, o); }
  if ((threadIdx.x & 63) == 0) { rs[w] = ns; rs2[w] = ns2; }
  __syncthreads();
  if (threadIdx.x == 0) {
    float ts = rs[0]+rs[1]+rs[2]+rs[3], ts2 = rs2[0]+rs2[1]+rs2[2]+rs2[3];
    float nmu = ts * (1.0f/16384.0f);
    float nvar = ts2 * (1.0f/16384.0f) - nmu*nmu;
    stats[(b*32+grp)*2] = nmu; stats[(b*32+grp)*2+1] = rsqrtf(nvar + 1e-6f);
  }
  // pass3: token-major bf16 write (16 ch per token, 32B per lane)
#pragma unroll
  for (int j = 0; j < 4; ++j) {
    int sI = threadIdx.x + j*256;
    unsigned int wd[8];
#pragma unroll
    for (int c = 0; c < 8; ++c) {
      unsigned int lo = f2bf(L[(2*c)*1024 + sI]);
      unsigned int hi = f2bf(L[(2*c+1)*1024 + sI]);
      wd[c] = lo | (hi << 16);
    }
    size_t oo = (size_t)(b*1024 + sI)*512 + grp*16;
    *(uint4*)(hsb + oo)     = make_uint4(wd[0], wd[1], wd[2], wd[3]);
    *(uint4*)(hsb + oo + 8) = make_uint4(wd[4], wd[5], wd[6], wd[7]);
  }
}

// ---------- im2col: A1 (B*S,64) bf16 -> IM2 (B*S,576) bf16 ----------
__global__ __launch_bounds__(256) void im2col_kernel(
    const unsigned short* __restrict__ a1, unsigned short* __restrict__ im2) {
  int row0 = blockIdx.x * 8;
#pragma unroll
  for (int it = 0; it < 3; ++it) {
    int cc = it*256 + threadIdx.x;
    if (cc >= 576) break;
    int rl = cc / 72, rr = cc - rl*72;
    int tap = rr >> 3, ch8 = rr & 7;
    int row = row0 + rl;
    int bb = row >> 10, s = row & 1023;
    int y = s >> 5, xx0 = s & 31;
    int yy = y + tap/3 - 1, xx = xx0 + tap%3 - 1;
    ushort4 v0 = make_ushort4(0,0,0,0), v1 = make_ushort4(0,0,0,0);
    if ((unsigned)yy < 32u && (unsigned)xx < 32u) {
      const unsigned short* src = a1 + ((size_t)(bb*1024 + yy*32 + xx))*64 + ch8*8;
      v0 = *(const ushort4*)src; v1 = *(const ushort4*)(src + 4);
    }
    unsigned short* dst = im2 + (size_t)row*576 + tap*64 + ch8*8;
    *(ushort4*)dst = v0; *(ushort4*)(dst + 4) = v1;
  }
}

// ---------- gate(conv3 fused) + GN(norm): HSB,A2 -> SHB (normed), MSHB (gated) ----------
__global__ __launch_bounds__(256) void gate_norm_kernel(
    const unsigned short* __restrict__ hsb, const unsigned short* __restrict__ a2,
    const float* __restrict__ w3, const float* __restrict__ b3,
    const float* __restrict__ stats, const float* __restrict__ g,
    const float* __restrict__ be,
    unsigned short* __restrict__ sh, unsigned short* __restrict__ msh) {
  int b = blockIdx.y;
  int s = blockIdx.x * 4 + (threadIdx.x >> 6);
  int oct = threadIdx.x & 63;
  int c0 = oct * 8;
  int grp = c0 >> 4;
  // conv3: dot(A2[s], w3) over 64 ch, one ch per lane
  float part = bf2f(a2[((size_t)(b*1024) + s)*64 + oct]) * w3[oct];
#pragma unroll
  for (int o = 32; o; o >>= 1) part += __shfl_xor(part, o);
  float wgt = sigm(part + b3[0]);
  float mu = stats[(b*32 + grp)*2], rstd = stats[(b*32 + grp)*2 + 1];
  size_t o = (size_t)(b*1024 + s)*512 + c0;
  ushort4 u0 = *(const ushort4*)(hsb + o), u1 = *(const ushort4*)(hsb + o + 4);
  unsigned short uu[8] = {u0.x,u0.y,u0.z,u0.w,u1.x,u1.y,u1.z,u1.w};
  unsigned short so[8], mo[8];
#pragma unroll
  for (int j = 0; j < 8; ++j) {
    float v = bf2f(uu[j]);
    so[j] = f2bf((v - mu)*rstd*g[c0+j] + be[c0+j]);
    mo[j] = f2bf(v * wgt);
  }
  *(ushort4*)(sh + o)     = make_ushort4(so[0], so[1], so[2], so[3]);
  *(ushort4*)(sh + o + 4) = make_ushort4(so[4], so[5], so[6], so[7]);
  *(ushort4*)(msh + o)     = make_ushort4(mo[0], mo[1], mo[2], mo[3]);
  *(ushort4*)(msh + o + 4) = make_ushort4(mo[4], mo[5], mo[6], mo[7]);
}

// ---------- weight f32 -> bf16 convert with scale; slot 13 = conv2 reorder ----------
struct WCvt { const float* src; int dstOff; int n; float scale; };
struct WCvtArgs { WCvt w[14]; };
__global__ __launch_bounds__(256) void wconvert_kernel(WCvtArgs a, unsigned short* __restrict__ dst) {
  WCvt e = a.w[blockIdx.y];
  int i = blockIdx.x * 256 + threadIdx.x;
  if (i >= e.n) return;
  if (blockIdx.y == 13) {
    int oc = i / 576, r = i - oc*576;
    int tap = r >> 6, ic = r & 63;
    dst[e.dstOff + i] = f2bf(e.src[(oc*64 + ic)*9 + tap]);
  } else {
    dst[e.dstOff + i] = f2bf(e.src[i] * e.scale);
  }
}

// ---------- merged V transposes: QKVM cols (1024..1535)->VTB, (2048..2559)->VMT ----------
__global__ __launch_bounds__(256) void transpose2_kernel(
    const unsigned short* __restrict__ qkvm,
    unsigned short* __restrict__ vtb, unsigned short* __restrict__ vmt) {
  __shared__ unsigned short t[64][65];
  int s0 = blockIdx.x * 64, c0 = blockIdx.y * 64;
  int z = blockIdx.z, b = z & 7;
  const unsigned short* in = qkvm + (z >= 8 ? 2048 : 1024);
  unsigned short* out = (z >= 8) ? vmt : vtb;
  int tx = threadIdx.x & 63, ty = threadIdx.x >> 6;
#pragma unroll
  for (int i = 0; i < 16; ++i) {
    int s = ty + i*4;
    t[s][tx] = in[((size_t)(b*1024 + s0 + s))*2560 + c0 + tx];
  }
  __syncthreads();
#pragma unroll
  for (int i = 0; i < 16; ++i) {
    int c = ty + i*4;
    out[((size_t)b*512 + c0 + c)*1024 + s0 + tx] = t[tx][c];
  }
}

// ---------- tiled GEMM (m97 structure) ----------
// epi: 0 = f32 store, 1 = bf16 store, 2 = silu -> bf16 store
struct GemmDesc {
  const unsigned short* A; const unsigned short* B; void* out; const float* bias;
  int M, N, K, lda, ldb, ldo, epi;
  long long Ay, Az, By, Bz, Oy, Oz;
};

template<int BM, int BN>
__global__ __launch_bounds__(256) void gemm_tile_kernel(GemmDesc d) {
  constexpr int WGM = (BN >= 128) ? 2 : 4;
  constexpr int WGN = 4 / WGM;
  constexpr int MT = BM / (16 * WGM);
  constexpr int NT = BN / (16 * WGN);
  constexpr int AIT = (BM * 4) / 256;
  constexpr int BIT = (BN * 4) / 256;
  __shared__ __align__(16) unsigned short As[BM * 32];
  __shared__ __align__(16) unsigned short Bs[BN * 32];

  int ntx = d.N / BN;
  int bm0 = (blockIdx.x / ntx) * BM, bn0 = (blockIdx.x % ntx) * BN;
  const unsigned short* A = d.A + (long long)blockIdx.y * d.Ay
      + (long long)blockIdx.z * d.Az + (size_t)bm0 * d.lda;
  const unsigned short* B = d.B + (long long)blockIdx.y * d.By
      + (long long)blockIdx.z * d.Bz + (size_t)bn0 * d.ldb;
  int tid = threadIdx.x, lane = tid & 63, w = tid >> 6;
  int wm = (WGN == 2) ? (w >> 1) : w;
  int wn = (WGN == 2) ? (w & 1) : 0;
  int ln = lane & 15, qd = lane >> 4;

  v4f acc[MT][NT];
#pragma unroll
  for (int i = 0; i < MT; ++i)
#pragma unroll
    for (int j = 0; j < NT; ++j) acc[i][j] = (v4f){0.f, 0.f, 0.f, 0.f};

  int nks = d.K >> 5;
  for (int ks = 0; ks < nks; ++ks) {
    int kof = ks * 32;
#pragma unroll
    for (int it = 0; it < AIT; ++it) {
      int c = it * 256 + tid;
      async16(A + (size_t)(c >> 2) * d.lda + (c & 3) * 8 + kof,
              As + (it * 256 + w * 64) * 8);
    }
#pragma unroll
    for (int it = 0; it < BIT; ++it) {
      int c = it * 256 + tid;
      async16(B + (size_t)(c >> 2) * d.ldb + (c & 3) * 8 + kof,
              Bs + (it * 256 + w * 64) * 8);
    }
    __syncthreads();
    v8bf af[MT], bfr[NT];
#pragma unroll
    for (int i = 0; i < MT; ++i)
      af[i] = *(const v8bf*)(As + (wm * MT * 16 + i * 16 + ln) * 32 + qd * 8);
#pragma unroll
    for (int j = 0; j < NT; ++j)
      bfr[j] = *(const v8bf*)(Bs + (wn * NT * 16 + j * 16 + ln) * 32 + qd * 8);
#pragma unroll
    for (int i = 0; i < MT; ++i)
#pragma unroll
      for (int j = 0; j < NT; ++j)
        acc[i][j] = __builtin_amdgcn_mfma_f32_16x16x32_bf16(af[i], bfr[j], acc[i][j], 0, 0, 0);
    __syncthreads();
  }

  size_t obase = (size_t)((long long)blockIdx.y * d.Oy + (long long)blockIdx.z * d.Oz);
#pragma unroll
  for (int i = 0; i < MT; ++i) {
#pragma unroll
    for (int j = 0; j < NT; ++j) {
      int col = bn0 + wn * NT * 16 + j * 16 + ln;
      float bia = d.bias ? d.bias[col] : 0.0f;
#pragma unroll
      for (int r = 0; r < 4; ++r) {
        int row = bm0 + wm * MT * 16 + i * 16 + qd * 4 + r;
        float v = acc[i][j][r] + bia;
        if (d.epi == 2) v = v * sigm(v);
        size_t oi = obase + (size_t)row * d.ldo + col;
        if (d.epi == 0) ((float*)d.out)[oi] = v;
        else ((unsigned short*)d.out)[oi] = f2bf(v);
      }
    }
  }
}

// ---------- flash attention, std MHSA: D=64, S=1024 ----------
// log2e folded into Q weights -> exp2; fixed-max softmax; truncating P cvt.
__global__ __launch_bounds__(256) void flash_attn_kernel(
    const unsigned short* __restrict__ QKVM, const unsigned short* __restrict__ VTB,
    unsigned short* __restrict__ out) {
  __shared__ __align__(16) unsigned short Ks[128*64];
  __shared__ __align__(16) unsigned short Vts[64*128];
  __shared__ __align__(16) unsigned short Pw[4][16*128];
  int h = blockIdx.x, b = blockIdx.y, qt = blockIdx.z;
  int tid = threadIdx.x, lane = tid & 63, w = tid >> 6;
  int ln = lane & 15, qd = lane >> 4;

  const unsigned short* Qbase = QKVM + ((size_t)(b*1024 + qt*128 + w*32))*2560 + h*64;
  v8bf aq[2][2];
#pragma unroll
  for (int i = 0; i < 2; ++i)
#pragma unroll
    for (int s = 0; s < 2; ++s)
      aq[i][s] = *(const v8bf*)(Qbase + (size_t)(i*16 + ln)*2560 + s*32 + qd*8);

  v4f o_acc[2][4];
  float l_part[2][4];
#pragma unroll
  for (int i = 0; i < 2; ++i)
#pragma unroll
    for (int dn = 0; dn < 4; ++dn) o_acc[i][dn] = (v4f){0.f,0.f,0.f,0.f};
#pragma unroll
  for (int i = 0; i < 2; ++i)
#pragma unroll
    for (int r = 0; r < 4; ++r) l_part[i][r] = 0.f;

  const unsigned short* Kg = QKVM + 512 + (size_t)(b*1024)*2560 + h*64;
  const unsigned short* Vg = VTB + ((size_t)(b*512) + h*64)*1024;

  for (int kt = 0; kt < 8; ++kt) {
#pragma unroll
    for (int it = 0; it < 4; ++it) {
      int c = it*256 + tid;
      async16(Kg + (size_t)(kt*128 + (c >> 3))*2560 + (((c & 7) ^ ((c >> 3) & 7)) << 3),
              Ks + c*8);
    }
#pragma unroll
    for (int it = 0; it < 4; ++it) {
      int c = it*256 + tid;
      async16(Vg + (size_t)(c >> 4)*1024 + kt*128 + ((((c & 15) ^ ((c >> 4) & 7))) << 3),
              Vts + c*8);
    }
    __syncthreads();

#pragma unroll
    for (int i = 0; i < 2; ++i) {
      v4f sc[8];
#pragma unroll
      for (int n = 0; n < 8; ++n) {
        v4f a = (v4f){0.f,0.f,0.f,0.f};
#pragma unroll
        for (int s = 0; s < 2; ++s) {
          v8bf kb = *(const v8bf*)(Ks + (n*16 + ln)*64 + (((s*4 + qd) ^ (ln & 7)) << 3));
          a = __builtin_amdgcn_mfma_f32_16x16x32_bf16(aq[i][s], kb, a, 0, 0, 0);
        }
        sc[n] = a;
      }
#pragma unroll
      for (int r = 0; r < 4; ++r) {
        int row7 = (qd*4 + r) & 7;
        float acc_l = 0.f;
#pragma unroll
        for (int n = 0; n < 8; ++n) {
          float p = exp2f(sc[n][r]);
          acc_l += p;
          Pw[w][(qd*4 + r)*128 + (((n*2 + (ln >> 3)) ^ row7) << 3) + (ln & 7)] = f2bf_trunc(p);
        }
        l_part[i][r] += acc_l;
      }
#pragma unroll
      for (int dn = 0; dn < 4; ++dn) {
        v4f a = o_acc[i][dn];
#pragma unroll
        for (int ks2 = 0; ks2 < 4; ++ks2) {
          int phys = (((ks2*4 + qd) ^ (ln & 7)) << 3);
          v8bf pf = *(const v8bf*)(&Pw[w][ln*128 + phys]);
          v8bf vf = *(const v8bf*)(Vts + (dn*16 + ln)*128 + phys);
          a = __builtin_amdgcn_mfma_f32_16x16x32_bf16(pf, vf, a, 0, 0, 0);
        }
        o_acc[i][dn] = a;
      }
    }
    __syncthreads();
  }

  unsigned short* ob = out + ((size_t)(b*1024 + qt*128 + w*32))*1024 + h*64;
#pragma unroll
  for (int i = 0; i < 2; ++i)
#pragma unroll
    for (int r = 0; r < 4; ++r) {
      float l = l_part[i][r];
      l += __shfl_xor(l, 1); l += __shfl_xor(l, 2);
      l += __shfl_xor(l, 4); l += __shfl_xor(l, 8);
      float rinv = 1.0f / l;
#pragma unroll
      for (int dn = 0; dn < 4; ++dn)
        ob[(size_t)(i*16 + qd*4 + r)*1024 + dn*16 + ln] = f2bf(o_acc[i][dn][r] * rinv);
    }
}

// ---------- row softmax over bf16 logits: (nrows,1024) -> P bf16 ----------
__global__ __launch_bounds__(256) void softmax_bf16_kernel(
    const unsigned short* __restrict__ S, unsigned short* __restrict__ P, int nrows) {
  int row = blockIdx.x * 4 + (threadIdx.x >> 6);
  if (row >= nrows) return;
  int l = threadIdx.x & 63;
  const ushort4* sp = (const ushort4*)(S + (size_t)row * 1024);
  float v[16];
  float m = -1e30f;
#pragma unroll
  for (int t = 0; t < 4; ++t) {
    ushort4 u = sp[t*64 + l];
    v[t*4+0] = bf2f(u.x); v[t*4+1] = bf2f(u.y); v[t*4+2] = bf2f(u.z); v[t*4+3] = bf2f(u.w);
    m = fmaxf(m, fmaxf(fmaxf(v[t*4], v[t*4+1]), fmaxf(v[t*4+2], v[t*4+3])));
  }
#pragma unroll
  for (int o = 32; o; o >>= 1) m = fmaxf(m, __shfl_xor(m, o));
  float sum = 0.f;
#pragma unroll
  for (int t = 0; t < 16; ++t) { v[t] = __expf(v[t] - m); sum += v[t]; }
#pragma unroll
  for (int o = 32; o; o >>= 1) sum += __shfl_xor(sum, o);
  float r = 1.0f / sum;
  ushort4* p = (ushort4*)(P + (size_t)row * 1024);
#pragma unroll
  for (int t = 0; t < 4; ++t)
    p[t*64 + l] = make_ushort4(f2bf_trunc(v[t*4]*r), f2bf_trunc(v[t*4+1]*r),
                               f2bf_trunc(v[t*4+2]*r), f2bf_trunc(v[t*4+3]*r));
}

// ---------- stats over (B,S,C) bf16 per (b,group) ----------
__global__ __launch_bounds__(256) void gn_stats_bf16_kernel(
    const unsigned short* __restrict__ t, float* __restrict__ stats) {
  int b = blockIdx.x >> 5, grp = blockIdx.x & 31;
  float s = 0.f, s2 = 0.f;
#pragma unroll
  for (int j = 0; j < 4; ++j) {
    int sI = threadIdx.x + j*256;
    const unsigned short* p = t + ((size_t)(b*1024 + sI))*512 + grp*16;
    uint4 a = *(const uint4*)p, c2 = *(const uint4*)(p + 8);
    unsigned int ww[8] = {a.x,a.y,a.z,a.w,c2.x,c2.y,c2.z,c2.w};
#pragma unroll
    for (int k = 0; k < 8; ++k) {
      float lo = bf2f((unsigned short)(ww[k] & 0xffff));
      float hi = bf2f((unsigned short)(ww[k] >> 16));
      s += lo + hi; s2 += lo*lo + hi*hi;
    }
  }
#pragma unroll
  for (int o = 32; o; o >>= 1) { s += __shfl_xor(s, o); s2 += __shfl_xor(s2, o); }
  __shared__ float rs[4], rs2[4];
  int w = threadIdx.x >> 6;
  if ((threadIdx.x & 63) == 0) { rs[w] = s; rs2[w] = s2; }
  __syncthreads();
  if (threadIdx.x == 0) {
    float ts = rs[0]+rs[1]+rs[2]+rs[3], ts2 = rs2[0]+rs2[1]+rs2[2]+rs2[3];
    float mu = ts * (1.0f/16384.0f);
    float var = ts2 * (1.0f/16384.0f) - mu*mu;
    stats[(b*32+grp)*2] = mu; stats[(b*32+grp)*2+1] = rsqrtf(var + 1e-6f);
  }
}

// ---------- GN(post) + residual, bf16 (B,S,C) -> f32 (B,C,S), LDS-tiled ----------
__global__ __launch_bounds__(256) void final_out_kernel(
    const unsigned short* __restrict__ fin, const float* __restrict__ stats,
    const float* __restrict__ g, const float* __restrict__ be,
    const float* __restrict__ x, float* __restrict__ out) {
  __shared__ float t[64][65];
  int s0 = blockIdx.x * 64, c0 = blockIdx.y * 64, b = blockIdx.z;
  int tx = threadIdx.x & 63, ty = threadIdx.x >> 6;
#pragma unroll
  for (int i = 0; i < 16; ++i) {
    int s = ty + i*4;
    t[s][tx] = bf2f(fin[((size_t)(b*1024 + s0 + s))*512 + c0 + tx]);
  }
  __syncthreads();
#pragma unroll
  for (int i = 0; i < 16; ++i) {
    int c = ty + i*4;
    int cc = c0 + c, grp = cc >> 4;
    float mu = stats[(b*32+grp)*2], rstd = stats[(b*32+grp)*2+1];
    float gg = g[cc], bb = be[cc];
    size_t oi = ((size_t)(b*512 + cc))*1024 + s0 + tx;
    out[oi] = (t[tx][c] - mu)*rstd*gg + bb + x[oi];
  }
}

// =====================================================================
static void launch_gemm128(hipStream_t st, const unsigned short* A, const unsigned short* B,
                           void* out, const float* bias,
                           int M, int N, int K, int lda, int ldb, int ldo, int epi,
                           long long Ay, long long Az, long long By, long long Bz,
                           long long Oy, long long Oz, int gy, int gz) {
  GemmDesc d{A, B, out, bias, M, N, K, lda, ldb, ldo, epi, Ay, Az, By, Bz, Oy, Oz};
  gemm_tile_kernel<128,128><<<dim3((M/128)*(N/128), gy, gz), dim3(256), 0, st>>>(d);
}
static void launch_gemm64(hipStream_t st, const unsigned short* A, const unsigned short* B,
                          void* out, const float* bias,
                          int M, int N, int K, int lda, int ldb, int ldo, int epi) {
  GemmDesc d{A, B, out, bias, M, N, K, lda, ldb, ldo, epi, 0,0,0,0,0,0};
  gemm_tile_kernel<128,64><<<dim3((M/128)*(N/64), 1, 1), dim3(256), 0, st>>>(d);
}

extern "C" void kernel_launch(void* const* d_in, const int* in_sizes, int n_in,
                              void* d_out, int out_size, void* d_ws, size_t ws_size,
                              hipStream_t stream) {
  const float* x      = (const float*)d_in[0];
  const float* pre_g  = (const float*)d_in[1];
  const float* pre_b  = (const float*)d_in[2];
  const float* norm_g = (const float*)d_in[3];
  const float* norm_b = (const float*)d_in[4];
  const float* post_g = (const float*)d_in[5];
  const float* post_b = (const float*)d_in[6];
  const float* pos    = (const float*)d_in[7];
  const float* sa_b1  = (const float*)d_in[9];
  const float* sa_b2  = (const float*)d_in[11];
  const float* sa_w3  = (const float*)d_in[12];
  const float* sa_b3  = (const float*)d_in[13];
  const float* ff_b1  = (const float*)d_in[24];
  const float* ff_b2  = (const float*)d_in[26];
  const float* out_b  = (const float*)d_in[28];
  float* outp = (float*)d_out;

  char* ws = (char*)d_ws;
  size_t off = 0;
  auto alloc = [&](size_t bytes) -> void* {
    void* p = ws + off; off += (bytes + 255) & ~(size_t)255; return p;
  };
  float* STATS = (float*)alloc(4096);
  unsigned short* HSB  = (unsigned short*)alloc(8388608);   // (B*S,512) hs bf16
  unsigned short* A1   = (unsigned short*)alloc(1048576);   // (B*S,64)
  unsigned short* IM2  = (unsigned short*)alloc(9437184);   // (B*S,576)
  unsigned short* A2   = (unsigned short*)alloc(1048576);   // (B*S,64)
  unsigned short* SHB  = (unsigned short*)alloc(8388608);   // normed
  unsigned short* MSHB = (unsigned short*)alloc(8388608);   // gated
  unsigned short* WBF  = (unsigned short*)alloc(6291456);   // packed bf16 weights
  unsigned short* QKVM = (unsigned short*)alloc(41943040);  // (B*S,2560) Q|K|V|K0|K1|V0|V1
  unsigned short* QM   = (unsigned short*)alloc(8388608);   // (B*S,512)  Q0|Q1
  unsigned short* VTB  = (unsigned short*)alloc(8388608);   // (B,512,1024) V^T
  unsigned short* VMT  = (unsigned short*)alloc(8388608);   // (B,512,1024) [V0|V1]^T
  unsigned short* SBUF = (unsigned short*)alloc(16777216);  // branch scores bf16
  unsigned short* PBUF = (unsigned short*)alloc(16777216);  // branch probs bf16
  unsigned short* COMB = (unsigned short*)alloc(16777216);  // (B*S,1024)
  unsigned short* FFMID= (unsigned short*)alloc(8388608);
  unsigned short* FUSED= (unsigned short*)alloc(8388608);
  unsigned short* FINALB=(unsigned short*)alloc(8388608);   // (B*S,512) bf16

  // WBF element offsets: QKVM W (2560x512) | QM W (512x512) | FF1 | FF2 | OW | W1 | W2R
  const int OQKVM=0, OQM=1310720, OFF1=1572864, OFF2=2097152,
            OOW=2359296, OW1=2621440, OW2R=2654208;

  // 1) GN(pre)+pos -> HSB bf16 token-major + GN(norm) stats
  gn_pre_kernel<<<dim3(256), dim3(256), 0, stream>>>(x, pre_g, pre_b, pos, HSB, STATS);
  // 2) weights -> bf16 (0.125*log2e folded into wq for exp2 flash; 1/16 into wq0/1)
  {
    WCvtArgs a;
    const float LG2E = 1.4426950408889634f;
    const int   srcIdx[14] = {14,15,16, 18,21,19,22, 17,20, 23,25,27, 8, 10};
    const int   dofs[14]   = {0, 262144, 524288,
                              786432, 917504, 1048576, 1179648,
                              OQM, OQM+131072,
                              OFF1, OFF2, OOW, OW1, OW2R};
    const int   ns[14]     = {262144,262144,262144, 131072,131072,131072,131072,
                              131072,131072, 524288,262144,262144, 32768, 36864};
    const float sc[14]     = {0.125f*LG2E,1.f,1.f, 1.f,1.f,1.f,1.f,
                              0.0625f,0.0625f, 1.f,1.f,1.f, 1.f, 1.f};
    for (int i = 0; i < 14; ++i) { a.w[i].src = (const float*)d_in[srcIdx[i]]; a.w[i].dstOff = dofs[i]; a.w[i].n = ns[i]; a.w[i].scale = sc[i]; }
    wconvert_kernel<<<dim3(2048, 14), dim3(256), 0, stream>>>(a, WBF);
  }
  // 3) spatial gate chain as GEMMs
  launch_gemm64(stream, HSB, WBF+OW1,  A1, sa_b1, 8192, 64, 512, 512, 512, 64, 2);
  im2col_kernel<<<dim3(1024), dim3(256), 0, stream>>>(A1, IM2);
  launch_gemm64(stream, IM2, WBF+OW2R, A2, sa_b2, 8192, 64, 576, 576, 576, 64, 2);
  // 4) gate(conv3 fused) + norm
  gate_norm_kernel<<<dim3(256, 8), dim3(256), 0, stream>>>(HSB, A2, sa_w3, sa_b3, STATS, norm_g, norm_b, SHB, MSHB);

  // 5) fused projections: QKV+K0K1V0V1 in one N=2560 GEMM; QM separate
  launch_gemm128(stream, SHB,  WBF+OQKVM, QKVM, nullptr, 8192, 2560, 512, 512, 512, 2560, 1, 0,0,0,0,0,0, 1,1);
  launch_gemm128(stream, MSHB, WBF+OQM,   QM,   nullptr, 8192, 512,  512, 512, 512, 512,  1, 0,0,0,0,0,0, 1,1);

  // 6) V transposes (merged)
  transpose2_kernel<<<dim3(16, 8, 16), dim3(256), 0, stream>>>(QKVM, VTB, VMT);

  // 7) std MHSA flash -> COMB[:, 0:512]
  flash_attn_kernel<<<dim3(8, 8, 8), dim3(256), 0, stream>>>(QKVM, VTB, COMB);

  // 8) two multi-scale branches
  for (int br = 0; br < 2; ++br) {
    launch_gemm128(stream, QM + br*256, QKVM + 1536 + br*256, SBUF, nullptr,
                   1024, 1024, 256, 512, 2560, 1024, 1,
                   1024LL*512, 0, 1024LL*2560, 0, 1024LL*1024, 0, 8, 1);
    softmax_bf16_kernel<<<dim3(2048), dim3(256), 0, stream>>>(SBUF, PBUF, 8192);
    launch_gemm128(stream, PBUF, VMT + (size_t)br*256*1024, COMB + 512 + br*256, nullptr,
                   1024, 256, 1024, 1024, 1024, 1024, 1,
                   1024LL*1024, 0, 512LL*1024, 0, 1024LL*1024, 0, 8, 1);
  }

  // 9) FF + out projection (OW -> bf16)
  launch_gemm128(stream, COMB,  WBF+OFF1, FFMID,  ff_b1, 8192, 512, 1024, 1024, 1024, 512, 2, 0,0,0,0,0,0, 1,1);
  launch_gemm128(stream, FFMID, WBF+OFF2, FUSED,  ff_b2, 8192, 512, 512,  512,  512,  512, 1, 0,0,0,0,0,0, 1,1);
  launch_gemm128(stream, FUSED, WBF+OOW,  FINALB, out_b, 8192, 512, 512,  512,  512,  512, 1, 0,0,0,0,0,0, 1,1);

  // 10) GN(post) + residual
  gn_stats_bf16_kernel<<<dim3(256), dim3(256), 0, stream>>>(FINALB, STATS);
  final_out_kernel<<<dim3(16, 8, 8), dim3(256), 0, stream>>>(FINALB, STATS, post_g, post_b, x, outp);

  (void)in_sizes; (void)n_in; (void)out_size; (void)ws_size;
}

// Round 6
// 457.338 us; speedup vs baseline: 3.5400x; 1.0493x over previous
//
#include <hip/hip_runtime.h>
#include <hip/hip_bf16.h>
#include <math.h>

typedef __attribute__((ext_vector_type(8))) __bf16 v8bf;
typedef __attribute__((ext_vector_type(4))) float v4f;

__device__ __forceinline__ unsigned short f2bf(float f) {
  union { float f; unsigned int u; } a; a.f = f;
  unsigned int r = a.u + 0x7fffu + ((a.u >> 16) & 1u);
  return (unsigned short)(r >> 16);
}
__device__ __forceinline__ unsigned short f2bf_trunc(float f) {
  union { float f; unsigned int u; } a; a.f = f;
  return (unsigned short)(a.u >> 16);
}
__device__ __forceinline__ float bf2f(unsigned short u) {
  union { unsigned int i; float f; } a; a.i = ((unsigned int)u) << 16; return a.f;
}
__device__ __forceinline__ float sigm(float x) { return 1.0f / (1.0f + __expf(-x)); }

__device__ __forceinline__ void async16(const void* g, void* l) {
  __builtin_amdgcn_global_load_lds(
      (const __attribute__((address_space(1))) unsigned int*)g,
      (__attribute__((address_space(3))) unsigned int*)l, 16, 0, 0);
}

// ---------- GN(pre)+pos -> HSB bf16 token-major directly; fused GN(norm) stats ----------
__global__ __launch_bounds__(256) void gn_pre_kernel(
    const float* __restrict__ x, const float* __restrict__ g, const float* __restrict__ be,
    const float* __restrict__ pos, unsigned short* __restrict__ hsb, float* __restrict__ stats) {
  __shared__ float L[16384];
  __shared__ float rs[4], rs2[4], mr[2];
  int b = blockIdx.x >> 5, grp = blockIdx.x & 31;
  const float4* base = (const float4*)(x + ((size_t)b*512 + grp*16)*1024);
  float4* L4 = (float4*)L;
  int w = threadIdx.x >> 6;
  float s = 0.f, s2 = 0.f;
  for (int i = threadIdx.x; i < 4096; i += 256) {
    float4 v = base[i];
    L4[i] = v;
    s += v.x + v.y + v.z + v.w;
    s2 += v.x*v.x + v.y*v.y + v.z*v.z + v.w*v.w;
  }
#pragma unroll
  for (int o = 32; o; o >>= 1) { s += __shfl_xor(s, o); s2 += __shfl_xor(s2, o); }
  if ((threadIdx.x & 63) == 0) { rs[w] = s; rs2[w] = s2; }
  __syncthreads();
  if (threadIdx.x == 0) {
    float ts = rs[0]+rs[1]+rs[2]+rs[3], ts2 = rs2[0]+rs2[1]+rs2[2]+rs2[3];
    float mu = ts * (1.0f/16384.0f);
    float var = ts2 * (1.0f/16384.0f) - mu*mu;
    mr[0] = mu; mr[1] = rsqrtf(var + 1e-6f);
  }
  __syncthreads();
  float mu = mr[0], rstd = mr[1];
  const float4* pb = (const float4*)(pos + (size_t)grp*16*1024);
  float ns = 0.f, ns2 = 0.f;
  for (int i = threadIdx.x; i < 4096; i += 256) {
    float4 v = L4[i], p = pb[i];
    int c = grp*16 + (i >> 8);
    float gg = g[c], bb = be[c];
    float4 o;
    o.x = (v.x - mu)*rstd*gg + bb + p.x;
    o.y = (v.y - mu)*rstd*gg + bb + p.y;
    o.z = (v.z - mu)*rstd*gg + bb + p.z;
    o.w = (v.w - mu)*rstd*gg + bb + p.w;
    L4[i] = o;
    ns += o.x + o.y + o.z + o.w;
    ns2 += o.x*o.x + o.y*o.y + o.z*o.z + o.w*o.w;
  }
#pragma unroll
  for (int o = 32; o; o >>= 1) { ns += __shfl_xor(ns, o); ns2 += __shfl_xor(ns2, o); }
  if ((threadIdx.x & 63) == 0) { rs[w] = ns; rs2[w] = ns2; }
  __syncthreads();
  if (threadIdx.x == 0) {
    float ts = rs[0]+rs[1]+rs[2]+rs[3], ts2 = rs2[0]+rs2[1]+rs2[2]+rs2[3];
    float nmu = ts * (1.0f/16384.0f);
    float nvar = ts2 * (1.0f/16384.0f) - nmu*nmu;
    stats[(b*32+grp)*2] = nmu; stats[(b*32+grp)*2+1] = rsqrtf(nvar + 1e-6f);
  }
#pragma unroll
  for (int j = 0; j < 4; ++j) {
    int sI = threadIdx.x + j*256;
    unsigned int wd[8];
#pragma unroll
    for (int c = 0; c < 8; ++c) {
      unsigned int lo = f2bf(L[(2*c)*1024 + sI]);
      unsigned int hi = f2bf(L[(2*c+1)*1024 + sI]);
      wd[c] = lo | (hi << 16);
    }
    size_t oo = (size_t)(b*1024 + sI)*512 + grp*16;
    *(uint4*)(hsb + oo)     = make_uint4(wd[0], wd[1], wd[2], wd[3]);
    *(uint4*)(hsb + oo + 8) = make_uint4(wd[4], wd[5], wd[6], wd[7]);
  }
}

// ---------- im2col: A1 (B*S,64) bf16 -> IM2 (B*S,576) bf16 ----------
__global__ __launch_bounds__(256) void im2col_kernel(
    const unsigned short* __restrict__ a1, unsigned short* __restrict__ im2) {
  int row0 = blockIdx.x * 8;
#pragma unroll
  for (int it = 0; it < 3; ++it) {
    int cc = it*256 + threadIdx.x;
    if (cc >= 576) break;
    int rl = cc / 72, rr = cc - rl*72;
    int tap = rr >> 3, ch8 = rr & 7;
    int row = row0 + rl;
    int bb = row >> 10, s = row & 1023;
    int y = s >> 5, xx0 = s & 31;
    int yy = y + tap/3 - 1, xx = xx0 + tap%3 - 1;
    ushort4 v0 = make_ushort4(0,0,0,0), v1 = make_ushort4(0,0,0,0);
    if ((unsigned)yy < 32u && (unsigned)xx < 32u) {
      const unsigned short* src = a1 + ((size_t)(bb*1024 + yy*32 + xx))*64 + ch8*8;
      v0 = *(const ushort4*)src; v1 = *(const ushort4*)(src + 4);
    }
    unsigned short* dst = im2 + (size_t)row*576 + tap*64 + ch8*8;
    *(ushort4*)dst = v0; *(ushort4*)(dst + 4) = v1;
  }
}

// ---------- gate(conv3 fused) + GN(norm) ----------
__global__ __launch_bounds__(256) void gate_norm_kernel(
    const unsigned short* __restrict__ hsb, const unsigned short* __restrict__ a2,
    const float* __restrict__ w3, const float* __restrict__ b3,
    const float* __restrict__ stats, const float* __restrict__ g,
    const float* __restrict__ be,
    unsigned short* __restrict__ sh, unsigned short* __restrict__ msh) {
  int b = blockIdx.y;
  int s = blockIdx.x * 4 + (threadIdx.x >> 6);
  int oct = threadIdx.x & 63;
  int c0 = oct * 8;
  int grp = c0 >> 4;
  float part = bf2f(a2[((size_t)(b*1024) + s)*64 + oct]) * w3[oct];
#pragma unroll
  for (int o = 32; o; o >>= 1) part += __shfl_xor(part, o);
  float wgt = sigm(part + b3[0]);
  float mu = stats[(b*32 + grp)*2], rstd = stats[(b*32 + grp)*2 + 1];
  size_t o = (size_t)(b*1024 + s)*512 + c0;
  ushort4 u0 = *(const ushort4*)(hsb + o), u1 = *(const ushort4*)(hsb + o + 4);
  unsigned short uu[8] = {u0.x,u0.y,u0.z,u0.w,u1.x,u1.y,u1.z,u1.w};
  unsigned short so[8], mo[8];
#pragma unroll
  for (int j = 0; j < 8; ++j) {
    float v = bf2f(uu[j]);
    so[j] = f2bf((v - mu)*rstd*g[c0+j] + be[c0+j]);
    mo[j] = f2bf(v * wgt);
  }
  *(ushort4*)(sh + o)     = make_ushort4(so[0], so[1], so[2], so[3]);
  *(ushort4*)(sh + o + 4) = make_ushort4(so[4], so[5], so[6], so[7]);
  *(ushort4*)(msh + o)     = make_ushort4(mo[0], mo[1], mo[2], mo[3]);
  *(ushort4*)(msh + o + 4) = make_ushort4(mo[4], mo[5], mo[6], mo[7]);
}

// ---------- weight f32 -> bf16; slot13 = conv2 reorder; slot14 = ff_w2 transpose ----------
struct WCvt { const float* src; int dstOff; int n; float scale; };
struct WCvtArgs { WCvt w[15]; };
__global__ __launch_bounds__(256) void wconvert_kernel(WCvtArgs a, unsigned short* __restrict__ dst) {
  WCvt e = a.w[blockIdx.y];
  int i = blockIdx.x * 256 + threadIdx.x;
  if (i >= e.n) return;
  if (blockIdx.y == 13) {
    int oc = i / 576, r = i - oc*576;
    int tap = r >> 6, ic = r & 63;
    dst[e.dstOff + i] = f2bf(e.src[(oc*64 + ic)*9 + tap]);
  } else if (blockIdx.y == 14) {
    dst[e.dstOff + i] = f2bf(e.src[(i & 511)*512 + (i >> 9)]);
  } else {
    dst[e.dstOff + i] = f2bf(e.src[i] * e.scale);
  }
}

// ---------- combined bias: bc = out_w @ ff_b2 + out_b ----------
__global__ __launch_bounds__(256) void bias_fold_kernel(
    const float* __restrict__ ow, const float* __restrict__ b2,
    const float* __restrict__ ob, float* __restrict__ bc) {
  int n = blockIdx.x * 256 + threadIdx.x;
  float s = ob[n];
  const float* r = ow + (size_t)n * 512;
#pragma unroll 8
  for (int j = 0; j < 512; ++j) s += r[j] * b2[j];
  bc[n] = s;
}

// ---------- merged V transposes ----------
__global__ __launch_bounds__(256) void transpose2_kernel(
    const unsigned short* __restrict__ qkvm,
    unsigned short* __restrict__ vtb, unsigned short* __restrict__ vmt) {
  __shared__ unsigned short t[64][65];
  int s0 = blockIdx.x * 64, c0 = blockIdx.y * 64;
  int z = blockIdx.z, b = z & 7;
  const unsigned short* in = qkvm + (z >= 8 ? 2048 : 1024);
  unsigned short* out = (z >= 8) ? vmt : vtb;
  int tx = threadIdx.x & 63, ty = threadIdx.x >> 6;
#pragma unroll
  for (int i = 0; i < 16; ++i) {
    int s = ty + i*4;
    t[s][tx] = in[((size_t)(b*1024 + s0 + s))*2560 + c0 + tx];
  }
  __syncthreads();
#pragma unroll
  for (int i = 0; i < 16; ++i) {
    int c = ty + i*4;
    out[((size_t)b*512 + c0 + c)*1024 + s0 + tx] = t[tx][c];
  }
}

// ---------- tiled GEMM (m97 structure) with XCD-aware tile swizzle ----------
struct GemmDesc {
  const unsigned short* A; const unsigned short* B; void* out; const float* bias;
  int M, N, K, lda, ldb, ldo, epi;
  long long Ay, Az, By, Bz, Oy, Oz;
};

template<int BM, int BN>
__global__ __launch_bounds__(256) void gemm_tile_kernel(GemmDesc d) {
  constexpr int WGM = (BN >= 128) ? 2 : 4;
  constexpr int WGN = 4 / WGM;
  constexpr int MT = BM / (16 * WGM);
  constexpr int NT = BN / (16 * WGN);
  constexpr int AIT = (BM * 4) / 256;
  constexpr int BIT = (BN * 4) / 256;
  __shared__ __align__(16) unsigned short As[BM * 32];
  __shared__ __align__(16) unsigned short Bs[BN * 32];

  int ntx = d.N / BN, mtx = d.M / BM;
  int bmt, bnt;
  if ((mtx & 7) == 0) {
    // consecutive blocks round-robin XCDs; give each XCD a contiguous m-stripe,
    // n slow / local-m fast so B-tiles are reused back-to-back within the stripe.
    int xcd = blockIdx.x & 7, j = blockIdx.x >> 3;
    int mpx = mtx >> 3;
    bmt = xcd * mpx + (j % mpx);
    bnt = j / mpx;
  } else {
    bmt = blockIdx.x / ntx; bnt = blockIdx.x % ntx;
  }
  int bm0 = bmt * BM, bn0 = bnt * BN;
  const unsigned short* A = d.A + (long long)blockIdx.y * d.Ay
      + (long long)blockIdx.z * d.Az + (size_t)bm0 * d.lda;
  const unsigned short* B = d.B + (long long)blockIdx.y * d.By
      + (long long)blockIdx.z * d.Bz + (size_t)bn0 * d.ldb;
  int tid = threadIdx.x, lane = tid & 63, w = tid >> 6;
  int wm = (WGN == 2) ? (w >> 1) : w;
  int wn = (WGN == 2) ? (w & 1) : 0;
  int ln = lane & 15, qd = lane >> 4;

  v4f acc[MT][NT];
#pragma unroll
  for (int i = 0; i < MT; ++i)
#pragma unroll
    for (int j = 0; j < NT; ++j) acc[i][j] = (v4f){0.f, 0.f, 0.f, 0.f};

  int nks = d.K >> 5;
  for (int ks = 0; ks < nks; ++ks) {
    int kof = ks * 32;
#pragma unroll
    for (int it = 0; it < AIT; ++it) {
      int c = it * 256 + tid;
      async16(A + (size_t)(c >> 2) * d.lda + (c & 3) * 8 + kof,
              As + (it * 256 + w * 64) * 8);
    }
#pragma unroll
    for (int it = 0; it < BIT; ++it) {
      int c = it * 256 + tid;
      async16(B + (size_t)(c >> 2) * d.ldb + (c & 3) * 8 + kof,
              Bs + (it * 256 + w * 64) * 8);
    }
    __syncthreads();
    v8bf af[MT], bfr[NT];
#pragma unroll
    for (int i = 0; i < MT; ++i)
      af[i] = *(const v8bf*)(As + (wm * MT * 16 + i * 16 + ln) * 32 + qd * 8);
#pragma unroll
    for (int j = 0; j < NT; ++j)
      bfr[j] = *(const v8bf*)(Bs + (wn * NT * 16 + j * 16 + ln) * 32 + qd * 8);
#pragma unroll
    for (int i = 0; i < MT; ++i)
#pragma unroll
      for (int j = 0; j < NT; ++j)
        acc[i][j] = __builtin_amdgcn_mfma_f32_16x16x32_bf16(af[i], bfr[j], acc[i][j], 0, 0, 0);
    __syncthreads();
  }

  size_t obase = (size_t)((long long)blockIdx.y * d.Oy + (long long)blockIdx.z * d.Oz);
#pragma unroll
  for (int i = 0; i < MT; ++i) {
#pragma unroll
    for (int j = 0; j < NT; ++j) {
      int col = bn0 + wn * NT * 16 + j * 16 + ln;
      float bia = d.bias ? d.bias[col] : 0.0f;
#pragma unroll
      for (int r = 0; r < 4; ++r) {
        int row = bm0 + wm * MT * 16 + i * 16 + qd * 4 + r;
        float v = acc[i][j][r] + bia;
        if (d.epi == 2) v = v * sigm(v);
        size_t oi = obase + (size_t)row * d.ldo + col;
        if (d.epi == 0) ((float*)d.out)[oi] = v;
        else ((unsigned short*)d.out)[oi] = f2bf(v);
      }
    }
  }
}

// ---------- flash attention, std MHSA ----------
__global__ __launch_bounds__(256) void flash_attn_kernel(
    const unsigned short* __restrict__ QKVM, const unsigned short* __restrict__ VTB,
    unsigned short* __restrict__ out) {
  __shared__ __align__(16) unsigned short Ks[128*64];
  __shared__ __align__(16) unsigned short Vts[64*128];
  __shared__ __align__(16) unsigned short Pw[4][16*128];
  int h = blockIdx.x, b = blockIdx.y, qt = blockIdx.z;
  int tid = threadIdx.x, lane = tid & 63, w = tid >> 6;
  int ln = lane & 15, qd = lane >> 4;

  const unsigned short* Qbase = QKVM + ((size_t)(b*1024 + qt*128 + w*32))*2560 + h*64;
  v8bf aq[2][2];
#pragma unroll
  for (int i = 0; i < 2; ++i)
#pragma unroll
    for (int s = 0; s < 2; ++s)
      aq[i][s] = *(const v8bf*)(Qbase + (size_t)(i*16 + ln)*2560 + s*32 + qd*8);

  v4f o_acc[2][4];
  float l_part[2][4];
#pragma unroll
  for (int i = 0; i < 2; ++i)
#pragma unroll
    for (int dn = 0; dn < 4; ++dn) o_acc[i][dn] = (v4f){0.f,0.f,0.f,0.f};
#pragma unroll
  for (int i = 0; i < 2; ++i)
#pragma unroll
    for (int r = 0; r < 4; ++r) l_part[i][r] = 0.f;

  const unsigned short* Kg = QKVM + 512 + (size_t)(b*1024)*2560 + h*64;
  const unsigned short* Vg = VTB + ((size_t)(b*512) + h*64)*1024;

  for (int kt = 0; kt < 8; ++kt) {
#pragma unroll
    for (int it = 0; it < 4; ++it) {
      int c = it*256 + tid;
      async16(Kg + (size_t)(kt*128 + (c >> 3))*2560 + (((c & 7) ^ ((c >> 3) & 7)) << 3),
              Ks + c*8);
    }
#pragma unroll
    for (int it = 0; it < 4; ++it) {
      int c = it*256 + tid;
      async16(Vg + (size_t)(c >> 4)*1024 + kt*128 + ((((c & 15) ^ ((c >> 4) & 7))) << 3),
              Vts + c*8);
    }
    __syncthreads();

#pragma unroll
    for (int i = 0; i < 2; ++i) {
      v4f sc[8];
#pragma unroll
      for (int n = 0; n < 8; ++n) {
        v4f a = (v4f){0.f,0.f,0.f,0.f};
#pragma unroll
        for (int s = 0; s < 2; ++s) {
          v8bf kb = *(const v8bf*)(Ks + (n*16 + ln)*64 + (((s*4 + qd) ^ (ln & 7)) << 3));
          a = __builtin_amdgcn_mfma_f32_16x16x32_bf16(aq[i][s], kb, a, 0, 0, 0);
        }
        sc[n] = a;
      }
#pragma unroll
      for (int r = 0; r < 4; ++r) {
        int row7 = (qd*4 + r) & 7;
        float acc_l = 0.f;
#pragma unroll
        for (int n = 0; n < 8; ++n) {
          float p = exp2f(sc[n][r]);
          acc_l += p;
          Pw[w][(qd*4 + r)*128 + (((n*2 + (ln >> 3)) ^ row7) << 3) + (ln & 7)] = f2bf_trunc(p);
        }
        l_part[i][r] += acc_l;
      }
#pragma unroll
      for (int dn = 0; dn < 4; ++dn) {
        v4f a = o_acc[i][dn];
#pragma unroll
        for (int ks2 = 0; ks2 < 4; ++ks2) {
          int phys = (((ks2*4 + qd) ^ (ln & 7)) << 3);
          v8bf pf = *(const v8bf*)(&Pw[w][ln*128 + phys]);
          v8bf vf = *(const v8bf*)(Vts + (dn*16 + ln)*128 + phys);
          a = __builtin_amdgcn_mfma_f32_16x16x32_bf16(pf, vf, a, 0, 0, 0);
        }
        o_acc[i][dn] = a;
      }
    }
    __syncthreads();
  }

  unsigned short* ob = out + ((size_t)(b*1024 + qt*128 + w*32))*1024 + h*64;
#pragma unroll
  for (int i = 0; i < 2; ++i)
#pragma unroll
    for (int r = 0; r < 4; ++r) {
      float l = l_part[i][r];
      l += __shfl_xor(l, 1); l += __shfl_xor(l, 2);
      l += __shfl_xor(l, 4); l += __shfl_xor(l, 8);
      float rinv = 1.0f / l;
#pragma unroll
      for (int dn = 0; dn < 4; ++dn)
        ob[(size_t)(i*16 + qd*4 + r)*1024 + dn*16 + ln] = f2bf(o_acc[i][dn][r] * rinv);
    }
}

// ---------- row softmax over bf16 logits ----------
__global__ __launch_bounds__(256) void softmax_bf16_kernel(
    const unsigned short* __restrict__ S, unsigned short* __restrict__ P, int nrows) {
  int row = blockIdx.x * 4 + (threadIdx.x >> 6);
  if (row >= nrows) return;
  int l = threadIdx.x & 63;
  const ushort4* sp = (const ushort4*)(S + (size_t)row * 1024);
  float v[16];
  float m = -1e30f;
#pragma unroll
  for (int t = 0; t < 4; ++t) {
    ushort4 u = sp[t*64 + l];
    v[t*4+0] = bf2f(u.x); v[t*4+1] = bf2f(u.y); v[t*4+2] = bf2f(u.z); v[t*4+3] = bf2f(u.w);
    m = fmaxf(m, fmaxf(fmaxf(v[t*4], v[t*4+1]), fmaxf(v[t*4+2], v[t*4+3])));
  }
#pragma unroll
  for (int o = 32; o; o >>= 1) m = fmaxf(m, __shfl_xor(m, o));
  float sum = 0.f;
#pragma unroll
  for (int t = 0; t < 16; ++t) { v[t] = __expf(v[t] - m); sum += v[t]; }
#pragma unroll
  for (int o = 32; o; o >>= 1) sum += __shfl_xor(sum, o);
  float r = 1.0f / sum;
  ushort4* p = (ushort4*)(P + (size_t)row * 1024);
#pragma unroll
  for (int t = 0; t < 4; ++t)
    p[t*64 + l] = make_ushort4(f2bf_trunc(v[t*4]*r), f2bf_trunc(v[t*4+1]*r),
                               f2bf_trunc(v[t*4+2]*r), f2bf_trunc(v[t*4+3]*r));
}

// ---------- stats over (B,S,C) bf16 per (b,group) ----------
__global__ __launch_bounds__(256) void gn_stats_bf16_kernel(
    const unsigned short* __restrict__ t, float* __restrict__ stats) {
  int b = blockIdx.x >> 5, grp = blockIdx.x & 31;
  float s = 0.f, s2 = 0.f;
#pragma unroll
  for (int j = 0; j < 4; ++j) {
    int sI = threadIdx.x + j*256;
    const unsigned short* p = t + ((size_t)(b*1024 + sI))*512 + grp*16;
    uint4 a = *(const uint4*)p, c2 = *(const uint4*)(p + 8);
    unsigned int ww[8] = {a.x,a.y,a.z,a.w,c2.x,c2.y,c2.z,c2.w};
#pragma unroll
    for (int k = 0; k < 8; ++k) {
      float lo = bf2f((unsigned short)(ww[k] & 0xffff));
      float hi = bf2f((unsigned short)(ww[k] >> 16));
      s += lo + hi; s2 += lo*lo + hi*hi;
    }
  }
#pragma unroll
  for (int o = 32; o; o >>= 1) { s += __shfl_xor(s, o); s2 += __shfl_xor(s2, o); }
  __shared__ float rs[4], rs2[4];
  int w = threadIdx.x >> 6;
  if ((threadIdx.x & 63) == 0) { rs[w] = s; rs2[w] = s2; }
  __syncthreads();
  if (threadIdx.x == 0) {
    float ts = rs[0]+rs[1]+rs[2]+rs[3], ts2 = rs2[0]+rs2[1]+rs2[2]+rs2[3];
    float mu = ts * (1.0f/16384.0f);
    float var = ts2 * (1.0f/16384.0f) - mu*mu;
    stats[(b*32+grp)*2] = mu; stats[(b*32+grp)*2+1] = rsqrtf(var + 1e-6f);
  }
}

// ---------- GN(post) + residual, bf16 (B,S,C) -> f32 (B,C,S), LDS-tiled ----------
__global__ __launch_bounds__(256) void final_out_kernel(
    const unsigned short* __restrict__ fin, const float* __restrict__ stats,
    const float* __restrict__ g, const float* __restrict__ be,
    const float* __restrict__ x, float* __restrict__ out) {
  __shared__ float t[64][65];
  int s0 = blockIdx.x * 64, c0 = blockIdx.y * 64, b = blockIdx.z;
  int tx = threadIdx.x & 63, ty = threadIdx.x >> 6;
#pragma unroll
  for (int i = 0; i < 16; ++i) {
    int s = ty + i*4;
    t[s][tx] = bf2f(fin[((size_t)(b*1024 + s0 + s))*512 + c0 + tx]);
  }
  __syncthreads();
#pragma unroll
  for (int i = 0; i < 16; ++i) {
    int c = ty + i*4;
    int cc = c0 + c, grp = cc >> 4;
    float mu = stats[(b*32+grp)*2], rstd = stats[(b*32+grp)*2+1];
    float gg = g[cc], bb = be[cc];
    size_t oi = ((size_t)(b*512 + cc))*1024 + s0 + tx;
    out[oi] = (t[tx][c] - mu)*rstd*gg + bb + x[oi];
  }
}

// =====================================================================
static void launch_gemm128(hipStream_t st, const unsigned short* A, const unsigned short* B,
                           void* out, const float* bias,
                           int M, int N, int K, int lda, int ldb, int ldo, int epi,
                           long long Ay, long long Az, long long By, long long Bz,
                           long long Oy, long long Oz, int gy, int gz) {
  GemmDesc d{A, B, out, bias, M, N, K, lda, ldb, ldo, epi, Ay, Az, By, Bz, Oy, Oz};
  gemm_tile_kernel<128,128><<<dim3((M/128)*(N/128), gy, gz), dim3(256), 0, st>>>(d);
}
static void launch_gemm64(hipStream_t st, const unsigned short* A, const unsigned short* B,
                          void* out, const float* bias,
                          int M, int N, int K, int lda, int ldb, int ldo, int epi) {
  GemmDesc d{A, B, out, bias, M, N, K, lda, ldb, ldo, epi, 0,0,0,0,0,0};
  gemm_tile_kernel<128,64><<<dim3((M/128)*(N/64), 1, 1), dim3(256), 0, st>>>(d);
}

extern "C" void kernel_launch(void* const* d_in, const int* in_sizes, int n_in,
                              void* d_out, int out_size, void* d_ws, size_t ws_size,
                              hipStream_t stream) {
  const float* x      = (const float*)d_in[0];
  const float* pre_g  = (const float*)d_in[1];
  const float* pre_b  = (const float*)d_in[2];
  const float* norm_g = (const float*)d_in[3];
  const float* norm_b = (const float*)d_in[4];
  const float* post_g = (const float*)d_in[5];
  const float* post_b = (const float*)d_in[6];
  const float* pos    = (const float*)d_in[7];
  const float* sa_b1  = (const float*)d_in[9];
  const float* sa_b2  = (const float*)d_in[11];
  const float* sa_w3  = (const float*)d_in[12];
  const float* sa_b3  = (const float*)d_in[13];
  const float* ff_b1  = (const float*)d_in[24];
  const float* ff_b2  = (const float*)d_in[26];
  const float* out_w  = (const float*)d_in[27];
  const float* out_b  = (const float*)d_in[28];
  float* outp = (float*)d_out;

  char* ws = (char*)d_ws;
  size_t off = 0;
  auto alloc = [&](size_t bytes) -> void* {
    void* p = ws + off; off += (bytes + 255) & ~(size_t)255; return p;
  };
  float* STATS = (float*)alloc(4096);
  float* BC    = (float*)alloc(2048);               // folded bias
  unsigned short* HSB  = (unsigned short*)alloc(8388608);
  unsigned short* A1   = (unsigned short*)alloc(1048576);
  unsigned short* IM2  = (unsigned short*)alloc(9437184);
  unsigned short* A2   = (unsigned short*)alloc(1048576);
  unsigned short* SHB  = (unsigned short*)alloc(8388608);
  unsigned short* MSHB = (unsigned short*)alloc(8388608);
  unsigned short* WBF  = (unsigned short*)alloc(6291456);
  unsigned short* WCOMB= (unsigned short*)alloc(524288);    // (512,512) folded FF2*OW
  unsigned short* QKVM = (unsigned short*)alloc(41943040);  // (B*S,2560)
  unsigned short* QM   = (unsigned short*)alloc(8388608);   // (B*S,512) Q0|Q1
  unsigned short* VTB  = (unsigned short*)alloc(8388608);
  unsigned short* VMT  = (unsigned short*)alloc(8388608);
  unsigned short* SBUF = (unsigned short*)alloc(33554432);  // 2 branches
  unsigned short* PBUF = (unsigned short*)alloc(33554432);
  unsigned short* COMB = (unsigned short*)alloc(16777216);
  unsigned short* FFMID= (unsigned short*)alloc(8388608);
  unsigned short* FINALB=(unsigned short*)alloc(8388608);

  // WBF element offsets
  const int OQKVM=0, OQM=1310720, OFF1=1572864, OFF2T=2097152,
            OOW=2359296, OW1=2621440, OW2R=2654208;

  // 1) GN(pre)+pos -> HSB + GN(norm) stats
  gn_pre_kernel<<<dim3(256), dim3(256), 0, stream>>>(x, pre_g, pre_b, pos, HSB, STATS);
  // 2) weights -> bf16
  {
    WCvtArgs a;
    const float LG2E = 1.4426950408889634f;
    const int   srcIdx[15] = {14,15,16, 18,21,19,22, 17,20, 23,27, 8, 0 /*unused pad*/, 10, 25};
    const int   dofs[15]   = {0, 262144, 524288,
                              786432, 917504, 1048576, 1179648,
                              OQM, OQM+131072,
                              OFF1, OOW, OW1, 0, OW2R, OFF2T};
    const int   ns[15]     = {262144,262144,262144, 131072,131072,131072,131072,
                              131072,131072, 524288,262144, 32768, 0, 36864, 262144};
    const float sc[15]     = {0.125f*LG2E,1.f,1.f, 1.f,1.f,1.f,1.f,
                              0.0625f,0.0625f, 1.f,1.f, 1.f, 0.f, 1.f, 1.f};
    for (int i = 0; i < 15; ++i) { a.w[i].src = (const float*)d_in[srcIdx[i]]; a.w[i].dstOff = dofs[i]; a.w[i].n = ns[i]; a.w[i].scale = sc[i]; }
    wconvert_kernel<<<dim3(2048, 15), dim3(256), 0, stream>>>(a, WBF);
  }
  // 2b) fold FF2+OW:  WCOMB[n,k] = sum_j out_w[n,j]*ff_w2[j,k];  BC = out_w@ff_b2 + out_b
  {
    GemmDesc d{WBF+OOW, WBF+OFF2T, WCOMB, nullptr, 512, 512, 512, 512, 512, 512, 1, 0,0,0,0,0,0};
    gemm_tile_kernel<128,128><<<dim3(16, 1, 1), dim3(256), 0, stream>>>(d);
  }
  bias_fold_kernel<<<dim3(2), dim3(256), 0, stream>>>(out_w, ff_b2, out_b, BC);
  // 3) spatial gate chain
  launch_gemm64(stream, HSB, WBF+OW1,  A1, sa_b1, 8192, 64, 512, 512, 512, 64, 2);
  im2col_kernel<<<dim3(1024), dim3(256), 0, stream>>>(A1, IM2);
  launch_gemm64(stream, IM2, WBF+OW2R, A2, sa_b2, 8192, 64, 576, 576, 576, 64, 2);
  // 4) gate + norm
  gate_norm_kernel<<<dim3(256, 8), dim3(256), 0, stream>>>(HSB, A2, sa_w3, sa_b3, STATS, norm_g, norm_b, SHB, MSHB);

  // 5) projections
  launch_gemm128(stream, SHB,  WBF+OQKVM, QKVM, nullptr, 8192, 2560, 512, 512, 512, 2560, 1, 0,0,0,0,0,0, 1,1);
  launch_gemm128(stream, MSHB, WBF+OQM,   QM,   nullptr, 8192, 512,  512, 512, 512, 512,  1, 0,0,0,0,0,0, 1,1);

  // 6) V transposes
  transpose2_kernel<<<dim3(16, 8, 16), dim3(256), 0, stream>>>(QKVM, VTB, VMT);

  // 7) std MHSA flash -> COMB[:, 0:512]
  flash_attn_kernel<<<dim3(8, 8, 8), dim3(256), 0, stream>>>(QKVM, VTB, COMB);

  // 8) both multi-scale branches, batched (z = branch)
  launch_gemm128(stream, QM, QKVM + 1536, SBUF, nullptr,
                 1024, 1024, 256, 512, 2560, 1024, 1,
                 1024LL*512, 256, 1024LL*2560, 256, 1024LL*1024, 8388608, 8, 2);
  softmax_bf16_kernel<<<dim3(4096), dim3(256), 0, stream>>>(SBUF, PBUF, 16384);
  launch_gemm128(stream, PBUF, VMT, COMB + 512, nullptr,
                 1024, 256, 1024, 1024, 1024, 1024, 1,
                 1024LL*1024, 8388608, 512LL*1024, 256LL*1024, 1024LL*1024, 256, 8, 2);

  // 9) FF (folded FF2+OW)
  launch_gemm128(stream, COMB,  WBF+OFF1, FFMID,  ff_b1, 8192, 512, 1024, 1024, 1024, 512, 2, 0,0,0,0,0,0, 1,1);
  launch_gemm128(stream, FFMID, WCOMB,    FINALB, BC,    8192, 512, 512,  512,  512,  512, 1, 0,0,0,0,0,0, 1,1);

  // 10) GN(post) + residual
  gn_stats_bf16_kernel<<<dim3(256), dim3(256), 0, stream>>>(FINALB, STATS);
  final_out_kernel<<<dim3(16, 8, 8), dim3(256), 0, stream>>>(FINALB, STATS, post_g, post_b, x, outp);

  (void)in_sizes; (void)n_in; (void)out_size; (void)ws_size;
}

// Round 7
// 406.664 us; speedup vs baseline: 3.9811x; 1.1246x over previous
//
#include <hip/hip_runtime.h>
#include <hip/hip_bf16.h>
#include <math.h>

typedef __attribute__((ext_vector_type(8))) __bf16 v8bf;
typedef __attribute__((ext_vector_type(4))) float v4f;

__device__ __forceinline__ unsigned short f2bf(float f) {
  union { float f; unsigned int u; } a; a.f = f;
  unsigned int r = a.u + 0x7fffu + ((a.u >> 16) & 1u);
  return (unsigned short)(r >> 16);
}
__device__ __forceinline__ unsigned short f2bf_trunc(float f) {
  union { float f; unsigned int u; } a; a.f = f;
  return (unsigned short)(a.u >> 16);
}
__device__ __forceinline__ float bf2f(unsigned short u) {
  union { unsigned int i; float f; } a; a.i = ((unsigned int)u) << 16; return a.f;
}
__device__ __forceinline__ float sigm(float x) { return 1.0f / (1.0f + __expf(-x)); }

__device__ __forceinline__ void async16(const void* g, void* l) {
  __builtin_amdgcn_global_load_lds(
      (const __attribute__((address_space(1))) unsigned int*)g,
      (__attribute__((address_space(3))) unsigned int*)l, 16, 0, 0);
}

// ---------- GN(pre)+pos -> HSB bf16 token-major; fused GN(norm) stats ----------
__global__ __launch_bounds__(256) void gn_pre_kernel(
    const float* __restrict__ x, const float* __restrict__ g, const float* __restrict__ be,
    const float* __restrict__ pos, unsigned short* __restrict__ hsb, float* __restrict__ stats) {
  __shared__ float L[16384];
  __shared__ float rs[4], rs2[4], mr[2];
  int b = blockIdx.x >> 5, grp = blockIdx.x & 31;
  const float4* base = (const float4*)(x + ((size_t)b*512 + grp*16)*1024);
  float4* L4 = (float4*)L;
  int w = threadIdx.x >> 6;
  float s = 0.f, s2 = 0.f;
  for (int i = threadIdx.x; i < 4096; i += 256) {
    float4 v = base[i];
    L4[i] = v;
    s += v.x + v.y + v.z + v.w;
    s2 += v.x*v.x + v.y*v.y + v.z*v.z + v.w*v.w;
  }
#pragma unroll
  for (int o = 32; o; o >>= 1) { s += __shfl_xor(s, o); s2 += __shfl_xor(s2, o); }
  if ((threadIdx.x & 63) == 0) { rs[w] = s; rs2[w] = s2; }
  __syncthreads();
  if (threadIdx.x == 0) {
    float ts = rs[0]+rs[1]+rs[2]+rs[3], ts2 = rs2[0]+rs2[1]+rs2[2]+rs2[3];
    float mu = ts * (1.0f/16384.0f);
    float var = ts2 * (1.0f/16384.0f) - mu*mu;
    mr[0] = mu; mr[1] = rsqrtf(var + 1e-6f);
  }
  __syncthreads();
  float mu = mr[0], rstd = mr[1];
  const float4* pb = (const float4*)(pos + (size_t)grp*16*1024);
  float ns = 0.f, ns2 = 0.f;
  for (int i = threadIdx.x; i < 4096; i += 256) {
    float4 v = L4[i], p = pb[i];
    int c = grp*16 + (i >> 8);
    float gg = g[c], bb = be[c];
    float4 o;
    o.x = (v.x - mu)*rstd*gg + bb + p.x;
    o.y = (v.y - mu)*rstd*gg + bb + p.y;
    o.z = (v.z - mu)*rstd*gg + bb + p.z;
    o.w = (v.w - mu)*rstd*gg + bb + p.w;
    L4[i] = o;
    ns += o.x + o.y + o.z + o.w;
    ns2 += o.x*o.x + o.y*o.y + o.z*o.z + o.w*o.w;
  }
#pragma unroll
  for (int o = 32; o; o >>= 1) { ns += __shfl_xor(ns, o); ns2 += __shfl_xor(ns2, o); }
  if ((threadIdx.x & 63) == 0) { rs[w] = ns; rs2[w] = ns2; }
  __syncthreads();
  if (threadIdx.x == 0) {
    float ts = rs[0]+rs[1]+rs[2]+rs[3], ts2 = rs2[0]+rs2[1]+rs2[2]+rs2[3];
    float nmu = ts * (1.0f/16384.0f);
    float nvar = ts2 * (1.0f/16384.0f) - nmu*nmu;
    stats[(b*32+grp)*2] = nmu; stats[(b*32+grp)*2+1] = rsqrtf(nvar + 1e-6f);
  }
#pragma unroll
  for (int j = 0; j < 4; ++j) {
    int sI = threadIdx.x + j*256;
    unsigned int wd[8];
#pragma unroll
    for (int c = 0; c < 8; ++c) {
      unsigned int lo = f2bf(L[(2*c)*1024 + sI]);
      unsigned int hi = f2bf(L[(2*c+1)*1024 + sI]);
      wd[c] = lo | (hi << 16);
    }
    size_t oo = (size_t)(b*1024 + sI)*512 + grp*16;
    *(uint4*)(hsb + oo)     = make_uint4(wd[0], wd[1], wd[2], wd[3]);
    *(uint4*)(hsb + oo + 8) = make_uint4(wd[4], wd[5], wd[6], wd[7]);
  }
}

// ---------- im2col ----------
__global__ __launch_bounds__(256) void im2col_kernel(
    const unsigned short* __restrict__ a1, unsigned short* __restrict__ im2) {
  int row0 = blockIdx.x * 8;
#pragma unroll
  for (int it = 0; it < 3; ++it) {
    int cc = it*256 + threadIdx.x;
    if (cc >= 576) break;
    int rl = cc / 72, rr = cc - rl*72;
    int tap = rr >> 3, ch8 = rr & 7;
    int row = row0 + rl;
    int bb = row >> 10, s = row & 1023;
    int y = s >> 5, xx0 = s & 31;
    int yy = y + tap/3 - 1, xx = xx0 + tap%3 - 1;
    ushort4 v0 = make_ushort4(0,0,0,0), v1 = make_ushort4(0,0,0,0);
    if ((unsigned)yy < 32u && (unsigned)xx < 32u) {
      const unsigned short* src = a1 + ((size_t)(bb*1024 + yy*32 + xx))*64 + ch8*8;
      v0 = *(const ushort4*)src; v1 = *(const ushort4*)(src + 4);
    }
    unsigned short* dst = im2 + (size_t)row*576 + tap*64 + ch8*8;
    *(ushort4*)dst = v0; *(ushort4*)(dst + 4) = v1;
  }
}

// ---------- gate(conv3 fused) + GN(norm) ----------
__global__ __launch_bounds__(256) void gate_norm_kernel(
    const unsigned short* __restrict__ hsb, const unsigned short* __restrict__ a2,
    const float* __restrict__ w3, const float* __restrict__ b3,
    const float* __restrict__ stats, const float* __restrict__ g,
    const float* __restrict__ be,
    unsigned short* __restrict__ sh, unsigned short* __restrict__ msh) {
  int b = blockIdx.y;
  int s = blockIdx.x * 4 + (threadIdx.x >> 6);
  int oct = threadIdx.x & 63;
  int c0 = oct * 8;
  int grp = c0 >> 4;
  float part = bf2f(a2[((size_t)(b*1024) + s)*64 + oct]) * w3[oct];
#pragma unroll
  for (int o = 32; o; o >>= 1) part += __shfl_xor(part, o);
  float wgt = sigm(part + b3[0]);
  float mu = stats[(b*32 + grp)*2], rstd = stats[(b*32 + grp)*2 + 1];
  size_t o = (size_t)(b*1024 + s)*512 + c0;
  ushort4 u0 = *(const ushort4*)(hsb + o), u1 = *(const ushort4*)(hsb + o + 4);
  unsigned short uu[8] = {u0.x,u0.y,u0.z,u0.w,u1.x,u1.y,u1.z,u1.w};
  unsigned short so[8], mo[8];
#pragma unroll
  for (int j = 0; j < 8; ++j) {
    float v = bf2f(uu[j]);
    so[j] = f2bf((v - mu)*rstd*g[c0+j] + be[c0+j]);
    mo[j] = f2bf(v * wgt);
  }
  *(ushort4*)(sh + o)     = make_ushort4(so[0], so[1], so[2], so[3]);
  *(ushort4*)(sh + o + 4) = make_ushort4(so[4], so[5], so[6], so[7]);
  *(ushort4*)(msh + o)     = make_ushort4(mo[0], mo[1], mo[2], mo[3]);
  *(ushort4*)(msh + o + 4) = make_ushort4(mo[4], mo[5], mo[6], mo[7]);
}

// ---------- weight conversions ----------
struct WCvt { const float* src; int dstOff; int n; float scale; };
struct WCvtArgs { WCvt w[15]; };
__global__ __launch_bounds__(256) void wconvert_kernel(WCvtArgs a, unsigned short* __restrict__ dst) {
  WCvt e = a.w[blockIdx.y];
  int i = blockIdx.x * 256 + threadIdx.x;
  if (i >= e.n) return;
  if (blockIdx.y == 13) {
    int oc = i / 576, r = i - oc*576;
    int tap = r >> 6, ic = r & 63;
    dst[e.dstOff + i] = f2bf(e.src[(oc*64 + ic)*9 + tap]);
  } else if (blockIdx.y == 14) {
    dst[e.dstOff + i] = f2bf(e.src[(i & 511)*512 + (i >> 9)]);
  } else {
    dst[e.dstOff + i] = f2bf(e.src[i] * e.scale);
  }
}

__global__ __launch_bounds__(256) void bias_fold_kernel(
    const float* __restrict__ ow, const float* __restrict__ b2,
    const float* __restrict__ ob, float* __restrict__ bc) {
  int n = blockIdx.x * 256 + threadIdx.x;
  float s = ob[n];
  const float* r = ow + (size_t)n * 512;
#pragma unroll 8
  for (int j = 0; j < 512; ++j) s += r[j] * b2[j];
  bc[n] = s;
}

// ---------- merged V transposes ----------
__global__ __launch_bounds__(256) void transpose2_kernel(
    const unsigned short* __restrict__ qkvm,
    unsigned short* __restrict__ vtb, unsigned short* __restrict__ vmt) {
  __shared__ unsigned short t[64][65];
  int s0 = blockIdx.x * 64, c0 = blockIdx.y * 64;
  int z = blockIdx.z, b = z & 7;
  const unsigned short* in = qkvm + (z >= 8 ? 2048 : 1024);
  unsigned short* out = (z >= 8) ? vmt : vtb;
  int tx = threadIdx.x & 63, ty = threadIdx.x >> 6;
#pragma unroll
  for (int i = 0; i < 16; ++i) {
    int s = ty + i*4;
    t[s][tx] = in[((size_t)(b*1024 + s0 + s))*2560 + c0 + tx];
  }
  __syncthreads();
#pragma unroll
  for (int i = 0; i < 16; ++i) {
    int c = ty + i*4;
    out[((size_t)b*512 + c0 + c)*1024 + s0 + tx] = t[tx][c];
  }
}

// ---------- tiled GEMM: BK=64, swizzled LDS, XCD-aware tile mapping ----------
struct GemmDesc {
  const unsigned short* A; const unsigned short* B; void* out; const float* bias;
  int M, N, K, lda, ldb, ldo, epi;
  long long Ay, Az, By, Bz, Oy, Oz;
};

template<int BM, int BN>
__global__ __launch_bounds__(256) void gemm_tile_kernel(GemmDesc d) {
  constexpr int WGM = (BN >= 128) ? 2 : 4;
  constexpr int WGN = 4 / WGM;
  constexpr int MT = BM / (16 * WGM);
  constexpr int NT = BN / (16 * WGN);
  constexpr int AIT = (BM * 8) / 256;
  constexpr int BIT = (BN * 8) / 256;
  __shared__ __align__(16) unsigned short As[BM * 64];
  __shared__ __align__(16) unsigned short Bs[BN * 64];

  int ntx = d.N / BN, mtx = d.M / BM;
  int bmt, bnt;
  if ((mtx & 7) == 0) {
    int xcd = blockIdx.x & 7, j = blockIdx.x >> 3;
    int mpx = mtx >> 3;
    bmt = xcd * mpx + (j % mpx);
    bnt = j / mpx;
  } else {
    bmt = blockIdx.x / ntx; bnt = blockIdx.x % ntx;
  }
  int bm0 = bmt * BM, bn0 = bnt * BN;
  const unsigned short* A = d.A + (long long)blockIdx.y * d.Ay
      + (long long)blockIdx.z * d.Az + (size_t)bm0 * d.lda;
  const unsigned short* B = d.B + (long long)blockIdx.y * d.By
      + (long long)blockIdx.z * d.Bz + (size_t)bn0 * d.ldb;
  int tid = threadIdx.x, lane = tid & 63, w = tid >> 6;
  int wm = (WGN == 2) ? (w >> 1) : w;
  int wn = (WGN == 2) ? (w & 1) : 0;
  int ln = lane & 15, qd = lane >> 4;

  v4f acc[MT][NT];
#pragma unroll
  for (int i = 0; i < MT; ++i)
#pragma unroll
    for (int j = 0; j < NT; ++j) acc[i][j] = (v4f){0.f, 0.f, 0.f, 0.f};

  int nks = d.K >> 6;
  for (int ks = 0; ks < nks; ++ks) {
    int kof = ks * 64;
#pragma unroll
    for (int it = 0; it < AIT; ++it) {
      int c = it * 256 + tid;
      int row = c >> 3, ch = c & 7;
      async16(A + (size_t)row * d.lda + ((ch ^ (row & 7)) << 3) + kof, As + c * 8);
    }
#pragma unroll
    for (int it = 0; it < BIT; ++it) {
      int c = it * 256 + tid;
      int row = c >> 3, ch = c & 7;
      async16(B + (size_t)row * d.ldb + ((ch ^ (row & 7)) << 3) + kof, Bs + c * 8);
    }
    __syncthreads();
#pragma unroll
    for (int k2 = 0; k2 < 2; ++k2) {
      v8bf af[MT], bfr[NT];
#pragma unroll
      for (int i = 0; i < MT; ++i) {
        int row = wm * MT * 16 + i * 16 + ln;
        af[i] = *(const v8bf*)(As + row * 64 + (((k2*4 + qd) ^ (ln & 7)) << 3));
      }
#pragma unroll
      for (int j = 0; j < NT; ++j) {
        int row = wn * NT * 16 + j * 16 + ln;
        bfr[j] = *(const v8bf*)(Bs + row * 64 + (((k2*4 + qd) ^ (ln & 7)) << 3));
      }
#pragma unroll
      for (int i = 0; i < MT; ++i)
#pragma unroll
        for (int j = 0; j < NT; ++j)
          acc[i][j] = __builtin_amdgcn_mfma_f32_16x16x32_bf16(af[i], bfr[j], acc[i][j], 0, 0, 0);
    }
    __syncthreads();
  }

  size_t obase = (size_t)((long long)blockIdx.y * d.Oy + (long long)blockIdx.z * d.Oz);
#pragma unroll
  for (int i = 0; i < MT; ++i) {
#pragma unroll
    for (int j = 0; j < NT; ++j) {
      int col = bn0 + wn * NT * 16 + j * 16 + ln;
      float bia = d.bias ? d.bias[col] : 0.0f;
#pragma unroll
      for (int r = 0; r < 4; ++r) {
        int row = bm0 + wm * MT * 16 + i * 16 + qd * 4 + r;
        float v = acc[i][j][r] + bia;
        if (d.epi == 2) v = v * sigm(v);
        size_t oi = obase + (size_t)row * d.ldo + col;
        if (d.epi == 0) ((float*)d.out)[oi] = v;
        else ((unsigned short*)d.out)[oi] = f2bf(v);
      }
    }
  }
}

// ---------- flash attention, 512 threads (8 waves x 16 q-rows) ----------
__global__ __launch_bounds__(512) void flash_attn_kernel(
    const unsigned short* __restrict__ QKVM, const unsigned short* __restrict__ VTB,
    unsigned short* __restrict__ out) {
  __shared__ __align__(16) unsigned short Ks[128*64];
  __shared__ __align__(16) unsigned short Vts[64*128];
  __shared__ __align__(16) unsigned short Pw[8][16*128];
  int h = blockIdx.x, b = blockIdx.y, qt = blockIdx.z;
  int tid = threadIdx.x, lane = tid & 63, w = tid >> 6;
  int ln = lane & 15, qd = lane >> 4;

  const unsigned short* Qbase = QKVM + ((size_t)(b*1024 + qt*128 + w*16))*2560 + h*64;
  v8bf aq[2];
#pragma unroll
  for (int s = 0; s < 2; ++s)
    aq[s] = *(const v8bf*)(Qbase + (size_t)ln*2560 + s*32 + qd*8);

  v4f o_acc[4];
  float l_part[4];
#pragma unroll
  for (int dn = 0; dn < 4; ++dn) o_acc[dn] = (v4f){0.f,0.f,0.f,0.f};
#pragma unroll
  for (int r = 0; r < 4; ++r) l_part[r] = 0.f;

  const unsigned short* Kg = QKVM + 512 + (size_t)(b*1024)*2560 + h*64;
  const unsigned short* Vg = VTB + ((size_t)(b*512) + h*64)*1024;

  for (int kt = 0; kt < 8; ++kt) {
#pragma unroll
    for (int it = 0; it < 2; ++it) {
      int c = it*512 + tid;
      async16(Kg + (size_t)(kt*128 + (c >> 3))*2560 + (((c & 7) ^ ((c >> 3) & 7)) << 3),
              Ks + c*8);
    }
#pragma unroll
    for (int it = 0; it < 2; ++it) {
      int c = it*512 + tid;
      async16(Vg + (size_t)(c >> 4)*1024 + kt*128 + ((((c & 15) ^ ((c >> 4) & 7))) << 3),
              Vts + c*8);
    }
    __syncthreads();

    v4f sc[8];
#pragma unroll
    for (int n = 0; n < 8; ++n) {
      v4f a = (v4f){0.f,0.f,0.f,0.f};
#pragma unroll
      for (int s = 0; s < 2; ++s) {
        v8bf kb = *(const v8bf*)(Ks + (n*16 + ln)*64 + (((s*4 + qd) ^ (ln & 7)) << 3));
        a = __builtin_amdgcn_mfma_f32_16x16x32_bf16(aq[s], kb, a, 0, 0, 0);
      }
      sc[n] = a;
    }
#pragma unroll
    for (int r = 0; r < 4; ++r) {
      int row7 = (qd*4 + r) & 7;
      float acc_l = 0.f;
#pragma unroll
      for (int n = 0; n < 8; ++n) {
        float p = exp2f(sc[n][r]);
        acc_l += p;
        Pw[w][(qd*4 + r)*128 + (((n*2 + (ln >> 3)) ^ row7) << 3) + (ln & 7)] = f2bf_trunc(p);
      }
      l_part[r] += acc_l;
    }
#pragma unroll
    for (int dn = 0; dn < 4; ++dn) {
      v4f a = o_acc[dn];
#pragma unroll
      for (int ks2 = 0; ks2 < 4; ++ks2) {
        int phys = (((ks2*4 + qd) ^ (ln & 7)) << 3);
        v8bf pf = *(const v8bf*)(&Pw[w][ln*128 + phys]);
        v8bf vf = *(const v8bf*)(Vts + (dn*16 + ln)*128 + phys);
        a = __builtin_amdgcn_mfma_f32_16x16x32_bf16(pf, vf, a, 0, 0, 0);
      }
      o_acc[dn] = a;
    }
    __syncthreads();
  }

  unsigned short* ob = out + ((size_t)(b*1024 + qt*128 + w*16))*1024 + h*64;
#pragma unroll
  for (int r = 0; r < 4; ++r) {
    float l = l_part[r];
    l += __shfl_xor(l, 1); l += __shfl_xor(l, 2);
    l += __shfl_xor(l, 4); l += __shfl_xor(l, 8);
    float rinv = 1.0f / l;
#pragma unroll
    for (int dn = 0; dn < 4; ++dn)
      ob[(size_t)(qd*4 + r)*1024 + dn*16 + ln] = f2bf(o_acc[dn][r] * rinv);
  }
}

// ---------- row softmax over bf16 logits ----------
__global__ __launch_bounds__(256) void softmax_bf16_kernel(
    const unsigned short* __restrict__ S, unsigned short* __restrict__ P, int nrows) {
  int row = blockIdx.x * 4 + (threadIdx.x >> 6);
  if (row >= nrows) return;
  int l = threadIdx.x & 63;
  const ushort4* sp = (const ushort4*)(S + (size_t)row * 1024);
  float v[16];
  float m = -1e30f;
#pragma unroll
  for (int t = 0; t < 4; ++t) {
    ushort4 u = sp[t*64 + l];
    v[t*4+0] = bf2f(u.x); v[t*4+1] = bf2f(u.y); v[t*4+2] = bf2f(u.z); v[t*4+3] = bf2f(u.w);
    m = fmaxf(m, fmaxf(fmaxf(v[t*4], v[t*4+1]), fmaxf(v[t*4+2], v[t*4+3])));
  }
#pragma unroll
  for (int o = 32; o; o >>= 1) m = fmaxf(m, __shfl_xor(m, o));
  float sum = 0.f;
#pragma unroll
  for (int t = 0; t < 16; ++t) { v[t] = __expf(v[t] - m); sum += v[t]; }
#pragma unroll
  for (int o = 32; o; o >>= 1) sum += __shfl_xor(sum, o);
  float r = 1.0f / sum;
  ushort4* p = (ushort4*)(P + (size_t)row * 1024);
#pragma unroll
  for (int t = 0; t < 4; ++t)
    p[t*64 + l] = make_ushort4(f2bf_trunc(v[t*4]*r), f2bf_trunc(v[t*4+1]*r),
                               f2bf_trunc(v[t*4+2]*r), f2bf_trunc(v[t*4+3]*r));
}

// ---------- stats over (B,S,C) bf16 per (b,group) ----------
__global__ __launch_bounds__(256) void gn_stats_bf16_kernel(
    const unsigned short* __restrict__ t, float* __restrict__ stats) {
  int b = blockIdx.x >> 5, grp = blockIdx.x & 31;
  float s = 0.f, s2 = 0.f;
#pragma unroll
  for (int j = 0; j < 4; ++j) {
    int sI = threadIdx.x + j*256;
    const unsigned short* p = t + ((size_t)(b*1024 + sI))*512 + grp*16;
    uint4 a = *(const uint4*)p, c2 = *(const uint4*)(p + 8);
    unsigned int ww[8] = {a.x,a.y,a.z,a.w,c2.x,c2.y,c2.z,c2.w};
#pragma unroll
    for (int k = 0; k < 8; ++k) {
      float lo = bf2f((unsigned short)(ww[k] & 0xffff));
      float hi = bf2f((unsigned short)(ww[k] >> 16));
      s += lo + hi; s2 += lo*lo + hi*hi;
    }
  }
#pragma unroll
  for (int o = 32; o; o >>= 1) { s += __shfl_xor(s, o); s2 += __shfl_xor(s2, o); }
  __shared__ float rs[4], rs2[4];
  int w = threadIdx.x >> 6;
  if ((threadIdx.x & 63) == 0) { rs[w] = s; rs2[w] = s2; }
  __syncthreads();
  if (threadIdx.x == 0) {
    float ts = rs[0]+rs[1]+rs[2]+rs[3], ts2 = rs2[0]+rs2[1]+rs2[2]+rs2[3];
    float mu = ts * (1.0f/16384.0f);
    float var = ts2 * (1.0f/16384.0f) - mu*mu;
    stats[(b*32+grp)*2] = mu; stats[(b*32+grp)*2+1] = rsqrtf(var + 1e-6f);
  }
}

// ---------- GN(post) + residual ----------
__global__ __launch_bounds__(256) void final_out_kernel(
    const unsigned short* __restrict__ fin, const float* __restrict__ stats,
    const float* __restrict__ g, const float* __restrict__ be,
    const float* __restrict__ x, float* __restrict__ out) {
  __shared__ float t[64][65];
  int s0 = blockIdx.x * 64, c0 = blockIdx.y * 64, b = blockIdx.z;
  int tx = threadIdx.x & 63, ty = threadIdx.x >> 6;
#pragma unroll
  for (int i = 0; i < 16; ++i) {
    int s = ty + i*4;
    t[s][tx] = bf2f(fin[((size_t)(b*1024 + s0 + s))*512 + c0 + tx]);
  }
  __syncthreads();
#pragma unroll
  for (int i = 0; i < 16; ++i) {
    int c = ty + i*4;
    int cc = c0 + c, grp = cc >> 4;
    float mu = stats[(b*32+grp)*2], rstd = stats[(b*32+grp)*2+1];
    float gg = g[cc], bb = be[cc];
    size_t oi = ((size_t)(b*512 + cc))*1024 + s0 + tx;
    out[oi] = (t[tx][c] - mu)*rstd*gg + bb + x[oi];
  }
}

// =====================================================================
static void launch_gemm128(hipStream_t st, const unsigned short* A, const unsigned short* B,
                           void* out, const float* bias,
                           int M, int N, int K, int lda, int ldb, int ldo, int epi,
                           long long Ay, long long Az, long long By, long long Bz,
                           long long Oy, long long Oz, int gy, int gz) {
  GemmDesc d{A, B, out, bias, M, N, K, lda, ldb, ldo, epi, Ay, Az, By, Bz, Oy, Oz};
  gemm_tile_kernel<128,128><<<dim3((M/128)*(N/128), gy, gz), dim3(256), 0, st>>>(d);
}
static void launch_gemm64(hipStream_t st, const unsigned short* A, const unsigned short* B,
                          void* out, const float* bias,
                          int M, int N, int K, int lda, int ldb, int ldo, int epi) {
  GemmDesc d{A, B, out, bias, M, N, K, lda, ldb, ldo, epi, 0,0,0,0,0,0};
  gemm_tile_kernel<128,64><<<dim3((M/128)*(N/64), 1, 1), dim3(256), 0, st>>>(d);
}

extern "C" void kernel_launch(void* const* d_in, const int* in_sizes, int n_in,
                              void* d_out, int out_size, void* d_ws, size_t ws_size,
                              hipStream_t stream) {
  const float* x      = (const float*)d_in[0];
  const float* pre_g  = (const float*)d_in[1];
  const float* pre_b  = (const float*)d_in[2];
  const float* norm_g = (const float*)d_in[3];
  const float* norm_b = (const float*)d_in[4];
  const float* post_g = (const float*)d_in[5];
  const float* post_b = (const float*)d_in[6];
  const float* pos    = (const float*)d_in[7];
  const float* sa_b1  = (const float*)d_in[9];
  const float* sa_b2  = (const float*)d_in[11];
  const float* sa_w3  = (const float*)d_in[12];
  const float* sa_b3  = (const float*)d_in[13];
  const float* ff_b1  = (const float*)d_in[24];
  const float* ff_b2  = (const float*)d_in[26];
  const float* out_w  = (const float*)d_in[27];
  const float* out_b  = (const float*)d_in[28];
  float* outp = (float*)d_out;

  char* ws = (char*)d_ws;
  size_t off = 0;
  auto alloc = [&](size_t bytes) -> void* {
    void* p = ws + off; off += (bytes + 255) & ~(size_t)255; return p;
  };
  float* STATS = (float*)alloc(4096);
  float* BC    = (float*)alloc(2048);
  unsigned short* HSB  = (unsigned short*)alloc(8388608);
  unsigned short* A1   = (unsigned short*)alloc(1048576);
  unsigned short* IM2  = (unsigned short*)alloc(9437184);
  unsigned short* A2   = (unsigned short*)alloc(1048576);
  unsigned short* SHB  = (unsigned short*)alloc(8388608);
  unsigned short* MSHB = (unsigned short*)alloc(8388608);
  unsigned short* WBF  = (unsigned short*)alloc(6291456);
  unsigned short* WCOMB= (unsigned short*)alloc(524288);
  unsigned short* QKVM = (unsigned short*)alloc(41943040);
  unsigned short* QM   = (unsigned short*)alloc(8388608);
  unsigned short* VTB  = (unsigned short*)alloc(8388608);
  unsigned short* VMT  = (unsigned short*)alloc(8388608);
  unsigned short* SBUF = (unsigned short*)alloc(33554432);
  unsigned short* PBUF = (unsigned short*)alloc(33554432);
  unsigned short* COMB = (unsigned short*)alloc(16777216);
  unsigned short* FFMID= (unsigned short*)alloc(8388608);
  unsigned short* FINALB=(unsigned short*)alloc(8388608);

  const int OQKVM=0, OQM=1310720, OFF1=1572864, OFF2T=2097152,
            OOW=2359296, OW1=2621440, OW2R=2654208;

  // 1) GN(pre)+pos -> HSB + GN(norm) stats
  gn_pre_kernel<<<dim3(256), dim3(256), 0, stream>>>(x, pre_g, pre_b, pos, HSB, STATS);
  // 2) weights -> bf16
  {
    WCvtArgs a;
    const float LG2E = 1.4426950408889634f;
    const int   srcIdx[15] = {14,15,16, 18,21,19,22, 17,20, 23,27, 8, 0, 10, 25};
    const int   dofs[15]   = {0, 262144, 524288,
                              786432, 917504, 1048576, 1179648,
                              OQM, OQM+131072,
                              OFF1, OOW, OW1, 0, OW2R, OFF2T};
    const int   ns[15]     = {262144,262144,262144, 131072,131072,131072,131072,
                              131072,131072, 524288,262144, 32768, 0, 36864, 262144};
    const float sc[15]     = {0.125f*LG2E,1.f,1.f, 1.f,1.f,1.f,1.f,
                              0.0625f,0.0625f, 1.f,1.f, 1.f, 0.f, 1.f, 1.f};
    for (int i = 0; i < 15; ++i) { a.w[i].src = (const float*)d_in[srcIdx[i]]; a.w[i].dstOff = dofs[i]; a.w[i].n = ns[i]; a.w[i].scale = sc[i]; }
    wconvert_kernel<<<dim3(2048, 15), dim3(256), 0, stream>>>(a, WBF);
  }
  // 2b) fold FF2+OW
  {
    GemmDesc d{WBF+OOW, WBF+OFF2T, WCOMB, nullptr, 512, 512, 512, 512, 512, 512, 1, 0,0,0,0,0,0};
    gemm_tile_kernel<128,128><<<dim3(16, 1, 1), dim3(256), 0, stream>>>(d);
  }
  bias_fold_kernel<<<dim3(2), dim3(256), 0, stream>>>(out_w, ff_b2, out_b, BC);
  // 3) spatial gate chain
  launch_gemm64(stream, HSB, WBF+OW1,  A1, sa_b1, 8192, 64, 512, 512, 512, 64, 2);
  im2col_kernel<<<dim3(1024), dim3(256), 0, stream>>>(A1, IM2);
  launch_gemm64(stream, IM2, WBF+OW2R, A2, sa_b2, 8192, 64, 576, 576, 576, 64, 2);
  // 4) gate + norm
  gate_norm_kernel<<<dim3(256, 8), dim3(256), 0, stream>>>(HSB, A2, sa_w3, sa_b3, STATS, norm_g, norm_b, SHB, MSHB);

  // 5) projections
  launch_gemm128(stream, SHB,  WBF+OQKVM, QKVM, nullptr, 8192, 2560, 512, 512, 512, 2560, 1, 0,0,0,0,0,0, 1,1);
  launch_gemm64(stream, MSHB, WBF+OQM,   QM,   nullptr, 8192, 512,  512, 512, 512, 512,  1);

  // 6) V transposes
  transpose2_kernel<<<dim3(16, 8, 16), dim3(256), 0, stream>>>(QKVM, VTB, VMT);

  // 7) std MHSA flash (512 threads) -> COMB[:, 0:512]
  flash_attn_kernel<<<dim3(8, 8, 8), dim3(512), 0, stream>>>(QKVM, VTB, COMB);

  // 8) both multi-scale branches, batched (z = branch)
  launch_gemm128(stream, QM, QKVM + 1536, SBUF, nullptr,
                 1024, 1024, 256, 512, 2560, 1024, 1,
                 1024LL*512, 256, 1024LL*2560, 256, 1024LL*1024, 8388608, 8, 2);
  softmax_bf16_kernel<<<dim3(4096), dim3(256), 0, stream>>>(SBUF, PBUF, 16384);
  launch_gemm128(stream, PBUF, VMT, COMB + 512, nullptr,
                 1024, 256, 1024, 1024, 1024, 1024, 1,
                 1024LL*1024, 8388608, 512LL*1024, 256LL*1024, 1024LL*1024, 256, 8, 2);

  // 9) FF (folded FF2+OW)
  launch_gemm64(stream, COMB,  WBF+OFF1, FFMID,  ff_b1, 8192, 512, 1024, 1024, 1024, 512, 2);
  launch_gemm64(stream, FFMID, WCOMB,    FINALB, BC,    8192, 512, 512,  512,  512,  512, 1);

  // 10) GN(post) + residual
  gn_stats_bf16_kernel<<<dim3(256), dim3(256), 0, stream>>>(FINALB, STATS);
  final_out_kernel<<<dim3(16, 8, 8), dim3(256), 0, stream>>>(FINALB, STATS, post_g, post_b, x, outp);

  (void)in_sizes; (void)n_in; (void)out_size; (void)ws_size;
}

// Round 8
// 383.327 us; speedup vs baseline: 4.2235x; 1.0609x over previous
//
#include <hip/hip_runtime.h>
#include <hip/hip_bf16.h>
#include <math.h>

typedef __attribute__((ext_vector_type(8))) __bf16 v8bf;
typedef __attribute__((ext_vector_type(4))) float v4f;

__device__ __forceinline__ unsigned short f2bf(float f) {
  union { float f; unsigned int u; } a; a.f = f;
  unsigned int r = a.u + 0x7fffu + ((a.u >> 16) & 1u);
  return (unsigned short)(r >> 16);
}
__device__ __forceinline__ unsigned short f2bf_trunc(float f) {
  union { float f; unsigned int u; } a; a.f = f;
  return (unsigned short)(a.u >> 16);
}
__device__ __forceinline__ float bf2f(unsigned short u) {
  union { unsigned int i; float f; } a; a.i = ((unsigned int)u) << 16; return a.f;
}
__device__ __forceinline__ float sigm(float x) { return 1.0f / (1.0f + __expf(-x)); }

__device__ __forceinline__ void async16(const void* g, void* l) {
  __builtin_amdgcn_global_load_lds(
      (const __attribute__((address_space(1))) unsigned int*)g,
      (__attribute__((address_space(3))) unsigned int*)l, 16, 0, 0);
}

// ---------- GN(pre)+pos -> HSB bf16 token-major; fused GN(norm) stats ----------
__global__ __launch_bounds__(256) void gn_pre_kernel(
    const float* __restrict__ x, const float* __restrict__ g, const float* __restrict__ be,
    const float* __restrict__ pos, unsigned short* __restrict__ hsb, float* __restrict__ stats) {
  __shared__ float L[16384];
  __shared__ float rs[4], rs2[4], mr[2];
  int b = blockIdx.x >> 5, grp = blockIdx.x & 31;
  const float4* base = (const float4*)(x + ((size_t)b*512 + grp*16)*1024);
  float4* L4 = (float4*)L;
  int w = threadIdx.x >> 6;
  float s = 0.f, s2 = 0.f;
  for (int i = threadIdx.x; i < 4096; i += 256) {
    float4 v = base[i];
    L4[i] = v;
    s += v.x + v.y + v.z + v.w;
    s2 += v.x*v.x + v.y*v.y + v.z*v.z + v.w*v.w;
  }
#pragma unroll
  for (int o = 32; o; o >>= 1) { s += __shfl_xor(s, o); s2 += __shfl_xor(s2, o); }
  if ((threadIdx.x & 63) == 0) { rs[w] = s; rs2[w] = s2; }
  __syncthreads();
  if (threadIdx.x == 0) {
    float ts = rs[0]+rs[1]+rs[2]+rs[3], ts2 = rs2[0]+rs2[1]+rs2[2]+rs2[3];
    float mu = ts * (1.0f/16384.0f);
    float var = ts2 * (1.0f/16384.0f) - mu*mu;
    mr[0] = mu; mr[1] = rsqrtf(var + 1e-6f);
  }
  __syncthreads();
  float mu = mr[0], rstd = mr[1];
  const float4* pb = (const float4*)(pos + (size_t)grp*16*1024);
  float ns = 0.f, ns2 = 0.f;
  for (int i = threadIdx.x; i < 4096; i += 256) {
    float4 v = L4[i], p = pb[i];
    int c = grp*16 + (i >> 8);
    float gg = g[c], bb = be[c];
    float4 o;
    o.x = (v.x - mu)*rstd*gg + bb + p.x;
    o.y = (v.y - mu)*rstd*gg + bb + p.y;
    o.z = (v.z - mu)*rstd*gg + bb + p.z;
    o.w = (v.w - mu)*rstd*gg + bb + p.w;
    L4[i] = o;
    ns += o.x + o.y + o.z + o.w;
    ns2 += o.x*o.x + o.y*o.y + o.z*o.z + o.w*o.w;
  }
#pragma unroll
  for (int o = 32; o; o >>= 1) { ns += __shfl_xor(ns, o); ns2 += __shfl_xor(ns2, o); }
  if ((threadIdx.x & 63) == 0) { rs[w] = ns; rs2[w] = ns2; }
  __syncthreads();
  if (threadIdx.x == 0) {
    float ts = rs[0]+rs[1]+rs[2]+rs[3], ts2 = rs2[0]+rs2[1]+rs2[2]+rs2[3];
    float nmu = ts * (1.0f/16384.0f);
    float nvar = ts2 * (1.0f/16384.0f) - nmu*nmu;
    stats[(b*32+grp)*2] = nmu; stats[(b*32+grp)*2+1] = rsqrtf(nvar + 1e-6f);
  }
#pragma unroll
  for (int j = 0; j < 4; ++j) {
    int sI = threadIdx.x + j*256;
    unsigned int wd[8];
#pragma unroll
    for (int c = 0; c < 8; ++c) {
      unsigned int lo = f2bf(L[(2*c)*1024 + sI]);
      unsigned int hi = f2bf(L[(2*c+1)*1024 + sI]);
      wd[c] = lo | (hi << 16);
    }
    size_t oo = (size_t)(b*1024 + sI)*512 + grp*16;
    *(uint4*)(hsb + oo)     = make_uint4(wd[0], wd[1], wd[2], wd[3]);
    *(uint4*)(hsb + oo + 8) = make_uint4(wd[4], wd[5], wd[6], wd[7]);
  }
}

// ---------- im2col ----------
__global__ __launch_bounds__(256) void im2col_kernel(
    const unsigned short* __restrict__ a1, unsigned short* __restrict__ im2) {
  int row0 = blockIdx.x * 8;
#pragma unroll
  for (int it = 0; it < 3; ++it) {
    int cc = it*256 + threadIdx.x;
    if (cc >= 576) break;
    int rl = cc / 72, rr = cc - rl*72;
    int tap = rr >> 3, ch8 = rr & 7;
    int row = row0 + rl;
    int bb = row >> 10, s = row & 1023;
    int y = s >> 5, xx0 = s & 31;
    int yy = y + tap/3 - 1, xx = xx0 + tap%3 - 1;
    ushort4 v0 = make_ushort4(0,0,0,0), v1 = make_ushort4(0,0,0,0);
    if ((unsigned)yy < 32u && (unsigned)xx < 32u) {
      const unsigned short* src = a1 + ((size_t)(bb*1024 + yy*32 + xx))*64 + ch8*8;
      v0 = *(const ushort4*)src; v1 = *(const ushort4*)(src + 4);
    }
    unsigned short* dst = im2 + (size_t)row*576 + tap*64 + ch8*8;
    *(ushort4*)dst = v0; *(ushort4*)(dst + 4) = v1;
  }
}

// ---------- gate(conv3 fused) + GN(norm) ----------
__global__ __launch_bounds__(256) void gate_norm_kernel(
    const unsigned short* __restrict__ hsb, const unsigned short* __restrict__ a2,
    const float* __restrict__ w3, const float* __restrict__ b3,
    const float* __restrict__ stats, const float* __restrict__ g,
    const float* __restrict__ be,
    unsigned short* __restrict__ sh, unsigned short* __restrict__ msh) {
  int b = blockIdx.y;
  int s = blockIdx.x * 4 + (threadIdx.x >> 6);
  int oct = threadIdx.x & 63;
  int c0 = oct * 8;
  int grp = c0 >> 4;
  float part = bf2f(a2[((size_t)(b*1024) + s)*64 + oct]) * w3[oct];
#pragma unroll
  for (int o = 32; o; o >>= 1) part += __shfl_xor(part, o);
  float wgt = sigm(part + b3[0]);
  float mu = stats[(b*32 + grp)*2], rstd = stats[(b*32 + grp)*2 + 1];
  size_t o = (size_t)(b*1024 + s)*512 + c0;
  ushort4 u0 = *(const ushort4*)(hsb + o), u1 = *(const ushort4*)(hsb + o + 4);
  unsigned short uu[8] = {u0.x,u0.y,u0.z,u0.w,u1.x,u1.y,u1.z,u1.w};
  unsigned short so[8], mo[8];
#pragma unroll
  for (int j = 0; j < 8; ++j) {
    float v = bf2f(uu[j]);
    so[j] = f2bf((v - mu)*rstd*g[c0+j] + be[c0+j]);
    mo[j] = f2bf(v * wgt);
  }
  *(ushort4*)(sh + o)     = make_ushort4(so[0], so[1], so[2], so[3]);
  *(ushort4*)(sh + o + 4) = make_ushort4(so[4], so[5], so[6], so[7]);
  *(ushort4*)(msh + o)     = make_ushort4(mo[0], mo[1], mo[2], mo[3]);
  *(ushort4*)(msh + o + 4) = make_ushort4(mo[4], mo[5], mo[6], mo[7]);
}

// ---------- weight conversions ----------
struct WCvt { const float* src; int dstOff; int n; float scale; };
struct WCvtArgs { WCvt w[15]; };
__global__ __launch_bounds__(256) void wconvert_kernel(WCvtArgs a, unsigned short* __restrict__ dst) {
  WCvt e = a.w[blockIdx.y];
  int i = blockIdx.x * 256 + threadIdx.x;
  if (i >= e.n) return;
  if (blockIdx.y == 13) {
    int oc = i / 576, r = i - oc*576;
    int tap = r >> 6, ic = r & 63;
    dst[e.dstOff + i] = f2bf(e.src[(oc*64 + ic)*9 + tap]);
  } else if (blockIdx.y == 14) {
    dst[e.dstOff + i] = f2bf(e.src[(i & 511)*512 + (i >> 9)]);
  } else {
    dst[e.dstOff + i] = f2bf(e.src[i] * e.scale);
  }
}

__global__ __launch_bounds__(256) void bias_fold_kernel(
    const float* __restrict__ ow, const float* __restrict__ b2,
    const float* __restrict__ ob, float* __restrict__ bc) {
  int n = blockIdx.x * 256 + threadIdx.x;
  float s = ob[n];
  const float* r = ow + (size_t)n * 512;
#pragma unroll 8
  for (int j = 0; j < 512; ++j) s += r[j] * b2[j];
  bc[n] = s;
}

// ---------- merged V transposes ----------
__global__ __launch_bounds__(256) void transpose2_kernel(
    const unsigned short* __restrict__ qkvm,
    unsigned short* __restrict__ vtb, unsigned short* __restrict__ vmt) {
  __shared__ unsigned short t[64][65];
  int s0 = blockIdx.x * 64, c0 = blockIdx.y * 64;
  int z = blockIdx.z, b = z & 7;
  const unsigned short* in = qkvm + (z >= 8 ? 2048 : 1024);
  unsigned short* out = (z >= 8) ? vmt : vtb;
  int tx = threadIdx.x & 63, ty = threadIdx.x >> 6;
#pragma unroll
  for (int i = 0; i < 16; ++i) {
    int s = ty + i*4;
    t[s][tx] = in[((size_t)(b*1024 + s0 + s))*2560 + c0 + tx];
  }
  __syncthreads();
#pragma unroll
  for (int i = 0; i < 16; ++i) {
    int c = ty + i*4;
    out[((size_t)b*512 + c0 + c)*1024 + s0 + tx] = t[tx][c];
  }
}

// ---------- tiled GEMM: BK=64, swizzled LDS, XCD-aware tile mapping ----------
struct GemmDesc {
  const unsigned short* A; const unsigned short* B; void* out; const float* bias;
  int M, N, K, lda, ldb, ldo, epi;
  long long Ay, Az, By, Bz, Oy, Oz;
};

template<int BM, int BN>
__global__ __launch_bounds__(256) void gemm_tile_kernel(GemmDesc d) {
  constexpr int WGM = (BN >= 128) ? 2 : 4;
  constexpr int WGN = 4 / WGM;
  constexpr int MT = BM / (16 * WGM);
  constexpr int NT = BN / (16 * WGN);
  constexpr int AIT = (BM * 8) / 256;
  constexpr int BIT = (BN * 8) / 256;
  __shared__ __align__(16) unsigned short As[BM * 64];
  __shared__ __align__(16) unsigned short Bs[BN * 64];

  int ntx = d.N / BN, mtx = d.M / BM;
  int bmt, bnt;
  if ((mtx & 7) == 0) {
    int xcd = blockIdx.x & 7, j = blockIdx.x >> 3;
    int mpx = mtx >> 3;
    bmt = xcd * mpx + (j % mpx);
    bnt = j / mpx;
  } else {
    bmt = blockIdx.x / ntx; bnt = blockIdx.x % ntx;
  }
  int bm0 = bmt * BM, bn0 = bnt * BN;
  const unsigned short* A = d.A + (long long)blockIdx.y * d.Ay
      + (long long)blockIdx.z * d.Az + (size_t)bm0 * d.lda;
  const unsigned short* B = d.B + (long long)blockIdx.y * d.By
      + (long long)blockIdx.z * d.Bz + (size_t)bn0 * d.ldb;
  int tid = threadIdx.x, lane = tid & 63, w = tid >> 6;
  int wm = (WGN == 2) ? (w >> 1) : w;
  int wn = (WGN == 2) ? (w & 1) : 0;
  int ln = lane & 15, qd = lane >> 4;

  v4f acc[MT][NT];
#pragma unroll
  for (int i = 0; i < MT; ++i)
#pragma unroll
    for (int j = 0; j < NT; ++j) acc[i][j] = (v4f){0.f, 0.f, 0.f, 0.f};

  int nks = d.K >> 6;
  for (int ks = 0; ks < nks; ++ks) {
    int kof = ks * 64;
#pragma unroll
    for (int it = 0; it < AIT; ++it) {
      int c = it * 256 + tid;
      int row = c >> 3, ch = c & 7;
      async16(A + (size_t)row * d.lda + ((ch ^ (row & 7)) << 3) + kof, As + c * 8);
    }
#pragma unroll
    for (int it = 0; it < BIT; ++it) {
      int c = it * 256 + tid;
      int row = c >> 3, ch = c & 7;
      async16(B + (size_t)row * d.ldb + ((ch ^ (row & 7)) << 3) + kof, Bs + c * 8);
    }
    __syncthreads();
#pragma unroll
    for (int k2 = 0; k2 < 2; ++k2) {
      v8bf af[MT], bfr[NT];
#pragma unroll
      for (int i = 0; i < MT; ++i) {
        int row = wm * MT * 16 + i * 16 + ln;
        af[i] = *(const v8bf*)(As + row * 64 + (((k2*4 + qd) ^ (ln & 7)) << 3));
      }
#pragma unroll
      for (int j = 0; j < NT; ++j) {
        int row = wn * NT * 16 + j * 16 + ln;
        bfr[j] = *(const v8bf*)(Bs + row * 64 + (((k2*4 + qd) ^ (ln & 7)) << 3));
      }
#pragma unroll
      for (int i = 0; i < MT; ++i)
#pragma unroll
        for (int j = 0; j < NT; ++j)
          acc[i][j] = __builtin_amdgcn_mfma_f32_16x16x32_bf16(af[i], bfr[j], acc[i][j], 0, 0, 0);
    }
    __syncthreads();
  }

  size_t obase = (size_t)((long long)blockIdx.y * d.Oy + (long long)blockIdx.z * d.Oz);
#pragma unroll
  for (int i = 0; i < MT; ++i) {
#pragma unroll
    for (int j = 0; j < NT; ++j) {
      int col = bn0 + wn * NT * 16 + j * 16 + ln;
      float bia = d.bias ? d.bias[col] : 0.0f;
#pragma unroll
      for (int r = 0; r < 4; ++r) {
        int row = bm0 + wm * MT * 16 + i * 16 + qd * 4 + r;
        float v = acc[i][j][r] + bia;
        if (d.epi == 2) v = v * sigm(v);
        size_t oi = obase + (size_t)row * d.ldo + col;
        if (d.epi == 0) ((float*)d.out)[oi] = v;
        else ((unsigned short*)d.out)[oi] = f2bf(v);
      }
    }
  }
}

// ---------- flash attention, std MHSA (512 threads) ----------
__global__ __launch_bounds__(512) void flash_attn_kernel(
    const unsigned short* __restrict__ QKVM, const unsigned short* __restrict__ VTB,
    unsigned short* __restrict__ out) {
  __shared__ __align__(16) unsigned short Ks[128*64];
  __shared__ __align__(16) unsigned short Vts[64*128];
  __shared__ __align__(16) unsigned short Pw[8][16*128];
  int h = blockIdx.x, b = blockIdx.y, qt = blockIdx.z;
  int tid = threadIdx.x, lane = tid & 63, w = tid >> 6;
  int ln = lane & 15, qd = lane >> 4;

  const unsigned short* Qbase = QKVM + ((size_t)(b*1024 + qt*128 + w*16))*2560 + h*64;
  v8bf aq[2];
#pragma unroll
  for (int s = 0; s < 2; ++s)
    aq[s] = *(const v8bf*)(Qbase + (size_t)ln*2560 + s*32 + qd*8);

  v4f o_acc[4];
  float l_part[4];
#pragma unroll
  for (int dn = 0; dn < 4; ++dn) o_acc[dn] = (v4f){0.f,0.f,0.f,0.f};
#pragma unroll
  for (int r = 0; r < 4; ++r) l_part[r] = 0.f;

  const unsigned short* Kg = QKVM + 512 + (size_t)(b*1024)*2560 + h*64;
  const unsigned short* Vg = VTB + ((size_t)(b*512) + h*64)*1024;

  for (int kt = 0; kt < 8; ++kt) {
#pragma unroll
    for (int it = 0; it < 2; ++it) {
      int c = it*512 + tid;
      async16(Kg + (size_t)(kt*128 + (c >> 3))*2560 + (((c & 7) ^ ((c >> 3) & 7)) << 3),
              Ks + c*8);
    }
#pragma unroll
    for (int it = 0; it < 2; ++it) {
      int c = it*512 + tid;
      async16(Vg + (size_t)(c >> 4)*1024 + kt*128 + ((((c & 15) ^ ((c >> 4) & 7))) << 3),
              Vts + c*8);
    }
    __syncthreads();

    v4f sc[8];
#pragma unroll
    for (int n = 0; n < 8; ++n) {
      v4f a = (v4f){0.f,0.f,0.f,0.f};
#pragma unroll
      for (int s = 0; s < 2; ++s) {
        v8bf kb = *(const v8bf*)(Ks + (n*16 + ln)*64 + (((s*4 + qd) ^ (ln & 7)) << 3));
        a = __builtin_amdgcn_mfma_f32_16x16x32_bf16(aq[s], kb, a, 0, 0, 0);
      }
      sc[n] = a;
    }
#pragma unroll
    for (int r = 0; r < 4; ++r) {
      int row7 = (qd*4 + r) & 7;
      float acc_l = 0.f;
#pragma unroll
      for (int n = 0; n < 8; ++n) {
        float p = exp2f(sc[n][r]);
        acc_l += p;
        Pw[w][(qd*4 + r)*128 + (((n*2 + (ln >> 3)) ^ row7) << 3) + (ln & 7)] = f2bf_trunc(p);
      }
      l_part[r] += acc_l;
    }
#pragma unroll
    for (int dn = 0; dn < 4; ++dn) {
      v4f a = o_acc[dn];
#pragma unroll
      for (int ks2 = 0; ks2 < 4; ++ks2) {
        int phys = (((ks2*4 + qd) ^ (ln & 7)) << 3);
        v8bf pf = *(const v8bf*)(&Pw[w][ln*128 + phys]);
        v8bf vf = *(const v8bf*)(Vts + (dn*16 + ln)*128 + phys);
        a = __builtin_amdgcn_mfma_f32_16x16x32_bf16(pf, vf, a, 0, 0, 0);
      }
      o_acc[dn] = a;
    }
    __syncthreads();
  }

  unsigned short* ob = out + ((size_t)(b*1024 + qt*128 + w*16))*1024 + h*64;
#pragma unroll
  for (int r = 0; r < 4; ++r) {
    float l = l_part[r];
    l += __shfl_xor(l, 1); l += __shfl_xor(l, 2);
    l += __shfl_xor(l, 4); l += __shfl_xor(l, 8);
    float rinv = 1.0f / l;
#pragma unroll
    for (int dn = 0; dn < 4; ++dn)
      ob[(size_t)(qd*4 + r)*1024 + dn*16 + ln] = f2bf(o_acc[dn][r] * rinv);
  }
}

// ---------- flash attention, multi-scale branches: D=256, single head ----------
// grid (bb = b*2+br : 16, 1, qt : 16); 256 thr = 4 waves x 16 q-rows (64 rows/block).
// Q from QM (B*S,512) col br*256 (scale 1/16*log2e pre-folded); K from QKVM col
// 1536+br*256 (ld 2560); Vt from VMT (b, 512, 1024) rows br*256+. Out -> COMB[:,512+br*256+].
__global__ __launch_bounds__(256) void flash_branch_kernel(
    const unsigned short* __restrict__ QKVM, const unsigned short* __restrict__ QM,
    const unsigned short* __restrict__ VMT, unsigned short* __restrict__ out) {
  __shared__ __align__(16) unsigned short Ks[64*256];    // 32 KB, swizzled
  __shared__ __align__(16) unsigned short Vts[256*64];   // 32 KB, swizzled
  __shared__ __align__(16) unsigned short Pw[4][16*64];  // 8 KB
  int bb = blockIdx.x, b = bb >> 1, br = bb & 1;
  int qt = blockIdx.z;
  int tid = threadIdx.x, lane = tid & 63, w = tid >> 6;
  int ln = lane & 15, qd = lane >> 4;

  const unsigned short* Qb = QM + ((size_t)(b*1024 + qt*64 + w*16))*512 + br*256;
  v8bf aq[8];
#pragma unroll
  for (int s = 0; s < 8; ++s)
    aq[s] = *(const v8bf*)(Qb + (size_t)ln*512 + s*32 + qd*8);

  v4f o_acc[16];
  float l_part[4];
#pragma unroll
  for (int dn = 0; dn < 16; ++dn) o_acc[dn] = (v4f){0.f,0.f,0.f,0.f};
#pragma unroll
  for (int r = 0; r < 4; ++r) l_part[r] = 0.f;

  const unsigned short* Kg = QKVM + 1536 + br*256 + (size_t)(b*1024)*2560;
  const unsigned short* Vg = VMT + ((size_t)(b*512) + br*256)*1024;

  for (int kt = 0; kt < 16; ++kt) {
#pragma unroll
    for (int it = 0; it < 8; ++it) {   // K tile 64x256: 2048 chunks
      int c = it*256 + tid;
      int row = c >> 5, ch = c & 31;
      async16(Kg + (size_t)(kt*64 + row)*2560 + ((ch ^ (row & 7)) << 3), Ks + c*8);
    }
#pragma unroll
    for (int it = 0; it < 8; ++it) {   // Vt tile 256x64: 2048 chunks
      int c = it*256 + tid;
      int row = c >> 3, ch = c & 7;
      async16(Vg + (size_t)row*1024 + kt*64 + ((ch ^ (row & 7)) << 3), Vts + c*8);
    }
    __syncthreads();

    v4f sc[4];
#pragma unroll
    for (int n = 0; n < 4; ++n) {
      v4f a = (v4f){0.f,0.f,0.f,0.f};
      int krow = n*16 + ln;
#pragma unroll
      for (int s = 0; s < 8; ++s) {
        v8bf kb = *(const v8bf*)(Ks + krow*256 + (((s*4 + qd) ^ (krow & 7)) << 3));
        a = __builtin_amdgcn_mfma_f32_16x16x32_bf16(aq[s], kb, a, 0, 0, 0);
      }
      sc[n] = a;
    }
#pragma unroll
    for (int r = 0; r < 4; ++r) {
      int row7 = (qd*4 + r) & 7;
      float acc_l = 0.f;
#pragma unroll
      for (int n = 0; n < 4; ++n) {
        float p = exp2f(sc[n][r]);
        acc_l += p;
        Pw[w][(qd*4 + r)*64 + (((n*2 + (ln >> 3)) ^ row7) << 3) + (ln & 7)] = f2bf_trunc(p);
      }
      l_part[r] += acc_l;
    }
#pragma unroll
    for (int dn = 0; dn < 16; ++dn) {
      v4f a = o_acc[dn];
#pragma unroll
      for (int ks2 = 0; ks2 < 2; ++ks2) {
        int phys = (((ks2*4 + qd) ^ (ln & 7)) << 3);
        v8bf pf = *(const v8bf*)(&Pw[w][ln*64 + phys]);
        v8bf vf = *(const v8bf*)(Vts + (dn*16 + ln)*64 + phys);
        a = __builtin_amdgcn_mfma_f32_16x16x32_bf16(pf, vf, a, 0, 0, 0);
      }
      o_acc[dn] = a;
    }
    __syncthreads();
  }

  unsigned short* ob = out + ((size_t)(b*1024 + qt*64 + w*16))*1024 + 512 + br*256;
#pragma unroll
  for (int r = 0; r < 4; ++r) {
    float l = l_part[r];
    l += __shfl_xor(l, 1); l += __shfl_xor(l, 2);
    l += __shfl_xor(l, 4); l += __shfl_xor(l, 8);
    float rinv = 1.0f / l;
#pragma unroll
    for (int dn = 0; dn < 16; ++dn)
      ob[(size_t)(qd*4 + r)*1024 + dn*16 + ln] = f2bf(o_acc[dn][r] * rinv);
  }
}

// ---------- stats over (B,S,C) bf16 per (b,group) ----------
__global__ __launch_bounds__(256) void gn_stats_bf16_kernel(
    const unsigned short* __restrict__ t, float* __restrict__ stats) {
  int b = blockIdx.x >> 5, grp = blockIdx.x & 31;
  float s = 0.f, s2 = 0.f;
#pragma unroll
  for (int j = 0; j < 4; ++j) {
    int sI = threadIdx.x + j*256;
    const unsigned short* p = t + ((size_t)(b*1024 + sI))*512 + grp*16;
    uint4 a = *(const uint4*)p, c2 = *(const uint4*)(p + 8);
    unsigned int ww[8] = {a.x,a.y,a.z,a.w,c2.x,c2.y,c2.z,c2.w};
#pragma unroll
    for (int k = 0; k < 8; ++k) {
      float lo = bf2f((unsigned short)(ww[k] & 0xffff));
      float hi = bf2f((unsigned short)(ww[k] >> 16));
      s += lo + hi; s2 += lo*lo + hi*hi;
    }
  }
#pragma unroll
  for (int o = 32; o; o >>= 1) { s += __shfl_xor(s, o); s2 += __shfl_xor(s2, o); }
  __shared__ float rs[4], rs2[4];
  int w = threadIdx.x >> 6;
  if ((threadIdx.x & 63) == 0) { rs[w] = s; rs2[w] = s2; }
  __syncthreads();
  if (threadIdx.x == 0) {
    float ts = rs[0]+rs[1]+rs[2]+rs[3], ts2 = rs2[0]+rs2[1]+rs2[2]+rs2[3];
    float mu = ts * (1.0f/16384.0f);
    float var = ts2 * (1.0f/16384.0f) - mu*mu;
    stats[(b*32+grp)*2] = mu; stats[(b*32+grp)*2+1] = rsqrtf(var + 1e-6f);
  }
}

// ---------- GN(post) + residual ----------
__global__ __launch_bounds__(256) void final_out_kernel(
    const unsigned short* __restrict__ fin, const float* __restrict__ stats,
    const float* __restrict__ g, const float* __restrict__ be,
    const float* __restrict__ x, float* __restrict__ out) {
  __shared__ float t[64][65];
  int s0 = blockIdx.x * 64, c0 = blockIdx.y * 64, b = blockIdx.z;
  int tx = threadIdx.x & 63, ty = threadIdx.x >> 6;
#pragma unroll
  for (int i = 0; i < 16; ++i) {
    int s = ty + i*4;
    t[s][tx] = bf2f(fin[((size_t)(b*1024 + s0 + s))*512 + c0 + tx]);
  }
  __syncthreads();
#pragma unroll
  for (int i = 0; i < 16; ++i) {
    int c = ty + i*4;
    int cc = c0 + c, grp = cc >> 4;
    float mu = stats[(b*32+grp)*2], rstd = stats[(b*32+grp)*2+1];
    float gg = g[cc], bb = be[cc];
    size_t oi = ((size_t)(b*512 + cc))*1024 + s0 + tx;
    out[oi] = (t[tx][c] - mu)*rstd*gg + bb + x[oi];
  }
}

// =====================================================================
static void launch_gemm128(hipStream_t st, const unsigned short* A, const unsigned short* B,
                           void* out, const float* bias,
                           int M, int N, int K, int lda, int ldb, int ldo, int epi,
                           long long Ay, long long Az, long long By, long long Bz,
                           long long Oy, long long Oz, int gy, int gz) {
  GemmDesc d{A, B, out, bias, M, N, K, lda, ldb, ldo, epi, Ay, Az, By, Bz, Oy, Oz};
  gemm_tile_kernel<128,128><<<dim3((M/128)*(N/128), gy, gz), dim3(256), 0, st>>>(d);
}
static void launch_gemm64(hipStream_t st, const unsigned short* A, const unsigned short* B,
                          void* out, const float* bias,
                          int M, int N, int K, int lda, int ldb, int ldo, int epi) {
  GemmDesc d{A, B, out, bias, M, N, K, lda, ldb, ldo, epi, 0,0,0,0,0,0};
  gemm_tile_kernel<128,64><<<dim3((M/128)*(N/64), 1, 1), dim3(256), 0, st>>>(d);
}

extern "C" void kernel_launch(void* const* d_in, const int* in_sizes, int n_in,
                              void* d_out, int out_size, void* d_ws, size_t ws_size,
                              hipStream_t stream) {
  const float* x      = (const float*)d_in[0];
  const float* pre_g  = (const float*)d_in[1];
  const float* pre_b  = (const float*)d_in[2];
  const float* norm_g = (const float*)d_in[3];
  const float* norm_b = (const float*)d_in[4];
  const float* post_g = (const float*)d_in[5];
  const float* post_b = (const float*)d_in[6];
  const float* pos    = (const float*)d_in[7];
  const float* sa_b1  = (const float*)d_in[9];
  const float* sa_b2  = (const float*)d_in[11];
  const float* sa_w3  = (const float*)d_in[12];
  const float* sa_b3  = (const float*)d_in[13];
  const float* ff_b1  = (const float*)d_in[24];
  const float* ff_b2  = (const float*)d_in[26];
  const float* out_w  = (const float*)d_in[27];
  const float* out_b  = (const float*)d_in[28];
  float* outp = (float*)d_out;

  char* ws = (char*)d_ws;
  size_t off = 0;
  auto alloc = [&](size_t bytes) -> void* {
    void* p = ws + off; off += (bytes + 255) & ~(size_t)255; return p;
  };
  float* STATS = (float*)alloc(4096);
  float* BC    = (float*)alloc(2048);
  unsigned short* HSB  = (unsigned short*)alloc(8388608);
  unsigned short* A1   = (unsigned short*)alloc(1048576);
  unsigned short* IM2  = (unsigned short*)alloc(9437184);
  unsigned short* A2   = (unsigned short*)alloc(1048576);
  unsigned short* SHB  = (unsigned short*)alloc(8388608);
  unsigned short* MSHB = (unsigned short*)alloc(8388608);
  unsigned short* WBF  = (unsigned short*)alloc(6291456);
  unsigned short* WCOMB= (unsigned short*)alloc(524288);
  unsigned short* QKVM = (unsigned short*)alloc(41943040);
  unsigned short* QM   = (unsigned short*)alloc(8388608);
  unsigned short* VTB  = (unsigned short*)alloc(8388608);
  unsigned short* VMT  = (unsigned short*)alloc(8388608);
  unsigned short* COMB = (unsigned short*)alloc(16777216);
  unsigned short* FFMID= (unsigned short*)alloc(8388608);
  unsigned short* FINALB=(unsigned short*)alloc(8388608);

  const int OQKVM=0, OQM=1310720, OFF1=1572864, OFF2T=2097152,
            OOW=2359296, OW1=2621440, OW2R=2654208;

  // 1) GN(pre)+pos -> HSB + GN(norm) stats
  gn_pre_kernel<<<dim3(256), dim3(256), 0, stream>>>(x, pre_g, pre_b, pos, HSB, STATS);
  // 2) weights -> bf16 (log2e folded into all attention Q weights)
  {
    WCvtArgs a;
    const float LG2E = 1.4426950408889634f;
    const int   srcIdx[15] = {14,15,16, 18,21,19,22, 17,20, 23,27, 8, 0, 10, 25};
    const int   dofs[15]   = {0, 262144, 524288,
                              786432, 917504, 1048576, 1179648,
                              OQM, OQM+131072,
                              OFF1, OOW, OW1, 0, OW2R, OFF2T};
    const int   ns[15]     = {262144,262144,262144, 131072,131072,131072,131072,
                              131072,131072, 524288,262144, 32768, 0, 36864, 262144};
    const float sc[15]     = {0.125f*LG2E,1.f,1.f, 1.f,1.f,1.f,1.f,
                              0.0625f*LG2E,0.0625f*LG2E, 1.f,1.f, 1.f, 0.f, 1.f, 1.f};
    for (int i = 0; i < 15; ++i) { a.w[i].src = (const float*)d_in[srcIdx[i]]; a.w[i].dstOff = dofs[i]; a.w[i].n = ns[i]; a.w[i].scale = sc[i]; }
    wconvert_kernel<<<dim3(2048, 15), dim3(256), 0, stream>>>(a, WBF);
  }
  // 2b) fold FF2+OW
  {
    GemmDesc d{WBF+OOW, WBF+OFF2T, WCOMB, nullptr, 512, 512, 512, 512, 512, 512, 1, 0,0,0,0,0,0};
    gemm_tile_kernel<128,128><<<dim3(16, 1, 1), dim3(256), 0, stream>>>(d);
  }
  bias_fold_kernel<<<dim3(2), dim3(256), 0, stream>>>(out_w, ff_b2, out_b, BC);
  // 3) spatial gate chain
  launch_gemm64(stream, HSB, WBF+OW1,  A1, sa_b1, 8192, 64, 512, 512, 512, 64, 2);
  im2col_kernel<<<dim3(1024), dim3(256), 0, stream>>>(A1, IM2);
  launch_gemm64(stream, IM2, WBF+OW2R, A2, sa_b2, 8192, 64, 576, 576, 576, 64, 2);
  // 4) gate + norm
  gate_norm_kernel<<<dim3(256, 8), dim3(256), 0, stream>>>(HSB, A2, sa_w3, sa_b3, STATS, norm_g, norm_b, SHB, MSHB);

  // 5) projections
  launch_gemm128(stream, SHB,  WBF+OQKVM, QKVM, nullptr, 8192, 2560, 512, 512, 512, 2560, 1, 0,0,0,0,0,0, 1,1);
  launch_gemm64(stream, MSHB, WBF+OQM,   QM,   nullptr, 8192, 512,  512, 512, 512, 512,  1);

  // 6) V transposes
  transpose2_kernel<<<dim3(16, 8, 16), dim3(256), 0, stream>>>(QKVM, VTB, VMT);

  // 7) std MHSA flash -> COMB[:, 0:512]
  flash_attn_kernel<<<dim3(8, 8, 8), dim3(512), 0, stream>>>(QKVM, VTB, COMB);

  // 8) branch flash -> COMB[:, 512:1024]
  flash_branch_kernel<<<dim3(16, 1, 16), dim3(256), 0, stream>>>(QKVM, QM, VMT, COMB);

  // 9) FF (folded FF2+OW)
  launch_gemm64(stream, COMB,  WBF+OFF1, FFMID,  ff_b1, 8192, 512, 1024, 1024, 1024, 512, 2);
  launch_gemm64(stream, FFMID, WCOMB,    FINALB, BC,    8192, 512, 512,  512,  512,  512, 1);

  // 10) GN(post) + residual
  gn_stats_bf16_kernel<<<dim3(256), dim3(256), 0, stream>>>(FINALB, STATS);
  final_out_kernel<<<dim3(16, 8, 8), dim3(256), 0, stream>>>(FINALB, STATS, post_g, post_b, x, outp);

  (void)in_sizes; (void)n_in; (void)out_size; (void)ws_size;
}